// Round 2
// baseline (343.489 us; speedup 1.0000x reference)
//
#include <hip/hip_runtime.h>
#include <hip/hip_bf16.h>
#include <cstddef>
#include <cstdint>

typedef __bf16 bf16_t;
typedef bf16_t bf16x8 __attribute__((ext_vector_type(8)));
typedef bf16_t bf16x4 __attribute__((ext_vector_type(4)));
typedef float f32x4 __attribute__((ext_vector_type(4)));

#define LATENT 768
#define FFN_DIM 3072
#define NTOK 4096      // 2*2048
#define SEQ 2048
#define HEADS 12
#define HD 64

#define C2F 0.18033688011112042f   // 0.125 * log2(e)

__device__ __forceinline__ void gload_lds16(const bf16_t* g, bf16_t* l) {
    __builtin_amdgcn_global_load_lds((const __attribute__((address_space(1))) void*)g,
                                     (__attribute__((address_space(3))) void*)l, 16, 0, 0);
}

// ---------------------------------------------------------------------------
// fp32 -> bf16 conversion, multi-segment; segment 7 = f32 bias concat (bq|bk|bv)
// ---------------------------------------------------------------------------
struct CvtDesc {
    const float* src[7];
    bf16_t* dst[7];
    int n4[7];
    const float* bsrc[3];
    float* bdst;
};

__global__ __launch_bounds__(256) void cvt_f32_bf16(CvtDesc d) {
    int seg = blockIdx.y;
    if (seg == 7) {   // bias concat: 3 blocks x 768 floats
        int which = blockIdx.x;
        if (which >= 3) return;
        int t = threadIdx.x;
#pragma unroll
        for (int i = 0; i < 3; ++i)
            d.bdst[which * LATENT + t + i * 256] = d.bsrc[which][t + i * 256];
        return;
    }
    int i = blockIdx.x * 256 + threadIdx.x;
    if (i >= d.n4[seg]) return;
    float4 v = ((const float4*)d.src[seg])[i];
    bf16x4 o;
    o[0] = (bf16_t)v.x; o[1] = (bf16_t)v.y; o[2] = (bf16_t)v.z; o[3] = (bf16_t)v.w;
    *(bf16x4*)&d.dst[seg][(size_t)i * 4] = o;
}

// ---------------------------------------------------------------------------
// GEMM 128xNT (NT=128), 256 thr = 4 waves, BK=32, global_load_lds x16,
// DOUBLE-BUFFERED K-loop (prefetch k+1 after barrier, compute on k).
// K-ROTATION: each block traverses K-tiles circularly starting at a
// block-dependent offset, so co-resident blocks (which otherwise run in
// perfect lockstep and hammer the SAME A/B cache lines every iteration —
// XCD = bx%8 puts all A-slice sharers on one XCD) request disjoint lines.
// EPI: 0 none->f32, 1 none->bf16, 2 exact-GELU->bf16,
//      3 bf16 with cols<LATENT scaled by C2F (Q pre-scale for exp2 softmax)
// ---------------------------------------------------------------------------
template<int EPI, int NT>
__global__ __launch_bounds__(256) void gemm128(const bf16_t* __restrict__ A,
                                               const bf16_t* __restrict__ B,
                                               const float* __restrict__ bias,
                                               void* __restrict__ Cv,
                                               int M, int N, int K) {
    __shared__ __align__(16) bf16_t As[2][128 * 32];
    __shared__ __align__(16) bf16_t Bs[2][NT * 32];
    int t = threadIdx.x;
    int w = t >> 6;
    int lane = t & 63, l16 = lane & 15, quad = lane >> 4;
    int m0 = blockIdx.x * 128, n0 = blockIdx.y * NT;
    int mrow0 = (w & 1) * 64, ncol0 = (w >> 1) * (NT / 2);
    const int NJ = NT / 32;

    f32x4 acc[4][NJ] = {};

    int srow = lane >> 2;
    int sseg = (lane & 3) * 8;

    auto stage = [&](int k0, int buf) {
        const bf16_t* Ag = A + (size_t)(m0 + w * 32 + srow) * K + k0 + sseg;
        gload_lds16(Ag,          &As[buf][(w * 32) * 32]);
        gload_lds16(Ag + 16 * K, &As[buf][(w * 32 + 16) * 32]);
        if (NT == 128) {
            const bf16_t* Bg = B + (size_t)(n0 + w * 32 + srow) * K + k0 + sseg;
            gload_lds16(Bg,          &Bs[buf][(w * 32) * 32]);
            gload_lds16(Bg + 16 * K, &Bs[buf][(w * 32 + 16) * 32]);
        } else {
            const bf16_t* Bg = B + (size_t)(n0 + w * 16 + srow) * K + k0 + sseg;
            gload_lds16(Bg, &Bs[buf][(w * 16) * 32]);
        }
    };

    int niter = K / 32;
    // rotation: 7 coprime to niter (24/96) => co-XCD same-bx blocks (A-slice
    // sharers, varying by) get pairwise-distinct k-tiles each instant.
    int rot = (blockIdx.y * 7 + blockIdx.x * 5) % niter;
    auto ktile = [&](int kt) { int kk = kt + rot; return kk >= niter ? kk - niter : kk; };

    stage(ktile(0) * 32, 0);
    for (int kt = 0; kt < niter; ++kt) {
        __syncthreads();   // drains prev prefetch (vmcnt0) + readers of other buf
        int cur = kt & 1;
        if (kt + 1 < niter) stage(ktile(kt + 1) * 32, cur ^ 1);

        bf16x8 a[4], b[NJ];
#pragma unroll
        for (int i = 0; i < 4; ++i)
            a[i] = *(const bf16x8*)&As[cur][(mrow0 + i * 16 + l16) * 32 + quad * 8];
#pragma unroll
        for (int j = 0; j < NJ; ++j)
            b[j] = *(const bf16x8*)&Bs[cur][(ncol0 + j * 16 + l16) * 32 + quad * 8];
#pragma unroll
        for (int i = 0; i < 4; ++i)
#pragma unroll
            for (int j = 0; j < NJ; ++j)
                acc[i][j] = __builtin_amdgcn_mfma_f32_16x16x32_bf16(a[i], b[j], acc[i][j], 0, 0, 0);
    }

    float* Cf = (float*)Cv;
    bf16_t* Cb = (bf16_t*)Cv;
#pragma unroll
    for (int j = 0; j < NJ; ++j) {
        int col = n0 + ncol0 + j * 16 + l16;
        float bvv = bias[col];
#pragma unroll
        for (int i = 0; i < 4; ++i) {
            int row0 = m0 + mrow0 + i * 16 + quad * 4;
#pragma unroll
            for (int r = 0; r < 4; ++r) {
                float v = acc[i][j][r] + bvv;
                if (EPI == 2) v = 0.5f * v * (1.0f + erff(v * 0.70710678118654752f));
                if (EPI == 3) { if (col < LATENT) v *= C2F; }
                if (EPI == 0) Cf[(size_t)(row0 + r) * N + col] = v;
                else          Cb[(size_t)(row0 + r) * N + col] = (bf16_t)v;
            }
        }
    }
}

// ---------------------------------------------------------------------------
// GEMM 64x64 tile, 2 waves (128 thr), DOUBLE-BUFFERED K-loop, K-rotation.
// For N=768: grid 64x12 = 768 blocks = 3/CU balanced.
// ---------------------------------------------------------------------------
template<int EPI>
__global__ __launch_bounds__(128) void gemm64(const bf16_t* __restrict__ A,
                                              const bf16_t* __restrict__ B,
                                              const float* __restrict__ bias,
                                              void* __restrict__ Cv,
                                              int M, int N, int K) {
    __shared__ __align__(16) bf16_t As[2][64 * 32];
    __shared__ __align__(16) bf16_t Bs[2][64 * 32];
    int t = threadIdx.x;
    int w = t >> 6;                  // 0..1
    int lane = t & 63, l16 = lane & 15, quad = lane >> 4;
    int m0 = blockIdx.x * 64, n0 = blockIdx.y * 64;

    f32x4 acc[2][4] = {};

    int srow = lane >> 2;
    int sseg = (lane & 3) * 8;

    auto stage = [&](int k0, int buf) {
        const bf16_t* Ag = A + (size_t)(m0 + w * 32 + srow) * K + k0 + sseg;
        gload_lds16(Ag,          &As[buf][(w * 32) * 32]);
        gload_lds16(Ag + 16 * K, &As[buf][(w * 32 + 16) * 32]);
        const bf16_t* Bg = B + (size_t)(n0 + w * 32 + srow) * K + k0 + sseg;
        gload_lds16(Bg,          &Bs[buf][(w * 32) * 32]);
        gload_lds16(Bg + 16 * K, &Bs[buf][(w * 32 + 16) * 32]);
    };

    int niter = K / 32;
    int rot = (blockIdx.y * 7 + blockIdx.x * 5) % niter;
    auto ktile = [&](int kt) { int kk = kt + rot; return kk >= niter ? kk - niter : kk; };

    stage(ktile(0) * 32, 0);
    for (int kt = 0; kt < niter; ++kt) {
        __syncthreads();
        int cur = kt & 1;
        if (kt + 1 < niter) stage(ktile(kt + 1) * 32, cur ^ 1);

        bf16x8 a[2], b[4];
#pragma unroll
        for (int i = 0; i < 2; ++i)
            a[i] = *(const bf16x8*)&As[cur][(w * 32 + i * 16 + l16) * 32 + quad * 8];
#pragma unroll
        for (int j = 0; j < 4; ++j)
            b[j] = *(const bf16x8*)&Bs[cur][(j * 16 + l16) * 32 + quad * 8];
#pragma unroll
        for (int i = 0; i < 2; ++i)
#pragma unroll
            for (int j = 0; j < 4; ++j)
                acc[i][j] = __builtin_amdgcn_mfma_f32_16x16x32_bf16(a[i], b[j], acc[i][j], 0, 0, 0);
    }

    float* Cf = (float*)Cv;
    bf16_t* Cb = (bf16_t*)Cv;
#pragma unroll
    for (int j = 0; j < 4; ++j) {
        int col = n0 + j * 16 + l16;
        float bvv = bias[col];
#pragma unroll
        for (int i = 0; i < 2; ++i) {
            int row0 = m0 + w * 32 + i * 16 + quad * 4;
#pragma unroll
            for (int r = 0; r < 4; ++r) {
                float v = acc[i][j][r] + bvv;
                if (EPI == 2) v = 0.5f * v * (1.0f + erff(v * 0.70710678118654752f));
                if (EPI == 0) Cf[(size_t)(row0 + r) * N + col] = v;
                else          Cb[(size_t)(row0 + r) * N + col] = (bf16_t)v;
            }
        }
    }
}

// ---------------------------------------------------------------------------
// V transpose: QKV V-part [b, n, h, d] -> Vt [b, h, d, n]
// ---------------------------------------------------------------------------
__global__ __launch_bounds__(256) void v_transpose(const bf16_t* __restrict__ QKV,
                                                   bf16_t* __restrict__ Vt) {
    __shared__ bf16_t Ts[64][68];
    int t = threadIdx.x;
    int bh = blockIdx.y;
    int b = bh / HEADS, h = bh % HEADS;
    int n0 = blockIdx.x * 64;
    size_t rowbase = (size_t)b * SEQ;
    int r = t >> 3, seg = (t & 7) * 8;
#pragma unroll
    for (int i = 0; i < 2; ++i) {
        int rr = r + i * 32;
        *(bf16x8*)&Ts[rr][seg] =
            *(const bf16x8*)&QKV[(rowbase + n0 + rr) * (3 * LATENT) + 2 * LATENT + h * HD + seg];
    }
    __syncthreads();
#pragma unroll
    for (int i = 0; i < 2; ++i) {
        int d = r + i * 32;
        bf16x8 o;
#pragma unroll
        for (int jj = 0; jj < 8; ++jj) o[jj] = Ts[seg + jj][d];
        *(bf16x8*)&Vt[((size_t)bh * HD + d) * SEQ + n0 + seg] = o;
    }
}

// ---------------------------------------------------------------------------
// Flash attention (S^T formulation). Block = 4 waves x 64 q-rows = 256 q.
// P stored [q][key]: b64-packed writes, b128 A-frag reads. Q pre-scaled by C2.
// Double-buffered K/V staging with per-block K-tile ROTATION (the 8 q-blocks
// of one head otherwise stream identical K/V lines in lockstep). Linear
// softmax (pure k-sum, rotation-safe); split-K x2 -> f32 partials.
// ---------------------------------------------------------------------------
__global__ __launch_bounds__(256) void attn_flash(const bf16_t* __restrict__ QKV,
                                                  const bf16_t* __restrict__ Vt,
                                                  float* __restrict__ Op0,
                                                  float* __restrict__ Op1,
                                                  float* __restrict__ vs0,
                                                  float* __restrict__ vs1) {
    __shared__ __align__(16) bf16_t Ks[2][2][64][32];    // [buf][d-chunk][key][d32]
    __shared__ __align__(16) bf16_t Vts[2][2][64][32];   // [buf][key-chunk][d][key32]
    __shared__ __align__(16) bf16_t Ps[4][64][72];       // [wave][q][key]

    int t = threadIdx.x;
    int w = t >> 6;
    int lane = t & 63, l16 = lane & 15, quad = lane >> 4;
    int bh = blockIdx.x;
    int b = bh / HEADS, h = bh % HEADS;
    int qblk = blockIdx.y * 256;
    int z = blockIdx.z;
    float* Op = z ? Op1 : Op0;
    float* vs = z ? vs1 : vs0;
    size_t rowbase = (size_t)b * SEQ;
    int kbase = z * (SEQ / 2);
    const int LD = 3 * LATENT;
    int qw = qblk + w * 64;

    bf16x8 bq[4][2];
#pragma unroll
    for (int qt = 0; qt < 4; ++qt) {
        const bf16_t* qrow = QKV + (rowbase + qw + qt * 16 + l16) * LD + h * HD;
        bq[qt][0] = *(const bf16x8*)&qrow[quad * 8];
        bq[qt][1] = *(const bf16x8*)&qrow[32 + quad * 8];
    }

    f32x4 acc[4][4] = {};    // [qt][dt]
    float vsum[4] = {};

    int srow = lane >> 2;
    int sseg = (lane & 3) * 8;

    const int NKT = SEQ / 128;           // 16 k-tiles of 64 keys per z-half
    int rot = (blockIdx.y * 7) & (NKT - 1);   // distinct per q-block (7 coprime 16)

    auto stage = [&](int tile, int buf) {
        int koff = kbase + tile * 64;
        const bf16_t* kg = QKV + (rowbase + koff + w * 16 + srow) * LD + LATENT + h * HD + sseg;
        gload_lds16(kg,      &Ks[buf][0][w * 16][0]);
        gload_lds16(kg + 32, &Ks[buf][1][w * 16][0]);
        const bf16_t* vg = Vt + ((size_t)bh * HD + w * 16 + srow) * SEQ + koff + sseg;
        gload_lds16(vg,      &Vts[buf][0][w * 16][0]);
        gload_lds16(vg + 32, &Vts[buf][1][w * 16][0]);
    };
    auto ktile = [&](int kt) { int kk = kt + rot; return kk >= NKT ? kk - NKT : kk; };

    stage(ktile(0), 0);

    for (int kt = 0; kt < NKT; ++kt) {
        __syncthreads();
        int cur = kt & 1;
        if (kt + 1 < NKT) stage(ktile(kt + 1), cur ^ 1);

#pragma unroll
        for (int skt = 0; skt < 4; ++skt) {
            bf16x8 ak0 = *(const bf16x8*)&Ks[cur][0][skt * 16 + l16][quad * 8];
            bf16x8 ak1 = *(const bf16x8*)&Ks[cur][1][skt * 16 + l16][quad * 8];
#pragma unroll
            for (int qt = 0; qt < 4; ++qt) {
                f32x4 s = {};
                s = __builtin_amdgcn_mfma_f32_16x16x32_bf16(ak0, bq[qt][0], s, 0, 0, 0);
                s = __builtin_amdgcn_mfma_f32_16x16x32_bf16(ak1, bq[qt][1], s, 0, 0, 0);
                bf16x4 pk;
#pragma unroll
                for (int r = 0; r < 4; ++r) {
                    float p = __builtin_amdgcn_exp2f(s[r]);
                    vsum[qt] += p;
                    pk[r] = (bf16_t)p;
                }
                *(bf16x4*)&Ps[w][qt * 16 + l16][skt * 16 + quad * 4] = pk;
            }
        }
        __threadfence_block();

        bf16x8 bv[4][2];
#pragma unroll
        for (int dt = 0; dt < 4; ++dt) {
            bv[dt][0] = *(const bf16x8*)&Vts[cur][0][dt * 16 + l16][quad * 8];
            bv[dt][1] = *(const bf16x8*)&Vts[cur][1][dt * 16 + l16][quad * 8];
        }
#pragma unroll
        for (int qt = 0; qt < 4; ++qt) {
#pragma unroll
            for (int kc = 0; kc < 2; ++kc) {
                bf16x8 ap = *(const bf16x8*)&Ps[w][qt * 16 + l16][kc * 32 + quad * 8];
#pragma unroll
                for (int dt = 0; dt < 4; ++dt)
                    acc[qt][dt] = __builtin_amdgcn_mfma_f32_16x16x32_bf16(ap, bv[dt][kc], acc[qt][dt], 0, 0, 0);
            }
        }
    }

#pragma unroll
    for (int qt = 0; qt < 4; ++qt) {
        vsum[qt] += __shfl_xor(vsum[qt], 16, 64);
        vsum[qt] += __shfl_xor(vsum[qt], 32, 64);
        if (quad == 0)
            vs[(rowbase + qw + qt * 16 + l16) * HEADS + h] = vsum[qt];
    }

#pragma unroll
    for (int qt = 0; qt < 4; ++qt)
#pragma unroll
        for (int dt = 0; dt < 4; ++dt)
#pragma unroll
            for (int r = 0; r < 4; ++r) {
                size_t row = rowbase + qw + qt * 16 + quad * 4 + r;
                Op[row * LATENT + h * HD + dt * 16 + l16] = acc[qt][dt][r];
            }
}

// ---------------------------------------------------------------------------
// Combine the two attention split-K partials -> bf16
// ---------------------------------------------------------------------------
__global__ __launch_bounds__(256) void attn_combine(const float* __restrict__ Op0,
                                                    const float* __restrict__ Op1,
                                                    const float* __restrict__ vs0,
                                                    const float* __restrict__ vs1,
                                                    bf16_t* __restrict__ O) {
    int row = blockIdx.x;
    int t = threadIdx.x;
    const float* a = Op0 + (size_t)row * LATENT;
    const float* bb = Op1 + (size_t)row * LATENT;
#pragma unroll
    for (int i = 0; i < 3; ++i) {
        int c = t + i * 256;
        int h = c >> 6;
        float denom = vs0[(size_t)row * HEADS + h] + vs1[(size_t)row * HEADS + h];
        O[(size_t)row * LATENT + c] = (bf16_t)((a[c] + bb[c]) / denom);
    }
}

// ---------------------------------------------------------------------------
// Fused residual + LayerNorm
// ---------------------------------------------------------------------------
__global__ __launch_bounds__(256) void ln_residual(const float* __restrict__ base,
                                                   const float* __restrict__ add,
                                                   const float* __restrict__ g,
                                                   const float* __restrict__ bta,
                                                   float* __restrict__ outf,
                                                   bf16_t* __restrict__ outb) {
    int row = blockIdx.x;
    const float* xr = base + (size_t)row * LATENT;
    const float* ar = add + (size_t)row * LATENT;
    int t = threadIdx.x;
    float v[3];
    float s = 0.f;
#pragma unroll
    for (int i = 0; i < 3; ++i) {
        v[i] = xr[t + i * 256] + ar[t + i * 256];
        s += v[i];
    }
    __shared__ float red[4];
#pragma unroll
    for (int off = 1; off < 64; off <<= 1) s += __shfl_xor(s, off, 64);
    if ((t & 63) == 0) red[t >> 6] = s;
    __syncthreads();
    float mu = (red[0] + red[1] + red[2] + red[3]) * (1.f / LATENT);
    float q = 0.f;
#pragma unroll
    for (int i = 0; i < 3; ++i) {
        float d = v[i] - mu;
        q += d * d;
    }
#pragma unroll
    for (int off = 1; off < 64; off <<= 1) q += __shfl_xor(q, off, 64);
    __syncthreads();
    if ((t & 63) == 0) red[t >> 6] = q;
    __syncthreads();
    float var = (red[0] + red[1] + red[2] + red[3]) * (1.f / LATENT);
    float rs = rsqrtf(var + 1e-5f);
#pragma unroll
    for (int i = 0; i < 3; ++i) {
        int cix = t + i * 256;
        float o = (v[i] - mu) * rs * g[cix] + bta[cix];
        outf[(size_t)row * LATENT + cix] = o;
        if (outb) outb[(size_t)row * LATENT + cix] = (bf16_t)o;
    }
}

// ---------------------------------------------------------------------------
extern "C" void kernel_launch(void* const* d_in, const int* in_sizes, int n_in,
                              void* d_out, int out_size, void* d_ws, size_t ws_size,
                              hipStream_t stream) {
    const float* x   = (const float*)d_in[0];
    const float* Wq  = (const float*)d_in[1];
    const float* bq  = (const float*)d_in[2];
    const float* Wk  = (const float*)d_in[3];
    const float* bk  = (const float*)d_in[4];
    const float* Wv  = (const float*)d_in[5];
    const float* bv  = (const float*)d_in[6];
    const float* Wo  = (const float*)d_in[7];
    const float* bo  = (const float*)d_in[8];
    const float* g1  = (const float*)d_in[9];
    const float* be1 = (const float*)d_in[10];
    const float* g2  = (const float*)d_in[11];
    const float* be2 = (const float*)d_in[12];
    const float* W1  = (const float*)d_in[13];
    const float* b1  = (const float*)d_in[14];
    const float* W2  = (const float*)d_in[15];
    const float* b2  = (const float*)d_in[16];
    float* out = (float*)d_out;

    char* ws = (char*)d_ws;
    size_t off = 0;
    auto alloc = [&](size_t bytes) {
        char* p = ws + off;
        off = (off + bytes + 255) & ~(size_t)255;
        return p;
    };
    bf16_t* xbf   = (bf16_t*)alloc((size_t)NTOK * LATENT * 2);
    bf16_t* Wcat  = (bf16_t*)alloc((size_t)3 * LATENT * LATENT * 2);
    bf16_t* Wobf  = (bf16_t*)alloc((size_t)LATENT * LATENT * 2);
    bf16_t* W1bf  = (bf16_t*)alloc((size_t)FFN_DIM * LATENT * 2);
    bf16_t* W2bf  = (bf16_t*)alloc((size_t)LATENT * FFN_DIM * 2);
    float*  bcat  = (float*)alloc((size_t)3 * LATENT * 4);
    bf16_t* QKV   = (bf16_t*)alloc((size_t)NTOK * 3 * LATENT * 2);
    bf16_t* attnO = (bf16_t*)alloc((size_t)NTOK * LATENT * 2);
    float*  tmpf  = (float*)alloc((size_t)NTOK * LATENT * 4);
    float*  y1f   = (float*)alloc((size_t)NTOK * LATENT * 4);
    bf16_t* y1bf  = (bf16_t*)alloc((size_t)NTOK * LATENT * 2);
    bf16_t* hbf   = (bf16_t*)alloc((size_t)NTOK * FFN_DIM * 2);
    float*  vsa   = (float*)alloc((size_t)NTOK * HEADS * 4);
    float*  vsb   = (float*)alloc((size_t)NTOK * HEADS * 4);
    bf16_t* Vtg   = (bf16_t*)hbf;   // alias: Vt lifetime disjoint from h
    float*  Oa    = tmpf;           // attn partial 0 (consumed before Wo writes tmpf)
    float*  Ob    = y1f;            // attn partial 1 (consumed before ln1 writes y1f)

    // 1. convert to bf16 + bias concat (seg 7)
    CvtDesc cd;
    cd.src[0] = x;   cd.dst[0] = xbf;                        cd.n4[0] = NTOK * LATENT / 4;
    cd.src[1] = Wq;  cd.dst[1] = Wcat;                       cd.n4[1] = LATENT * LATENT / 4;
    cd.src[2] = Wk;  cd.dst[2] = Wcat + LATENT * LATENT;     cd.n4[2] = LATENT * LATENT / 4;
    cd.src[3] = Wv;  cd.dst[3] = Wcat + 2 * LATENT * LATENT; cd.n4[3] = LATENT * LATENT / 4;
    cd.src[4] = Wo;  cd.dst[4] = Wobf;                       cd.n4[4] = LATENT * LATENT / 4;
    cd.src[5] = W1;  cd.dst[5] = W1bf;                       cd.n4[5] = FFN_DIM * LATENT / 4;
    cd.src[6] = W2;  cd.dst[6] = W2bf;                       cd.n4[6] = FFN_DIM * LATENT / 4;
    cd.bsrc[0] = bq; cd.bsrc[1] = bk; cd.bsrc[2] = bv;
    cd.bdst = bcat;
    {
        int maxn4 = NTOK * LATENT / 4;
        dim3 grid((maxn4 + 255) / 256, 8);
        cvt_f32_bf16<<<grid, 256, 0, stream>>>(cd);
    }

    // 2. fused QKV GEMM; Q region pre-scaled by C2 (EPI=3)
    gemm128<3, 128><<<dim3(NTOK / 128, 3 * LATENT / 128), 256, 0, stream>>>(
        xbf, Wcat, bcat, QKV, NTOK, 3 * LATENT, LATENT);

    // 2.5 V transpose
    v_transpose<<<dim3(SEQ / 64, 2 * HEADS), 256, 0, stream>>>(QKV, Vtg);

    // 3. attention: S^T scheme, 384 blocks x 4 waves, split-K x2
    attn_flash<<<dim3(2 * HEADS, SEQ / 256, 2), 256, 0, stream>>>(QKV, Vtg, Oa, Ob, vsa, vsb);

    // 3.5 combine partials -> bf16
    attn_combine<<<NTOK, 256, 0, stream>>>(Oa, Ob, vsa, vsb, attnO);

    // 4. output projection: 64x64 tiles, 768 balanced blocks
    gemm64<0><<<dim3(NTOK / 64, LATENT / 64), 128, 0, stream>>>(
        attnO, Wobf, bo, tmpf, NTOK, LATENT, LATENT);

    // 5. y1 = LN(x + proj)
    ln_residual<<<NTOK, 256, 0, stream>>>(x, tmpf, g1, be1, y1f, y1bf);

    // 6. h = gelu(y1 @ W1^T + b1)
    gemm128<2, 128><<<dim3(NTOK / 128, FFN_DIM / 128), 256, 0, stream>>>(
        y1bf, W1bf, b1, hbf, NTOK, FFN_DIM, LATENT);

    // 7. ffn = h @ W2^T + b2: 64x64 tiles, 768 balanced blocks
    gemm64<0><<<dim3(NTOK / 64, LATENT / 64), 128, 0, stream>>>(
        hbf, W2bf, b2, tmpf, NTOK, LATENT, FFN_DIM);

    // 8. out = LN(y1 + ffn)
    ln_residual<<<NTOK, 256, 0, stream>>>(y1f, tmpf, g2, be2, out, nullptr);
}

// Round 4
// 325.957 us; speedup vs baseline: 1.0538x; 1.0538x over previous
//
#include <hip/hip_runtime.h>
#include <hip/hip_bf16.h>
#include <cstddef>
#include <cstdint>

typedef __bf16 bf16_t;
typedef bf16_t bf16x8 __attribute__((ext_vector_type(8)));
typedef bf16_t bf16x4 __attribute__((ext_vector_type(4)));
typedef float f32x4 __attribute__((ext_vector_type(4)));

#define LATENT 768
#define FFN_DIM 3072
#define NTOK 4096      // 2*2048
#define SEQ 2048
#define HEADS 12
#define HD 64

#define C2F 0.18033688011112042f   // 0.125 * log2(e)

__device__ __forceinline__ void gload_lds16(const bf16_t* g, bf16_t* l) {
    __builtin_amdgcn_global_load_lds((const __attribute__((address_space(1))) void*)g,
                                     (__attribute__((address_space(3))) void*)l, 16, 0, 0);
}

// ---------------------------------------------------------------------------
// fp32 -> bf16 conversion, multi-segment; segment 7 = f32 bias concat (bq|bk|bv)
// ---------------------------------------------------------------------------
struct CvtDesc {
    const float* src[7];
    bf16_t* dst[7];
    int n4[7];
    const float* bsrc[3];
    float* bdst;
};

__global__ __launch_bounds__(256) void cvt_f32_bf16(CvtDesc d) {
    int seg = blockIdx.y;
    if (seg == 7) {   // bias concat: 3 blocks x 768 floats
        int which = blockIdx.x;
        if (which >= 3) return;
        int t = threadIdx.x;
#pragma unroll
        for (int i = 0; i < 3; ++i)
            d.bdst[which * LATENT + t + i * 256] = d.bsrc[which][t + i * 256];
        return;
    }
    int i = blockIdx.x * 256 + threadIdx.x;
    if (i >= d.n4[seg]) return;
    float4 v = ((const float4*)d.src[seg])[i];
    bf16x4 o;
    o[0] = (bf16_t)v.x; o[1] = (bf16_t)v.y; o[2] = (bf16_t)v.z; o[3] = (bf16_t)v.w;
    *(bf16x4*)&d.dst[seg][(size_t)i * 4] = o;
}

// ---------------------------------------------------------------------------
// GEMM 128xNT (NT=128), 256 thr = 4 waves, BK=32, global_load_lds x16,
// DOUBLE-BUFFERED K-loop (prefetch k+1 after barrier, compute on k).
// DIAGONAL TILE REMAP (round 3): with grid (Mt, Nt) and Mt % 8 == 0, the
// default mapping puts ALL same-m-tile blocks (A-row sharers; 18-24 of them)
// on ONE XCD (xcd = hwid%8 = bx%8) -> that L2 serializes 24 simultaneous
// requests for the same 16 A-lines every K-step. xtile = (bx+by) % Mt
// spreads A-sharers 2-3 per XCD while KEEPING the lockstep K-walk (lockstep
// is what makes L2 stream reuse work -- round-2's K-rotation proved that by
// thrashing gemm64's L2, FETCH 30->254 MB).
// EPI: 0 none->f32, 1 none->bf16, 2 exact-GELU->bf16,
//      3 bf16 with cols<LATENT scaled by C2F (Q pre-scale for exp2 softmax)
// ---------------------------------------------------------------------------
template<int EPI, int NT>
__global__ __launch_bounds__(256) void gemm128(const bf16_t* __restrict__ A,
                                               const bf16_t* __restrict__ B,
                                               const float* __restrict__ bias,
                                               void* __restrict__ Cv,
                                               int M, int N, int K) {
    __shared__ __align__(16) bf16_t As[2][128 * 32];
    __shared__ __align__(16) bf16_t Bs[2][NT * 32];
    int t = threadIdx.x;
    int w = t >> 6;
    int lane = t & 63, l16 = lane & 15, quad = lane >> 4;
    int xt = blockIdx.x + blockIdx.y;           // diagonal remap (by < Mt here)
    if (xt >= (int)gridDim.x) xt -= gridDim.x;
    int m0 = xt * 128, n0 = blockIdx.y * NT;
    int mrow0 = (w & 1) * 64, ncol0 = (w >> 1) * (NT / 2);
    const int NJ = NT / 32;

    f32x4 acc[4][NJ] = {};

    int srow = lane >> 2;
    int sseg = (lane & 3) * 8;

    auto stage = [&](int k0, int buf) {
        const bf16_t* Ag = A + (size_t)(m0 + w * 32 + srow) * K + k0 + sseg;
        gload_lds16(Ag,          &As[buf][(w * 32) * 32]);
        gload_lds16(Ag + 16 * K, &As[buf][(w * 32 + 16) * 32]);
        if (NT == 128) {
            const bf16_t* Bg = B + (size_t)(n0 + w * 32 + srow) * K + k0 + sseg;
            gload_lds16(Bg,          &Bs[buf][(w * 32) * 32]);
            gload_lds16(Bg + 16 * K, &Bs[buf][(w * 32 + 16) * 32]);
        } else {
            const bf16_t* Bg = B + (size_t)(n0 + w * 16 + srow) * K + k0 + sseg;
            gload_lds16(Bg, &Bs[buf][(w * 16) * 32]);
        }
    };

    int niter = K / 32;
    stage(0, 0);
    for (int kt = 0; kt < niter; ++kt) {
        __syncthreads();   // drains prev prefetch (vmcnt0) + readers of other buf
        int cur = kt & 1;
        if (kt + 1 < niter) stage((kt + 1) * 32, cur ^ 1);

        bf16x8 a[4], b[NJ];
#pragma unroll
        for (int i = 0; i < 4; ++i)
            a[i] = *(const bf16x8*)&As[cur][(mrow0 + i * 16 + l16) * 32 + quad * 8];
#pragma unroll
        for (int j = 0; j < NJ; ++j)
            b[j] = *(const bf16x8*)&Bs[cur][(ncol0 + j * 16 + l16) * 32 + quad * 8];
#pragma unroll
        for (int i = 0; i < 4; ++i)
#pragma unroll
            for (int j = 0; j < NJ; ++j)
                acc[i][j] = __builtin_amdgcn_mfma_f32_16x16x32_bf16(a[i], b[j], acc[i][j], 0, 0, 0);
    }

    float* Cf = (float*)Cv;
    bf16_t* Cb = (bf16_t*)Cv;
#pragma unroll
    for (int j = 0; j < NJ; ++j) {
        int col = n0 + ncol0 + j * 16 + l16;
        float bvv = bias[col];
#pragma unroll
        for (int i = 0; i < 4; ++i) {
            int row0 = m0 + mrow0 + i * 16 + quad * 4;
#pragma unroll
            for (int r = 0; r < 4; ++r) {
                float v = acc[i][j][r] + bvv;
                if (EPI == 2) v = 0.5f * v * (1.0f + erff(v * 0.70710678118654752f));
                if (EPI == 3) { if (col < LATENT) v *= C2F; }
                if (EPI == 0) Cf[(size_t)(row0 + r) * N + col] = v;
                else          Cb[(size_t)(row0 + r) * N + col] = (bf16_t)v;
            }
        }
    }
}

// ---------------------------------------------------------------------------
// GEMM 64x64 tile, 2 waves (128 thr), DOUBLE-BUFFERED K-loop, diagonal remap
// (lockstep K-walk restored -- round-2 rotation caused 8.5x FETCH blowup).
// For N=768: grid 64x12 = 768 blocks = 3/CU balanced.
// ---------------------------------------------------------------------------
template<int EPI>
__global__ __launch_bounds__(128) void gemm64(const bf16_t* __restrict__ A,
                                              const bf16_t* __restrict__ B,
                                              const float* __restrict__ bias,
                                              void* __restrict__ Cv,
                                              int M, int N, int K) {
    __shared__ __align__(16) bf16_t As[2][64 * 32];
    __shared__ __align__(16) bf16_t Bs[2][64 * 32];
    int t = threadIdx.x;
    int w = t >> 6;                  // 0..1
    int lane = t & 63, l16 = lane & 15, quad = lane >> 4;
    int xt = blockIdx.x + blockIdx.y;           // diagonal remap (by < Mt here)
    if (xt >= (int)gridDim.x) xt -= gridDim.x;
    int m0 = xt * 64, n0 = blockIdx.y * 64;

    f32x4 acc[2][4] = {};

    int srow = lane >> 2;
    int sseg = (lane & 3) * 8;

    auto stage = [&](int k0, int buf) {
        const bf16_t* Ag = A + (size_t)(m0 + w * 32 + srow) * K + k0 + sseg;
        gload_lds16(Ag,          &As[buf][(w * 32) * 32]);
        gload_lds16(Ag + 16 * K, &As[buf][(w * 32 + 16) * 32]);
        const bf16_t* Bg = B + (size_t)(n0 + w * 32 + srow) * K + k0 + sseg;
        gload_lds16(Bg,          &Bs[buf][(w * 32) * 32]);
        gload_lds16(Bg + 16 * K, &Bs[buf][(w * 32 + 16) * 32]);
    };

    int niter = K / 32;
    stage(0, 0);
    for (int kt = 0; kt < niter; ++kt) {
        __syncthreads();
        int cur = kt & 1;
        if (kt + 1 < niter) stage((kt + 1) * 32, cur ^ 1);

        bf16x8 a[2], b[4];
#pragma unroll
        for (int i = 0; i < 2; ++i)
            a[i] = *(const bf16x8*)&As[cur][(w * 32 + i * 16 + l16) * 32 + quad * 8];
#pragma unroll
        for (int j = 0; j < 4; ++j)
            b[j] = *(const bf16x8*)&Bs[cur][(j * 16 + l16) * 32 + quad * 8];
#pragma unroll
        for (int i = 0; i < 2; ++i)
#pragma unroll
            for (int j = 0; j < 4; ++j)
                acc[i][j] = __builtin_amdgcn_mfma_f32_16x16x32_bf16(a[i], b[j], acc[i][j], 0, 0, 0);
    }

    float* Cf = (float*)Cv;
    bf16_t* Cb = (bf16_t*)Cv;
#pragma unroll
    for (int j = 0; j < 4; ++j) {
        int col = n0 + j * 16 + l16;
        float bvv = bias[col];
#pragma unroll
        for (int i = 0; i < 2; ++i) {
            int row0 = m0 + w * 32 + i * 16 + quad * 4;
#pragma unroll
            for (int r = 0; r < 4; ++r) {
                float v = acc[i][j][r] + bvv;
                if (EPI == 2) v = 0.5f * v * (1.0f + erff(v * 0.70710678118654752f));
                if (EPI == 0) Cf[(size_t)(row0 + r) * N + col] = v;
                else          Cb[(size_t)(row0 + r) * N + col] = (bf16_t)v;
            }
        }
    }
}

// ---------------------------------------------------------------------------
// V transpose: QKV V-part [b, n, h, d] -> Vt [b, h, d, n]
// ---------------------------------------------------------------------------
__global__ __launch_bounds__(256) void v_transpose(const bf16_t* __restrict__ QKV,
                                                   bf16_t* __restrict__ Vt) {
    __shared__ bf16_t Ts[64][68];
    int t = threadIdx.x;
    int bh = blockIdx.y;
    int b = bh / HEADS, h = bh % HEADS;
    int n0 = blockIdx.x * 64;
    size_t rowbase = (size_t)b * SEQ;
    int r = t >> 3, seg = (t & 7) * 8;
#pragma unroll
    for (int i = 0; i < 2; ++i) {
        int rr = r + i * 32;
        *(bf16x8*)&Ts[rr][seg] =
            *(const bf16x8*)&QKV[(rowbase + n0 + rr) * (3 * LATENT) + 2 * LATENT + h * HD + seg];
    }
    __syncthreads();
#pragma unroll
    for (int i = 0; i < 2; ++i) {
        int d = r + i * 32;
        bf16x8 o;
#pragma unroll
        for (int jj = 0; jj < 8; ++jj) o[jj] = Ts[seg + jj][d];
        *(bf16x8*)&Vt[((size_t)bh * HD + d) * SEQ + n0 + seg] = o;
    }
}

// ---------------------------------------------------------------------------
// Flash attention (S^T formulation). Block = 4 waves x 64 q-rows = 256 q.
// P stored [q][key]: b64-packed writes, b128 A-frag reads. Q pre-scaled by C2.
// Double-buffered K/V staging with per-block K-tile ROTATION (kept from r2:
// the 8 q-blocks of one head otherwise stream identical K/V lines in
// lockstep; per-XCD KV working set 1.5 MB << 4 MB L2, so no thrash risk).
// Linear softmax (pure k-sum, rotation-safe); split-K x2 -> f32 partials.
// ---------------------------------------------------------------------------
__global__ __launch_bounds__(256) void attn_flash(const bf16_t* __restrict__ QKV,
                                                  const bf16_t* __restrict__ Vt,
                                                  float* __restrict__ Op0,
                                                  float* __restrict__ Op1,
                                                  float* __restrict__ vs0,
                                                  float* __restrict__ vs1) {
    __shared__ __align__(16) bf16_t Ks[2][2][64][32];    // [buf][d-chunk][key][d32]
    __shared__ __align__(16) bf16_t Vts[2][2][64][32];   // [buf][key-chunk][d][key32]
    __shared__ __align__(16) bf16_t Ps[4][64][72];       // [wave][q][key]

    int t = threadIdx.x;
    int w = t >> 6;
    int lane = t & 63, l16 = lane & 15, quad = lane >> 4;
    int bh = blockIdx.x;
    int b = bh / HEADS, h = bh % HEADS;
    int qblk = blockIdx.y * 256;
    int z = blockIdx.z;
    float* Op = z ? Op1 : Op0;
    float* vs = z ? vs1 : vs0;
    size_t rowbase = (size_t)b * SEQ;
    int kbase = z * (SEQ / 2);
    const int LD = 3 * LATENT;
    int qw = qblk + w * 64;

    bf16x8 bq[4][2];
#pragma unroll
    for (int qt = 0; qt < 4; ++qt) {
        const bf16_t* qrow = QKV + (rowbase + qw + qt * 16 + l16) * LD + h * HD;
        bq[qt][0] = *(const bf16x8*)&qrow[quad * 8];
        bq[qt][1] = *(const bf16x8*)&qrow[32 + quad * 8];
    }

    f32x4 acc[4][4] = {};    // [qt][dt]
    float vsum[4] = {};

    int srow = lane >> 2;
    int sseg = (lane & 3) * 8;

    const int NKT = SEQ / 128;           // 16 k-tiles of 64 keys per z-half
    int rot = (blockIdx.y * 7) & (NKT - 1);   // distinct per q-block (7 coprime 16)

    auto stage = [&](int tile, int buf) {
        int koff = kbase + tile * 64;
        const bf16_t* kg = QKV + (rowbase + koff + w * 16 + srow) * LD + LATENT + h * HD + sseg;
        gload_lds16(kg,      &Ks[buf][0][w * 16][0]);
        gload_lds16(kg + 32, &Ks[buf][1][w * 16][0]);
        const bf16_t* vg = Vt + ((size_t)bh * HD + w * 16 + srow) * SEQ + koff + sseg;
        gload_lds16(vg,      &Vts[buf][0][w * 16][0]);
        gload_lds16(vg + 32, &Vts[buf][1][w * 16][0]);
    };
    auto ktile = [&](int kt) { int kk = kt + rot; return kk >= NKT ? kk - NKT : kk; };

    stage(ktile(0), 0);

    for (int kt = 0; kt < NKT; ++kt) {
        __syncthreads();
        int cur = kt & 1;
        if (kt + 1 < NKT) stage(ktile(kt + 1), cur ^ 1);

#pragma unroll
        for (int skt = 0; skt < 4; ++skt) {
            bf16x8 ak0 = *(const bf16x8*)&Ks[cur][0][skt * 16 + l16][quad * 8];
            bf16x8 ak1 = *(const bf16x8*)&Ks[cur][1][skt * 16 + l16][quad * 8];
#pragma unroll
            for (int qt = 0; qt < 4; ++qt) {
                f32x4 s = {};
                s = __builtin_amdgcn_mfma_f32_16x16x32_bf16(ak0, bq[qt][0], s, 0, 0, 0);
                s = __builtin_amdgcn_mfma_f32_16x16x32_bf16(ak1, bq[qt][1], s, 0, 0, 0);
                bf16x4 pk;
#pragma unroll
                for (int r = 0; r < 4; ++r) {
                    float p = __builtin_amdgcn_exp2f(s[r]);
                    vsum[qt] += p;
                    pk[r] = (bf16_t)p;
                }
                *(bf16x4*)&Ps[w][qt * 16 + l16][skt * 16 + quad * 4] = pk;
            }
        }
        __threadfence_block();

        bf16x8 bv[4][2];
#pragma unroll
        for (int dt = 0; dt < 4; ++dt) {
            bv[dt][0] = *(const bf16x8*)&Vts[cur][0][dt * 16 + l16][quad * 8];
            bv[dt][1] = *(const bf16x8*)&Vts[cur][1][dt * 16 + l16][quad * 8];
        }
#pragma unroll
        for (int qt = 0; qt < 4; ++qt) {
#pragma unroll
            for (int kc = 0; kc < 2; ++kc) {
                bf16x8 ap = *(const bf16x8*)&Ps[w][qt * 16 + l16][kc * 32 + quad * 8];
#pragma unroll
                for (int dt = 0; dt < 4; ++dt)
                    acc[qt][dt] = __builtin_amdgcn_mfma_f32_16x16x32_bf16(ap, bv[dt][kc], acc[qt][dt], 0, 0, 0);
            }
        }
    }

#pragma unroll
    for (int qt = 0; qt < 4; ++qt) {
        vsum[qt] += __shfl_xor(vsum[qt], 16, 64);
        vsum[qt] += __shfl_xor(vsum[qt], 32, 64);
        if (quad == 0)
            vs[(rowbase + qw + qt * 16 + l16) * HEADS + h] = vsum[qt];
    }

#pragma unroll
    for (int qt = 0; qt < 4; ++qt)
#pragma unroll
        for (int dt = 0; dt < 4; ++dt)
#pragma unroll
            for (int r = 0; r < 4; ++r) {
                size_t row = rowbase + qw + qt * 16 + quad * 4 + r;
                Op[row * LATENT + h * HD + dt * 16 + l16] = acc[qt][dt][r];
            }
}

// ---------------------------------------------------------------------------
// Combine the two attention split-K partials -> bf16
// ---------------------------------------------------------------------------
__global__ __launch_bounds__(256) void attn_combine(const float* __restrict__ Op0,
                                                    const float* __restrict__ Op1,
                                                    const float* __restrict__ vs0,
                                                    const float* __restrict__ vs1,
                                                    bf16_t* __restrict__ O) {
    int row = blockIdx.x;
    int t = threadIdx.x;
    const float* a = Op0 + (size_t)row * LATENT;
    const float* bb = Op1 + (size_t)row * LATENT;
#pragma unroll
    for (int i = 0; i < 3; ++i) {
        int c = t + i * 256;
        int h = c >> 6;
        float denom = vs0[(size_t)row * HEADS + h] + vs1[(size_t)row * HEADS + h];
        O[(size_t)row * LATENT + c] = (bf16_t)((a[c] + bb[c]) / denom);
    }
}

// ---------------------------------------------------------------------------
// Fused residual + LayerNorm
// ---------------------------------------------------------------------------
__global__ __launch_bounds__(256) void ln_residual(const float* __restrict__ base,
                                                   const float* __restrict__ add,
                                                   const float* __restrict__ g,
                                                   const float* __restrict__ bta,
                                                   float* __restrict__ outf,
                                                   bf16_t* __restrict__ outb) {
    int row = blockIdx.x;
    const float* xr = base + (size_t)row * LATENT;
    const float* ar = add + (size_t)row * LATENT;
    int t = threadIdx.x;
    float v[3];
    float s = 0.f;
#pragma unroll
    for (int i = 0; i < 3; ++i) {
        v[i] = xr[t + i * 256] + ar[t + i * 256];
        s += v[i];
    }
    __shared__ float red[4];
#pragma unroll
    for (int off = 1; off < 64; off <<= 1) s += __shfl_xor(s, off, 64);
    if ((t & 63) == 0) red[t >> 6] = s;
    __syncthreads();
    float mu = (red[0] + red[1] + red[2] + red[3]) * (1.f / LATENT);
    float q = 0.f;
#pragma unroll
    for (int i = 0; i < 3; ++i) {
        float d = v[i] - mu;
        q += d * d;
    }
#pragma unroll
    for (int off = 1; off < 64; off <<= 1) q += __shfl_xor(q, off, 64);
    __syncthreads();
    if ((t & 63) == 0) red[t >> 6] = q;
    __syncthreads();
    float var = (red[0] + red[1] + red[2] + red[3]) * (1.f / LATENT);
    float rs = rsqrtf(var + 1e-5f);
#pragma unroll
    for (int i = 0; i < 3; ++i) {
        int cix = t + i * 256;
        float o = (v[i] - mu) * rs * g[cix] + bta[cix];
        outf[(size_t)row * LATENT + cix] = o;
        if (outb) outb[(size_t)row * LATENT + cix] = (bf16_t)o;
    }
}

// ---------------------------------------------------------------------------
extern "C" void kernel_launch(void* const* d_in, const int* in_sizes, int n_in,
                              void* d_out, int out_size, void* d_ws, size_t ws_size,
                              hipStream_t stream) {
    const float* x   = (const float*)d_in[0];
    const float* Wq  = (const float*)d_in[1];
    const float* bq  = (const float*)d_in[2];
    const float* Wk  = (const float*)d_in[3];
    const float* bk  = (const float*)d_in[4];
    const float* Wv  = (const float*)d_in[5];
    const float* bv  = (const float*)d_in[6];
    const float* Wo  = (const float*)d_in[7];
    const float* bo  = (const float*)d_in[8];
    const float* g1  = (const float*)d_in[9];
    const float* be1 = (const float*)d_in[10];
    const float* g2  = (const float*)d_in[11];
    const float* be2 = (const float*)d_in[12];
    const float* W1  = (const float*)d_in[13];
    const float* b1  = (const float*)d_in[14];
    const float* W2  = (const float*)d_in[15];
    const float* b2  = (const float*)d_in[16];
    float* out = (float*)d_out;

    char* ws = (char*)d_ws;
    size_t off = 0;
    auto alloc = [&](size_t bytes) {
        char* p = ws + off;
        off = (off + bytes + 255) & ~(size_t)255;
        return p;
    };
    bf16_t* xbf   = (bf16_t*)alloc((size_t)NTOK * LATENT * 2);
    bf16_t* Wcat  = (bf16_t*)alloc((size_t)3 * LATENT * LATENT * 2);
    bf16_t* Wobf  = (bf16_t*)alloc((size_t)LATENT * LATENT * 2);
    bf16_t* W1bf  = (bf16_t*)alloc((size_t)FFN_DIM * LATENT * 2);
    bf16_t* W2bf  = (bf16_t*)alloc((size_t)LATENT * FFN_DIM * 2);
    float*  bcat  = (float*)alloc((size_t)3 * LATENT * 4);
    bf16_t* QKV   = (bf16_t*)alloc((size_t)NTOK * 3 * LATENT * 2);
    bf16_t* attnO = (bf16_t*)alloc((size_t)NTOK * LATENT * 2);
    float*  tmpf  = (float*)alloc((size_t)NTOK * LATENT * 4);
    float*  y1f   = (float*)alloc((size_t)NTOK * LATENT * 4);
    bf16_t* y1bf  = (bf16_t*)alloc((size_t)NTOK * LATENT * 2);
    bf16_t* hbf   = (bf16_t*)alloc((size_t)NTOK * FFN_DIM * 2);
    float*  vsa   = (float*)alloc((size_t)NTOK * HEADS * 4);
    float*  vsb   = (float*)alloc((size_t)NTOK * HEADS * 4);
    bf16_t* Vtg   = (bf16_t*)hbf;   // alias: Vt lifetime disjoint from h
    float*  Oa    = tmpf;           // attn partial 0 (consumed before Wo writes tmpf)
    float*  Ob    = y1f;            // attn partial 1 (consumed before ln1 writes y1f)

    // 1. convert to bf16 + bias concat (seg 7)
    CvtDesc cd;
    cd.src[0] = x;   cd.dst[0] = xbf;                        cd.n4[0] = NTOK * LATENT / 4;
    cd.src[1] = Wq;  cd.dst[1] = Wcat;                       cd.n4[1] = LATENT * LATENT / 4;
    cd.src[2] = Wk;  cd.dst[2] = Wcat + LATENT * LATENT;     cd.n4[2] = LATENT * LATENT / 4;
    cd.src[3] = Wv;  cd.dst[3] = Wcat + 2 * LATENT * LATENT; cd.n4[3] = LATENT * LATENT / 4;
    cd.src[4] = Wo;  cd.dst[4] = Wobf;                       cd.n4[4] = LATENT * LATENT / 4;
    cd.src[5] = W1;  cd.dst[5] = W1bf;                       cd.n4[5] = FFN_DIM * LATENT / 4;
    cd.src[6] = W2;  cd.dst[6] = W2bf;                       cd.n4[6] = FFN_DIM * LATENT / 4;
    cd.bsrc[0] = bq; cd.bsrc[1] = bk; cd.bsrc[2] = bv;
    cd.bdst = bcat;
    {
        int maxn4 = NTOK * LATENT / 4;
        dim3 grid((maxn4 + 255) / 256, 8);
        cvt_f32_bf16<<<grid, 256, 0, stream>>>(cd);
    }

    // 2. fused QKV GEMM; Q region pre-scaled by C2 (EPI=3)
    gemm128<3, 128><<<dim3(NTOK / 128, 3 * LATENT / 128), 256, 0, stream>>>(
        xbf, Wcat, bcat, QKV, NTOK, 3 * LATENT, LATENT);

    // 2.5 V transpose
    v_transpose<<<dim3(SEQ / 64, 2 * HEADS), 256, 0, stream>>>(QKV, Vtg);

    // 3. attention: S^T scheme, 384 blocks x 4 waves, split-K x2
    attn_flash<<<dim3(2 * HEADS, SEQ / 256, 2), 256, 0, stream>>>(QKV, Vtg, Oa, Ob, vsa, vsb);

    // 3.5 combine partials -> bf16
    attn_combine<<<NTOK, 256, 0, stream>>>(Oa, Ob, vsa, vsb, attnO);

    // 4. output projection: 64x64 tiles, 768 balanced blocks
    gemm64<0><<<dim3(NTOK / 64, LATENT / 64), 128, 0, stream>>>(
        attnO, Wobf, bo, tmpf, NTOK, LATENT, LATENT);

    // 5. y1 = LN(x + proj)
    ln_residual<<<NTOK, 256, 0, stream>>>(x, tmpf, g1, be1, y1f, y1bf);

    // 6. h = gelu(y1 @ W1^T + b1)
    gemm128<2, 128><<<dim3(NTOK / 128, FFN_DIM / 128), 256, 0, stream>>>(
        y1bf, W1bf, b1, hbf, NTOK, FFN_DIM, LATENT);

    // 7. ffn = h @ W2^T + b2: 64x64 tiles, 768 balanced blocks
    gemm64<0><<<dim3(NTOK / 64, LATENT / 64), 128, 0, stream>>>(
        hbf, W2bf, b2, tmpf, NTOK, LATENT, FFN_DIM);

    // 8. out = LN(y1 + ffn)
    ln_residual<<<NTOK, 256, 0, stream>>>(y1f, tmpf, g2, be2, out, nullptr);
}

// Round 5
// 311.027 us; speedup vs baseline: 1.1044x; 1.0480x over previous
//
#include <hip/hip_runtime.h>
#include <hip/hip_bf16.h>
#include <cstddef>
#include <cstdint>

typedef __bf16 bf16_t;
typedef bf16_t bf16x8 __attribute__((ext_vector_type(8)));
typedef bf16_t bf16x4 __attribute__((ext_vector_type(4)));
typedef float f32x4 __attribute__((ext_vector_type(4)));

#define LATENT 768
#define FFN_DIM 3072
#define NTOK 4096      // 2*2048
#define SEQ 2048
#define HEADS 12
#define HD 64

#define C2F 0.18033688011112042f   // 0.125 * log2(e)

__device__ __forceinline__ void gload_lds16(const bf16_t* g, bf16_t* l) {
    __builtin_amdgcn_global_load_lds((const __attribute__((address_space(1))) void*)g,
                                     (__attribute__((address_space(3))) void*)l, 16, 0, 0);
}

// ---------------------------------------------------------------------------
// fp32 -> bf16 conversion, multi-segment; segment 7 = f32 bias concat (bq|bk|bv)
// ---------------------------------------------------------------------------
struct CvtDesc {
    const float* src[7];
    bf16_t* dst[7];
    int n4[7];
    const float* bsrc[3];
    float* bdst;
};

__global__ __launch_bounds__(256) void cvt_f32_bf16(CvtDesc d) {
    int seg = blockIdx.y;
    if (seg == 7) {   // bias concat: 3 blocks x 768 floats
        int which = blockIdx.x;
        if (which >= 3) return;
        int t = threadIdx.x;
#pragma unroll
        for (int i = 0; i < 3; ++i)
            d.bdst[which * LATENT + t + i * 256] = d.bsrc[which][t + i * 256];
        return;
    }
    int i = blockIdx.x * 256 + threadIdx.x;
    if (i >= d.n4[seg]) return;
    float4 v = ((const float4*)d.src[seg])[i];
    bf16x4 o;
    o[0] = (bf16_t)v.x; o[1] = (bf16_t)v.y; o[2] = (bf16_t)v.z; o[3] = (bf16_t)v.w;
    *(bf16x4*)&d.dst[seg][(size_t)i * 4] = o;
}

// ---------------------------------------------------------------------------
// GEMM 128xNT (NT=128), 256 thr = 4 waves, BK=32, global_load_lds x16,
// DOUBLE-BUFFERED K-loop (prefetch k+1 after barrier, compute on k).
// DIAGONAL TILE REMAP — gemm128 ONLY (r4 evidence): with grid (Mt,Nt),
// Mt%8==0, identity mapping puts ALL 18-24 same-m-tile blocks (A-row
// sharers) on ONE XCD -> that L2 serializes their identical line bursts
// each K-step (gemm128 was 101us, MfmaUtil 7%). xt=(bx+by)%Mt spreads
// A-sharers 2-3/XCD; gemm128 dropped out of top-5 (<57us) in r4.
// NOTE: do NOT apply to gemm64 — r4 showed the same remap there QUADRUPLES
// per-XCD working set (FETCH 30->117MB) because bx%8 concentration doubles
// as per-XCD A-partitioning, which gemm64's 12-sharer shape needs.
// EPI: 0 none->f32, 1 none->bf16, 2 exact-GELU->bf16,
//      3 bf16 with cols<LATENT scaled by C2F (Q pre-scale for exp2 softmax)
// ---------------------------------------------------------------------------
template<int EPI, int NT>
__global__ __launch_bounds__(256) void gemm128(const bf16_t* __restrict__ A,
                                               const bf16_t* __restrict__ B,
                                               const float* __restrict__ bias,
                                               void* __restrict__ Cv,
                                               int M, int N, int K) {
    __shared__ __align__(16) bf16_t As[2][128 * 32];
    __shared__ __align__(16) bf16_t Bs[2][NT * 32];
    int t = threadIdx.x;
    int w = t >> 6;
    int lane = t & 63, l16 = lane & 15, quad = lane >> 4;
    int xt = blockIdx.x + blockIdx.y;           // diagonal remap (by < Mt here)
    if (xt >= (int)gridDim.x) xt -= gridDim.x;
    int m0 = xt * 128, n0 = blockIdx.y * NT;
    int mrow0 = (w & 1) * 64, ncol0 = (w >> 1) * (NT / 2);
    const int NJ = NT / 32;

    f32x4 acc[4][NJ] = {};

    int srow = lane >> 2;
    int sseg = (lane & 3) * 8;

    auto stage = [&](int k0, int buf) {
        const bf16_t* Ag = A + (size_t)(m0 + w * 32 + srow) * K + k0 + sseg;
        gload_lds16(Ag,          &As[buf][(w * 32) * 32]);
        gload_lds16(Ag + 16 * K, &As[buf][(w * 32 + 16) * 32]);
        if (NT == 128) {
            const bf16_t* Bg = B + (size_t)(n0 + w * 32 + srow) * K + k0 + sseg;
            gload_lds16(Bg,          &Bs[buf][(w * 32) * 32]);
            gload_lds16(Bg + 16 * K, &Bs[buf][(w * 32 + 16) * 32]);
        } else {
            const bf16_t* Bg = B + (size_t)(n0 + w * 16 + srow) * K + k0 + sseg;
            gload_lds16(Bg, &Bs[buf][(w * 16) * 32]);
        }
    };

    int niter = K / 32;
    stage(0, 0);
    for (int kt = 0; kt < niter; ++kt) {
        __syncthreads();   // drains prev prefetch (vmcnt0) + readers of other buf
        int cur = kt & 1;
        if (kt + 1 < niter) stage((kt + 1) * 32, cur ^ 1);

        bf16x8 a[4], b[NJ];
#pragma unroll
        for (int i = 0; i < 4; ++i)
            a[i] = *(const bf16x8*)&As[cur][(mrow0 + i * 16 + l16) * 32 + quad * 8];
#pragma unroll
        for (int j = 0; j < NJ; ++j)
            b[j] = *(const bf16x8*)&Bs[cur][(ncol0 + j * 16 + l16) * 32 + quad * 8];
#pragma unroll
        for (int i = 0; i < 4; ++i)
#pragma unroll
            for (int j = 0; j < NJ; ++j)
                acc[i][j] = __builtin_amdgcn_mfma_f32_16x16x32_bf16(a[i], b[j], acc[i][j], 0, 0, 0);
    }

    float* Cf = (float*)Cv;
    bf16_t* Cb = (bf16_t*)Cv;
#pragma unroll
    for (int j = 0; j < NJ; ++j) {
        int col = n0 + ncol0 + j * 16 + l16;
        float bvv = bias[col];
#pragma unroll
        for (int i = 0; i < 4; ++i) {
            int row0 = m0 + mrow0 + i * 16 + quad * 4;
#pragma unroll
            for (int r = 0; r < 4; ++r) {
                float v = acc[i][j][r] + bvv;
                if (EPI == 2) v = 0.5f * v * (1.0f + erff(v * 0.70710678118654752f));
                if (EPI == 3) { if (col < LATENT) v *= C2F; }
                if (EPI == 0) Cf[(size_t)(row0 + r) * N + col] = v;
                else          Cb[(size_t)(row0 + r) * N + col] = (bf16_t)v;
            }
        }
    }
}

// ---------------------------------------------------------------------------
// GEMM 64x64 tile, 2 waves (128 thr), DOUBLE-BUFFERED K-loop.
// IDENTITY tile mapping (reverted r4's diagonal remap): bx%8 concentration
// IS per-XCD A-partitioning here (working set A/8+B = 7.8MB fits L2);
// diagonal remap made every XCD touch ~all of A -> FETCH 30->117MB, 58us.
// For N=768: grid 64x12 = 768 blocks = 3/CU balanced.
// ---------------------------------------------------------------------------
template<int EPI>
__global__ __launch_bounds__(128) void gemm64(const bf16_t* __restrict__ A,
                                              const bf16_t* __restrict__ B,
                                              const float* __restrict__ bias,
                                              void* __restrict__ Cv,
                                              int M, int N, int K) {
    __shared__ __align__(16) bf16_t As[2][64 * 32];
    __shared__ __align__(16) bf16_t Bs[2][64 * 32];
    int t = threadIdx.x;
    int w = t >> 6;                  // 0..1
    int lane = t & 63, l16 = lane & 15, quad = lane >> 4;
    int m0 = blockIdx.x * 64, n0 = blockIdx.y * 64;

    f32x4 acc[2][4] = {};

    int srow = lane >> 2;
    int sseg = (lane & 3) * 8;

    auto stage = [&](int k0, int buf) {
        const bf16_t* Ag = A + (size_t)(m0 + w * 32 + srow) * K + k0 + sseg;
        gload_lds16(Ag,          &As[buf][(w * 32) * 32]);
        gload_lds16(Ag + 16 * K, &As[buf][(w * 32 + 16) * 32]);
        const bf16_t* Bg = B + (size_t)(n0 + w * 32 + srow) * K + k0 + sseg;
        gload_lds16(Bg,          &Bs[buf][(w * 32) * 32]);
        gload_lds16(Bg + 16 * K, &Bs[buf][(w * 32 + 16) * 32]);
    };

    int niter = K / 32;
    stage(0, 0);
    for (int kt = 0; kt < niter; ++kt) {
        __syncthreads();
        int cur = kt & 1;
        if (kt + 1 < niter) stage((kt + 1) * 32, cur ^ 1);

        bf16x8 a[2], b[4];
#pragma unroll
        for (int i = 0; i < 2; ++i)
            a[i] = *(const bf16x8*)&As[cur][(w * 32 + i * 16 + l16) * 32 + quad * 8];
#pragma unroll
        for (int j = 0; j < 4; ++j)
            b[j] = *(const bf16x8*)&Bs[cur][(j * 16 + l16) * 32 + quad * 8];
#pragma unroll
        for (int i = 0; i < 2; ++i)
#pragma unroll
            for (int j = 0; j < 4; ++j)
                acc[i][j] = __builtin_amdgcn_mfma_f32_16x16x32_bf16(a[i], b[j], acc[i][j], 0, 0, 0);
    }

    float* Cf = (float*)Cv;
    bf16_t* Cb = (bf16_t*)Cv;
#pragma unroll
    for (int j = 0; j < 4; ++j) {
        int col = n0 + j * 16 + l16;
        float bvv = bias[col];
#pragma unroll
        for (int i = 0; i < 2; ++i) {
            int row0 = m0 + w * 32 + i * 16 + quad * 4;
#pragma unroll
            for (int r = 0; r < 4; ++r) {
                float v = acc[i][j][r] + bvv;
                if (EPI == 2) v = 0.5f * v * (1.0f + erff(v * 0.70710678118654752f));
                if (EPI == 0) Cf[(size_t)(row0 + r) * N + col] = v;
                else          Cb[(size_t)(row0 + r) * N + col] = (bf16_t)v;
            }
        }
    }
}

// ---------------------------------------------------------------------------
// V transpose: QKV V-part [b, n, h, d] -> Vt [b, h, d, n]
// ---------------------------------------------------------------------------
__global__ __launch_bounds__(256) void v_transpose(const bf16_t* __restrict__ QKV,
                                                   bf16_t* __restrict__ Vt) {
    __shared__ bf16_t Ts[64][68];
    int t = threadIdx.x;
    int bh = blockIdx.y;
    int b = bh / HEADS, h = bh % HEADS;
    int n0 = blockIdx.x * 64;
    size_t rowbase = (size_t)b * SEQ;
    int r = t >> 3, seg = (t & 7) * 8;
#pragma unroll
    for (int i = 0; i < 2; ++i) {
        int rr = r + i * 32;
        *(bf16x8*)&Ts[rr][seg] =
            *(const bf16x8*)&QKV[(rowbase + n0 + rr) * (3 * LATENT) + 2 * LATENT + h * HD + seg];
    }
    __syncthreads();
#pragma unroll
    for (int i = 0; i < 2; ++i) {
        int d = r + i * 32;
        bf16x8 o;
#pragma unroll
        for (int jj = 0; jj < 8; ++jj) o[jj] = Ts[seg + jj][d];
        *(bf16x8*)&Vt[((size_t)bh * HD + d) * SEQ + n0 + seg] = o;
    }
}

// ---------------------------------------------------------------------------
// Flash attention (S^T formulation). Block = 4 waves x 64 q-rows = 256 q.
// P stored [q][key]: b64-packed writes, b128 A-frag reads. Q pre-scaled by C2.
// Double-buffered K/V staging (baseline sequential K-walk; the r2 rotation
// was never isolated and rotation only ever measured harmful elsewhere).
// Linear softmax; split-K x2 -> f32 partials.
// ---------------------------------------------------------------------------
__global__ __launch_bounds__(256) void attn_flash(const bf16_t* __restrict__ QKV,
                                                  const bf16_t* __restrict__ Vt,
                                                  float* __restrict__ Op0,
                                                  float* __restrict__ Op1,
                                                  float* __restrict__ vs0,
                                                  float* __restrict__ vs1) {
    __shared__ __align__(16) bf16_t Ks[2][2][64][32];    // [buf][d-chunk][key][d32]
    __shared__ __align__(16) bf16_t Vts[2][2][64][32];   // [buf][key-chunk][d][key32]
    __shared__ __align__(16) bf16_t Ps[4][64][72];       // [wave][q][key]

    int t = threadIdx.x;
    int w = t >> 6;
    int lane = t & 63, l16 = lane & 15, quad = lane >> 4;
    int bh = blockIdx.x;
    int b = bh / HEADS, h = bh % HEADS;
    int qblk = blockIdx.y * 256;
    int z = blockIdx.z;
    float* Op = z ? Op1 : Op0;
    float* vs = z ? vs1 : vs0;
    size_t rowbase = (size_t)b * SEQ;
    int kbase = z * (SEQ / 2);
    const int LD = 3 * LATENT;
    int qw = qblk + w * 64;

    bf16x8 bq[4][2];
#pragma unroll
    for (int qt = 0; qt < 4; ++qt) {
        const bf16_t* qrow = QKV + (rowbase + qw + qt * 16 + l16) * LD + h * HD;
        bq[qt][0] = *(const bf16x8*)&qrow[quad * 8];
        bq[qt][1] = *(const bf16x8*)&qrow[32 + quad * 8];
    }

    f32x4 acc[4][4] = {};    // [qt][dt]
    float vsum[4] = {};

    int srow = lane >> 2;
    int sseg = (lane & 3) * 8;

    {
        const bf16_t* kg = QKV + (rowbase + kbase + w * 16 + srow) * LD + LATENT + h * HD + sseg;
        gload_lds16(kg,      &Ks[0][0][w * 16][0]);
        gload_lds16(kg + 32, &Ks[0][1][w * 16][0]);
        const bf16_t* vg = Vt + ((size_t)bh * HD + w * 16 + srow) * SEQ + kbase + sseg;
        gload_lds16(vg,      &Vts[0][0][w * 16][0]);
        gload_lds16(vg + 32, &Vts[0][1][w * 16][0]);
    }

    for (int kt = 0; kt < SEQ / 128; ++kt) {
        __syncthreads();
        int cur = kt & 1;
        if (kt + 1 < SEQ / 128) {
            int nxt = cur ^ 1;
            int koff = kbase + (kt + 1) * 64;
            const bf16_t* kg = QKV + (rowbase + koff + w * 16 + srow) * LD + LATENT + h * HD + sseg;
            gload_lds16(kg,      &Ks[nxt][0][w * 16][0]);
            gload_lds16(kg + 32, &Ks[nxt][1][w * 16][0]);
            const bf16_t* vg = Vt + ((size_t)bh * HD + w * 16 + srow) * SEQ + koff + sseg;
            gload_lds16(vg,      &Vts[nxt][0][w * 16][0]);
            gload_lds16(vg + 32, &Vts[nxt][1][w * 16][0]);
        }

#pragma unroll
        for (int skt = 0; skt < 4; ++skt) {
            bf16x8 ak0 = *(const bf16x8*)&Ks[cur][0][skt * 16 + l16][quad * 8];
            bf16x8 ak1 = *(const bf16x8*)&Ks[cur][1][skt * 16 + l16][quad * 8];
#pragma unroll
            for (int qt = 0; qt < 4; ++qt) {
                f32x4 s = {};
                s = __builtin_amdgcn_mfma_f32_16x16x32_bf16(ak0, bq[qt][0], s, 0, 0, 0);
                s = __builtin_amdgcn_mfma_f32_16x16x32_bf16(ak1, bq[qt][1], s, 0, 0, 0);
                bf16x4 pk;
#pragma unroll
                for (int r = 0; r < 4; ++r) {
                    float p = __builtin_amdgcn_exp2f(s[r]);
                    vsum[qt] += p;
                    pk[r] = (bf16_t)p;
                }
                *(bf16x4*)&Ps[w][qt * 16 + l16][skt * 16 + quad * 4] = pk;
            }
        }
        __threadfence_block();

        bf16x8 bv[4][2];
#pragma unroll
        for (int dt = 0; dt < 4; ++dt) {
            bv[dt][0] = *(const bf16x8*)&Vts[cur][0][dt * 16 + l16][quad * 8];
            bv[dt][1] = *(const bf16x8*)&Vts[cur][1][dt * 16 + l16][quad * 8];
        }
#pragma unroll
        for (int qt = 0; qt < 4; ++qt) {
#pragma unroll
            for (int kc = 0; kc < 2; ++kc) {
                bf16x8 ap = *(const bf16x8*)&Ps[w][qt * 16 + l16][kc * 32 + quad * 8];
#pragma unroll
                for (int dt = 0; dt < 4; ++dt)
                    acc[qt][dt] = __builtin_amdgcn_mfma_f32_16x16x32_bf16(ap, bv[dt][kc], acc[qt][dt], 0, 0, 0);
            }
        }
    }

#pragma unroll
    for (int qt = 0; qt < 4; ++qt) {
        vsum[qt] += __shfl_xor(vsum[qt], 16, 64);
        vsum[qt] += __shfl_xor(vsum[qt], 32, 64);
        if (quad == 0)
            vs[(rowbase + qw + qt * 16 + l16) * HEADS + h] = vsum[qt];
    }

#pragma unroll
    for (int qt = 0; qt < 4; ++qt)
#pragma unroll
        for (int dt = 0; dt < 4; ++dt)
#pragma unroll
            for (int r = 0; r < 4; ++r) {
                size_t row = rowbase + qw + qt * 16 + quad * 4 + r;
                Op[row * LATENT + h * HD + dt * 16 + l16] = acc[qt][dt][r];
            }
}

// ---------------------------------------------------------------------------
// Combine the two attention split-K partials -> bf16
// ---------------------------------------------------------------------------
__global__ __launch_bounds__(256) void attn_combine(const float* __restrict__ Op0,
                                                    const float* __restrict__ Op1,
                                                    const float* __restrict__ vs0,
                                                    const float* __restrict__ vs1,
                                                    bf16_t* __restrict__ O) {
    int row = blockIdx.x;
    int t = threadIdx.x;
    const float* a = Op0 + (size_t)row * LATENT;
    const float* bb = Op1 + (size_t)row * LATENT;
#pragma unroll
    for (int i = 0; i < 3; ++i) {
        int c = t + i * 256;
        int h = c >> 6;
        float denom = vs0[(size_t)row * HEADS + h] + vs1[(size_t)row * HEADS + h];
        O[(size_t)row * LATENT + c] = (bf16_t)((a[c] + bb[c]) / denom);
    }
}

// ---------------------------------------------------------------------------
// Fused residual + LayerNorm
// ---------------------------------------------------------------------------
__global__ __launch_bounds__(256) void ln_residual(const float* __restrict__ base,
                                                   const float* __restrict__ add,
                                                   const float* __restrict__ g,
                                                   const float* __restrict__ bta,
                                                   float* __restrict__ outf,
                                                   bf16_t* __restrict__ outb) {
    int row = blockIdx.x;
    const float* xr = base + (size_t)row * LATENT;
    const float* ar = add + (size_t)row * LATENT;
    int t = threadIdx.x;
    float v[3];
    float s = 0.f;
#pragma unroll
    for (int i = 0; i < 3; ++i) {
        v[i] = xr[t + i * 256] + ar[t + i * 256];
        s += v[i];
    }
    __shared__ float red[4];
#pragma unroll
    for (int off = 1; off < 64; off <<= 1) s += __shfl_xor(s, off, 64);
    if ((t & 63) == 0) red[t >> 6] = s;
    __syncthreads();
    float mu = (red[0] + red[1] + red[2] + red[3]) * (1.f / LATENT);
    float q = 0.f;
#pragma unroll
    for (int i = 0; i < 3; ++i) {
        float d = v[i] - mu;
        q += d * d;
    }
#pragma unroll
    for (int off = 1; off < 64; off <<= 1) q += __shfl_xor(q, off, 64);
    __syncthreads();
    if ((t & 63) == 0) red[t >> 6] = q;
    __syncthreads();
    float var = (red[0] + red[1] + red[2] + red[3]) * (1.f / LATENT);
    float rs = rsqrtf(var + 1e-5f);
#pragma unroll
    for (int i = 0; i < 3; ++i) {
        int cix = t + i * 256;
        float o = (v[i] - mu) * rs * g[cix] + bta[cix];
        outf[(size_t)row * LATENT + cix] = o;
        if (outb) outb[(size_t)row * LATENT + cix] = (bf16_t)o;
    }
}

// ---------------------------------------------------------------------------
extern "C" void kernel_launch(void* const* d_in, const int* in_sizes, int n_in,
                              void* d_out, int out_size, void* d_ws, size_t ws_size,
                              hipStream_t stream) {
    const float* x   = (const float*)d_in[0];
    const float* Wq  = (const float*)d_in[1];
    const float* bq  = (const float*)d_in[2];
    const float* Wk  = (const float*)d_in[3];
    const float* bk  = (const float*)d_in[4];
    const float* Wv  = (const float*)d_in[5];
    const float* bv  = (const float*)d_in[6];
    const float* Wo  = (const float*)d_in[7];
    const float* bo  = (const float*)d_in[8];
    const float* g1  = (const float*)d_in[9];
    const float* be1 = (const float*)d_in[10];
    const float* g2  = (const float*)d_in[11];
    const float* be2 = (const float*)d_in[12];
    const float* W1  = (const float*)d_in[13];
    const float* b1  = (const float*)d_in[14];
    const float* W2  = (const float*)d_in[15];
    const float* b2  = (const float*)d_in[16];
    float* out = (float*)d_out;

    char* ws = (char*)d_ws;
    size_t off = 0;
    auto alloc = [&](size_t bytes) {
        char* p = ws + off;
        off = (off + bytes + 255) & ~(size_t)255;
        return p;
    };
    bf16_t* xbf   = (bf16_t*)alloc((size_t)NTOK * LATENT * 2);
    bf16_t* Wcat  = (bf16_t*)alloc((size_t)3 * LATENT * LATENT * 2);
    bf16_t* Wobf  = (bf16_t*)alloc((size_t)LATENT * LATENT * 2);
    bf16_t* W1bf  = (bf16_t*)alloc((size_t)FFN_DIM * LATENT * 2);
    bf16_t* W2bf  = (bf16_t*)alloc((size_t)LATENT * FFN_DIM * 2);
    float*  bcat  = (float*)alloc((size_t)3 * LATENT * 4);
    bf16_t* QKV   = (bf16_t*)alloc((size_t)NTOK * 3 * LATENT * 2);
    bf16_t* attnO = (bf16_t*)alloc((size_t)NTOK * LATENT * 2);
    float*  tmpf  = (float*)alloc((size_t)NTOK * LATENT * 4);
    float*  y1f   = (float*)alloc((size_t)NTOK * LATENT * 4);
    bf16_t* y1bf  = (bf16_t*)alloc((size_t)NTOK * LATENT * 2);
    bf16_t* hbf   = (bf16_t*)alloc((size_t)NTOK * FFN_DIM * 2);
    float*  vsa   = (float*)alloc((size_t)NTOK * HEADS * 4);
    float*  vsb   = (float*)alloc((size_t)NTOK * HEADS * 4);
    bf16_t* Vtg   = (bf16_t*)hbf;   // alias: Vt lifetime disjoint from h
    float*  Oa    = tmpf;           // attn partial 0 (consumed before Wo writes tmpf)
    float*  Ob    = y1f;            // attn partial 1 (consumed before ln1 writes y1f)

    // 1. convert to bf16 + bias concat (seg 7)
    CvtDesc cd;
    cd.src[0] = x;   cd.dst[0] = xbf;                        cd.n4[0] = NTOK * LATENT / 4;
    cd.src[1] = Wq;  cd.dst[1] = Wcat;                       cd.n4[1] = LATENT * LATENT / 4;
    cd.src[2] = Wk;  cd.dst[2] = Wcat + LATENT * LATENT;     cd.n4[2] = LATENT * LATENT / 4;
    cd.src[3] = Wv;  cd.dst[3] = Wcat + 2 * LATENT * LATENT; cd.n4[3] = LATENT * LATENT / 4;
    cd.src[4] = Wo;  cd.dst[4] = Wobf;                       cd.n4[4] = LATENT * LATENT / 4;
    cd.src[5] = W1;  cd.dst[5] = W1bf;                       cd.n4[5] = FFN_DIM * LATENT / 4;
    cd.src[6] = W2;  cd.dst[6] = W2bf;                       cd.n4[6] = FFN_DIM * LATENT / 4;
    cd.bsrc[0] = bq; cd.bsrc[1] = bk; cd.bsrc[2] = bv;
    cd.bdst = bcat;
    {
        int maxn4 = NTOK * LATENT / 4;
        dim3 grid((maxn4 + 255) / 256, 8);
        cvt_f32_bf16<<<grid, 256, 0, stream>>>(cd);
    }

    // 2. fused QKV GEMM; Q region pre-scaled by C2 (EPI=3)
    gemm128<3, 128><<<dim3(NTOK / 128, 3 * LATENT / 128), 256, 0, stream>>>(
        xbf, Wcat, bcat, QKV, NTOK, 3 * LATENT, LATENT);

    // 2.5 V transpose
    v_transpose<<<dim3(SEQ / 64, 2 * HEADS), 256, 0, stream>>>(QKV, Vtg);

    // 3. attention: S^T scheme, 384 blocks x 4 waves, split-K x2
    attn_flash<<<dim3(2 * HEADS, SEQ / 256, 2), 256, 0, stream>>>(QKV, Vtg, Oa, Ob, vsa, vsb);

    // 3.5 combine partials -> bf16
    attn_combine<<<NTOK, 256, 0, stream>>>(Oa, Ob, vsa, vsb, attnO);

    // 4. output projection: 64x64 tiles, 768 balanced blocks
    gemm64<0><<<dim3(NTOK / 64, LATENT / 64), 128, 0, stream>>>(
        attnO, Wobf, bo, tmpf, NTOK, LATENT, LATENT);

    // 5. y1 = LN(x + proj)
    ln_residual<<<NTOK, 256, 0, stream>>>(x, tmpf, g1, be1, y1f, y1bf);

    // 6. h = gelu(y1 @ W1^T + b1)
    gemm128<2, 128><<<dim3(NTOK / 128, FFN_DIM / 128), 256, 0, stream>>>(
        y1bf, W1bf, b1, hbf, NTOK, FFN_DIM, LATENT);

    // 7. ffn = h @ W2^T + b2: 64x64 tiles, 768 balanced blocks
    gemm64<0><<<dim3(NTOK / 64, LATENT / 64), 128, 0, stream>>>(
        hbf, W2bf, b2, tmpf, NTOK, LATENT, FFN_DIM);

    // 8. out = LN(y1 + ffn)
    ln_residual<<<NTOK, 256, 0, stream>>>(y1f, tmpf, g2, be2, out, nullptr);
}

// Round 6
// 302.148 us; speedup vs baseline: 1.1368x; 1.0294x over previous
//
#include <hip/hip_runtime.h>
#include <hip/hip_bf16.h>
#include <cstddef>
#include <cstdint>

typedef __bf16 bf16_t;
typedef bf16_t bf16x8 __attribute__((ext_vector_type(8)));
typedef bf16_t bf16x4 __attribute__((ext_vector_type(4)));
typedef float f32x4 __attribute__((ext_vector_type(4)));

#define LATENT 768
#define FFN_DIM 3072
#define NTOK 4096      // 2*2048
#define SEQ 2048
#define HEADS 12
#define HD 64

#define C2F 0.18033688011112042f   // 0.125 * log2(e)

__device__ __forceinline__ void gload_lds16(const bf16_t* g, bf16_t* l) {
    __builtin_amdgcn_global_load_lds((const __attribute__((address_space(1))) void*)g,
                                     (__attribute__((address_space(3))) void*)l, 16, 0, 0);
}

// ---------------------------------------------------------------------------
// fp32 -> bf16 conversion, multi-segment; segment 7 = f32 bias concat (bq|bk|bv)
// ---------------------------------------------------------------------------
struct CvtDesc {
    const float* src[7];
    bf16_t* dst[7];
    int n4[7];
    const float* bsrc[3];
    float* bdst;
};

__global__ __launch_bounds__(256) void cvt_f32_bf16(CvtDesc d) {
    int seg = blockIdx.y;
    if (seg == 7) {   // bias concat: 3 blocks x 768 floats
        int which = blockIdx.x;
        if (which >= 3) return;
        int t = threadIdx.x;
#pragma unroll
        for (int i = 0; i < 3; ++i)
            d.bdst[which * LATENT + t + i * 256] = d.bsrc[which][t + i * 256];
        return;
    }
    int i = blockIdx.x * 256 + threadIdx.x;
    if (i >= d.n4[seg]) return;
    float4 v = ((const float4*)d.src[seg])[i];
    bf16x4 o;
    o[0] = (bf16_t)v.x; o[1] = (bf16_t)v.y; o[2] = (bf16_t)v.z; o[3] = (bf16_t)v.w;
    *(bf16x4*)&d.dst[seg][(size_t)i * 4] = o;
}

// ---------------------------------------------------------------------------
// GEMM 128x128, **512 thr = 8 waves** (r6: occupancy for latency hiding).
// All kernels showed Occupancy 12-15%, MfmaUtil<20%, HBM<50% -> latency-bound.
// At 4 waves x 2.25 blocks/CU = 2.25 waves/SIMD there is nothing to overlap
// the per-K-step vmcnt(0)+barrier drain with. 8 waves/block -> 18-24
// waves/CU (4.5-6/SIMD). Same tile, same math: wave (wm=w&1, wn=w>>1) owns
// 64x32 out (4x2 frags, 8 MFMA/step); staging = 1 A + 1 B gload per thread.
// Diagonal remap kept from r5 (wall-neutral, profiled-better).
// EPI: 0 none->f32, 1 none->bf16, 2 exact-GELU->bf16,
//      3 bf16 with cols<LATENT scaled by C2F (Q pre-scale for exp2 softmax)
// ---------------------------------------------------------------------------
template<int EPI>
__global__ __launch_bounds__(512) void gemm128(const bf16_t* __restrict__ A,
                                               const bf16_t* __restrict__ B,
                                               const float* __restrict__ bias,
                                               void* __restrict__ Cv,
                                               int M, int N, int K) {
    __shared__ __align__(16) bf16_t As[2][128 * 32];
    __shared__ __align__(16) bf16_t Bs[2][128 * 32];
    int t = threadIdx.x;
    int w = t >> 6;                           // 0..7
    int lane = t & 63, l16 = lane & 15, quad = lane >> 4;
    int xt = blockIdx.x + blockIdx.y;         // diagonal remap
    if (xt >= (int)gridDim.x) xt -= gridDim.x;
    int m0 = xt * 128, n0 = blockIdx.y * 128;
    int wm = w & 1, wn = w >> 1;              // 2M x 4N wave grid
    int mrow0 = wm * 64, ncol0 = wn * 32;

    f32x4 acc[4][2] = {};

    int srow = lane >> 2;                     // 0..15
    int sseg = (lane & 3) * 8;

    auto stage = [&](int k0, int buf) {
        const bf16_t* Ag = A + (size_t)(m0 + w * 16 + srow) * K + k0 + sseg;
        gload_lds16(Ag, &As[buf][(w * 16) * 32]);
        const bf16_t* Bg = B + (size_t)(n0 + w * 16 + srow) * K + k0 + sseg;
        gload_lds16(Bg, &Bs[buf][(w * 16) * 32]);
    };

    int niter = K / 32;
    stage(0, 0);
    for (int kt = 0; kt < niter; ++kt) {
        __syncthreads();   // drains prev prefetch (vmcnt0) + readers of other buf
        int cur = kt & 1;
        if (kt + 1 < niter) stage((kt + 1) * 32, cur ^ 1);

        bf16x8 a[4], b[2];
#pragma unroll
        for (int i = 0; i < 4; ++i)
            a[i] = *(const bf16x8*)&As[cur][(mrow0 + i * 16 + l16) * 32 + quad * 8];
#pragma unroll
        for (int j = 0; j < 2; ++j)
            b[j] = *(const bf16x8*)&Bs[cur][(ncol0 + j * 16 + l16) * 32 + quad * 8];
#pragma unroll
        for (int i = 0; i < 4; ++i)
#pragma unroll
            for (int j = 0; j < 2; ++j)
                acc[i][j] = __builtin_amdgcn_mfma_f32_16x16x32_bf16(a[i], b[j], acc[i][j], 0, 0, 0);
    }

    float* Cf = (float*)Cv;
    bf16_t* Cb = (bf16_t*)Cv;
#pragma unroll
    for (int j = 0; j < 2; ++j) {
        int col = n0 + ncol0 + j * 16 + l16;
        float bvv = bias[col];
#pragma unroll
        for (int i = 0; i < 4; ++i) {
            int row0 = m0 + mrow0 + i * 16 + quad * 4;
#pragma unroll
            for (int r = 0; r < 4; ++r) {
                float v = acc[i][j][r] + bvv;
                if (EPI == 2) v = 0.5f * v * (1.0f + erff(v * 0.70710678118654752f));
                if (EPI == 3) { if (col < LATENT) v *= C2F; }
                if (EPI == 0) Cf[(size_t)(row0 + r) * N + col] = v;
                else          Cb[(size_t)(row0 + r) * N + col] = (bf16_t)v;
            }
        }
    }
}

// ---------------------------------------------------------------------------
// GEMM 64x64 tile, **256 thr = 4 waves** (r6: was 2 waves = 1.5 waves/SIMD,
// latency-exposed). 4 waves as 2Mx2N, each 32x32 out (2x2 frags). Staging =
// 1 A + 1 B gload per thread. Identity tile mapping (bx%8 = per-XCD
// A-partitioning; r4 proved diagonal remap here thrashes L2 FETCH 30->117MB).
// For N=768: grid 64x12 = 768 blocks = 3/CU -> 12 waves/CU.
// ---------------------------------------------------------------------------
template<int EPI>
__global__ __launch_bounds__(256) void gemm64(const bf16_t* __restrict__ A,
                                              const bf16_t* __restrict__ B,
                                              const float* __restrict__ bias,
                                              void* __restrict__ Cv,
                                              int M, int N, int K) {
    __shared__ __align__(16) bf16_t As[2][64 * 32];
    __shared__ __align__(16) bf16_t Bs[2][64 * 32];
    int t = threadIdx.x;
    int w = t >> 6;                  // 0..3
    int lane = t & 63, l16 = lane & 15, quad = lane >> 4;
    int m0 = blockIdx.x * 64, n0 = blockIdx.y * 64;
    int wm = w & 1, wn = w >> 1;     // 2M x 2N wave grid

    f32x4 acc[2][2] = {};

    int srow = lane >> 2;
    int sseg = (lane & 3) * 8;

    auto stage = [&](int k0, int buf) {
        const bf16_t* Ag = A + (size_t)(m0 + w * 16 + srow) * K + k0 + sseg;
        gload_lds16(Ag, &As[buf][(w * 16) * 32]);
        const bf16_t* Bg = B + (size_t)(n0 + w * 16 + srow) * K + k0 + sseg;
        gload_lds16(Bg, &Bs[buf][(w * 16) * 32]);
    };

    int niter = K / 32;
    stage(0, 0);
    for (int kt = 0; kt < niter; ++kt) {
        __syncthreads();
        int cur = kt & 1;
        if (kt + 1 < niter) stage((kt + 1) * 32, cur ^ 1);

        bf16x8 a[2], b[2];
#pragma unroll
        for (int i = 0; i < 2; ++i)
            a[i] = *(const bf16x8*)&As[cur][(wm * 32 + i * 16 + l16) * 32 + quad * 8];
#pragma unroll
        for (int j = 0; j < 2; ++j)
            b[j] = *(const bf16x8*)&Bs[cur][(wn * 32 + j * 16 + l16) * 32 + quad * 8];
#pragma unroll
        for (int i = 0; i < 2; ++i)
#pragma unroll
            for (int j = 0; j < 2; ++j)
                acc[i][j] = __builtin_amdgcn_mfma_f32_16x16x32_bf16(a[i], b[j], acc[i][j], 0, 0, 0);
    }

    float* Cf = (float*)Cv;
    bf16_t* Cb = (bf16_t*)Cv;
#pragma unroll
    for (int j = 0; j < 2; ++j) {
        int col = n0 + wn * 32 + j * 16 + l16;
        float bvv = bias[col];
#pragma unroll
        for (int i = 0; i < 2; ++i) {
            int row0 = m0 + wm * 32 + i * 16 + quad * 4;
#pragma unroll
            for (int r = 0; r < 4; ++r) {
                float v = acc[i][j][r] + bvv;
                if (EPI == 2) v = 0.5f * v * (1.0f + erff(v * 0.70710678118654752f));
                if (EPI == 0) Cf[(size_t)(row0 + r) * N + col] = v;
                else          Cb[(size_t)(row0 + r) * N + col] = (bf16_t)v;
            }
        }
    }
}

// ---------------------------------------------------------------------------
// V transpose: QKV V-part [b, n, h, d] -> Vt [b, h, d, n]
// ---------------------------------------------------------------------------
__global__ __launch_bounds__(256) void v_transpose(const bf16_t* __restrict__ QKV,
                                                   bf16_t* __restrict__ Vt) {
    __shared__ bf16_t Ts[64][68];
    int t = threadIdx.x;
    int bh = blockIdx.y;
    int b = bh / HEADS, h = bh % HEADS;
    int n0 = blockIdx.x * 64;
    size_t rowbase = (size_t)b * SEQ;
    int r = t >> 3, seg = (t & 7) * 8;
#pragma unroll
    for (int i = 0; i < 2; ++i) {
        int rr = r + i * 32;
        *(bf16x8*)&Ts[rr][seg] =
            *(const bf16x8*)&QKV[(rowbase + n0 + rr) * (3 * LATENT) + 2 * LATENT + h * HD + seg];
    }
    __syncthreads();
#pragma unroll
    for (int i = 0; i < 2; ++i) {
        int d = r + i * 32;
        bf16x8 o;
#pragma unroll
        for (int jj = 0; jj < 8; ++jj) o[jj] = Ts[seg + jj][d];
        *(bf16x8*)&Vt[((size_t)bh * HD + d) * SEQ + n0 + seg] = o;
    }
}

// ---------------------------------------------------------------------------
// Flash attention (S^T formulation). r6: block = 4 waves x **32 q-rows** =
// 128 q (was 64 q/wave = 256 q) -> grid (24,16,2) = 768 blocks = 3 blocks/CU
// = 12 waves/CU (was 1.5 blocks/CU = 6 waves/CU, latency-exposed at
// Occupancy 12%). K/V staging per block unchanged (L2-served re-reads).
// LDS 50 KB -> 3 blocks/CU fit. Linear softmax; split-K x2 -> f32 partials.
// ---------------------------------------------------------------------------
__global__ __launch_bounds__(256) void attn_flash(const bf16_t* __restrict__ QKV,
                                                  const bf16_t* __restrict__ Vt,
                                                  float* __restrict__ Op0,
                                                  float* __restrict__ Op1,
                                                  float* __restrict__ vs0,
                                                  float* __restrict__ vs1) {
    __shared__ __align__(16) bf16_t Ks[2][2][64][32];    // [buf][d-chunk][key][d32]
    __shared__ __align__(16) bf16_t Vts[2][2][64][32];   // [buf][key-chunk][d][key32]
    __shared__ __align__(16) bf16_t Ps[4][32][72];       // [wave][q][key]

    int t = threadIdx.x;
    int w = t >> 6;
    int lane = t & 63, l16 = lane & 15, quad = lane >> 4;
    int bh = blockIdx.x;
    int b = bh / HEADS, h = bh % HEADS;
    int qblk = blockIdx.y * 128;
    int z = blockIdx.z;
    float* Op = z ? Op1 : Op0;
    float* vs = z ? vs1 : vs0;
    size_t rowbase = (size_t)b * SEQ;
    int kbase = z * (SEQ / 2);
    const int LD = 3 * LATENT;
    int qw = qblk + w * 32;

    bf16x8 bq[2][2];
#pragma unroll
    for (int qt = 0; qt < 2; ++qt) {
        const bf16_t* qrow = QKV + (rowbase + qw + qt * 16 + l16) * LD + h * HD;
        bq[qt][0] = *(const bf16x8*)&qrow[quad * 8];
        bq[qt][1] = *(const bf16x8*)&qrow[32 + quad * 8];
    }

    f32x4 acc[2][4] = {};    // [qt][dt]
    float vsum[2] = {};

    int srow = lane >> 2;
    int sseg = (lane & 3) * 8;

    {
        const bf16_t* kg = QKV + (rowbase + kbase + w * 16 + srow) * LD + LATENT + h * HD + sseg;
        gload_lds16(kg,      &Ks[0][0][w * 16][0]);
        gload_lds16(kg + 32, &Ks[0][1][w * 16][0]);
        const bf16_t* vg = Vt + ((size_t)bh * HD + w * 16 + srow) * SEQ + kbase + sseg;
        gload_lds16(vg,      &Vts[0][0][w * 16][0]);
        gload_lds16(vg + 32, &Vts[0][1][w * 16][0]);
    }

    for (int kt = 0; kt < SEQ / 128; ++kt) {
        __syncthreads();
        int cur = kt & 1;
        if (kt + 1 < SEQ / 128) {
            int nxt = cur ^ 1;
            int koff = kbase + (kt + 1) * 64;
            const bf16_t* kg = QKV + (rowbase + koff + w * 16 + srow) * LD + LATENT + h * HD + sseg;
            gload_lds16(kg,      &Ks[nxt][0][w * 16][0]);
            gload_lds16(kg + 32, &Ks[nxt][1][w * 16][0]);
            const bf16_t* vg = Vt + ((size_t)bh * HD + w * 16 + srow) * SEQ + koff + sseg;
            gload_lds16(vg,      &Vts[nxt][0][w * 16][0]);
            gload_lds16(vg + 32, &Vts[nxt][1][w * 16][0]);
        }

#pragma unroll
        for (int skt = 0; skt < 4; ++skt) {
            bf16x8 ak0 = *(const bf16x8*)&Ks[cur][0][skt * 16 + l16][quad * 8];
            bf16x8 ak1 = *(const bf16x8*)&Ks[cur][1][skt * 16 + l16][quad * 8];
#pragma unroll
            for (int qt = 0; qt < 2; ++qt) {
                f32x4 s = {};
                s = __builtin_amdgcn_mfma_f32_16x16x32_bf16(ak0, bq[qt][0], s, 0, 0, 0);
                s = __builtin_amdgcn_mfma_f32_16x16x32_bf16(ak1, bq[qt][1], s, 0, 0, 0);
                bf16x4 pk;
#pragma unroll
                for (int r = 0; r < 4; ++r) {
                    float p = __builtin_amdgcn_exp2f(s[r]);
                    vsum[qt] += p;
                    pk[r] = (bf16_t)p;
                }
                *(bf16x4*)&Ps[w][qt * 16 + l16][skt * 16 + quad * 4] = pk;
            }
        }
        __threadfence_block();

        bf16x8 bv[4][2];
#pragma unroll
        for (int dt = 0; dt < 4; ++dt) {
            bv[dt][0] = *(const bf16x8*)&Vts[cur][0][dt * 16 + l16][quad * 8];
            bv[dt][1] = *(const bf16x8*)&Vts[cur][1][dt * 16 + l16][quad * 8];
        }
#pragma unroll
        for (int qt = 0; qt < 2; ++qt) {
#pragma unroll
            for (int kc = 0; kc < 2; ++kc) {
                bf16x8 ap = *(const bf16x8*)&Ps[w][qt * 16 + l16][kc * 32 + quad * 8];
#pragma unroll
                for (int dt = 0; dt < 4; ++dt)
                    acc[qt][dt] = __builtin_amdgcn_mfma_f32_16x16x32_bf16(ap, bv[dt][kc], acc[qt][dt], 0, 0, 0);
            }
        }
    }

#pragma unroll
    for (int qt = 0; qt < 2; ++qt) {
        vsum[qt] += __shfl_xor(vsum[qt], 16, 64);
        vsum[qt] += __shfl_xor(vsum[qt], 32, 64);
        if (quad == 0)
            vs[(rowbase + qw + qt * 16 + l16) * HEADS + h] = vsum[qt];
    }

#pragma unroll
    for (int qt = 0; qt < 2; ++qt)
#pragma unroll
        for (int dt = 0; dt < 4; ++dt)
#pragma unroll
            for (int r = 0; r < 4; ++r) {
                size_t row = rowbase + qw + qt * 16 + quad * 4 + r;
                Op[row * LATENT + h * HD + dt * 16 + l16] = acc[qt][dt][r];
            }
}

// ---------------------------------------------------------------------------
// Combine the two attention split-K partials -> bf16
// ---------------------------------------------------------------------------
__global__ __launch_bounds__(256) void attn_combine(const float* __restrict__ Op0,
                                                    const float* __restrict__ Op1,
                                                    const float* __restrict__ vs0,
                                                    const float* __restrict__ vs1,
                                                    bf16_t* __restrict__ O) {
    int row = blockIdx.x;
    int t = threadIdx.x;
    const float* a = Op0 + (size_t)row * LATENT;
    const float* bb = Op1 + (size_t)row * LATENT;
#pragma unroll
    for (int i = 0; i < 3; ++i) {
        int c = t + i * 256;
        int h = c >> 6;
        float denom = vs0[(size_t)row * HEADS + h] + vs1[(size_t)row * HEADS + h];
        O[(size_t)row * LATENT + c] = (bf16_t)((a[c] + bb[c]) / denom);
    }
}

// ---------------------------------------------------------------------------
// Fused residual + LayerNorm
// ---------------------------------------------------------------------------
__global__ __launch_bounds__(256) void ln_residual(const float* __restrict__ base,
                                                   const float* __restrict__ add,
                                                   const float* __restrict__ g,
                                                   const float* __restrict__ bta,
                                                   float* __restrict__ outf,
                                                   bf16_t* __restrict__ outb) {
    int row = blockIdx.x;
    const float* xr = base + (size_t)row * LATENT;
    const float* ar = add + (size_t)row * LATENT;
    int t = threadIdx.x;
    float v[3];
    float s = 0.f;
#pragma unroll
    for (int i = 0; i < 3; ++i) {
        v[i] = xr[t + i * 256] + ar[t + i * 256];
        s += v[i];
    }
    __shared__ float red[4];
#pragma unroll
    for (int off = 1; off < 64; off <<= 1) s += __shfl_xor(s, off, 64);
    if ((t & 63) == 0) red[t >> 6] = s;
    __syncthreads();
    float mu = (red[0] + red[1] + red[2] + red[3]) * (1.f / LATENT);
    float q = 0.f;
#pragma unroll
    for (int i = 0; i < 3; ++i) {
        float d = v[i] - mu;
        q += d * d;
    }
#pragma unroll
    for (int off = 1; off < 64; off <<= 1) q += __shfl_xor(q, off, 64);
    __syncthreads();
    if ((t & 63) == 0) red[t >> 6] = q;
    __syncthreads();
    float var = (red[0] + red[1] + red[2] + red[3]) * (1.f / LATENT);
    float rs = rsqrtf(var + 1e-5f);
#pragma unroll
    for (int i = 0; i < 3; ++i) {
        int cix = t + i * 256;
        float o = (v[i] - mu) * rs * g[cix] + bta[cix];
        outf[(size_t)row * LATENT + cix] = o;
        if (outb) outb[(size_t)row * LATENT + cix] = (bf16_t)o;
    }
}

// ---------------------------------------------------------------------------
extern "C" void kernel_launch(void* const* d_in, const int* in_sizes, int n_in,
                              void* d_out, int out_size, void* d_ws, size_t ws_size,
                              hipStream_t stream) {
    const float* x   = (const float*)d_in[0];
    const float* Wq  = (const float*)d_in[1];
    const float* bq  = (const float*)d_in[2];
    const float* Wk  = (const float*)d_in[3];
    const float* bk  = (const float*)d_in[4];
    const float* Wv  = (const float*)d_in[5];
    const float* bv  = (const float*)d_in[6];
    const float* Wo  = (const float*)d_in[7];
    const float* bo  = (const float*)d_in[8];
    const float* g1  = (const float*)d_in[9];
    const float* be1 = (const float*)d_in[10];
    const float* g2  = (const float*)d_in[11];
    const float* be2 = (const float*)d_in[12];
    const float* W1  = (const float*)d_in[13];
    const float* b1  = (const float*)d_in[14];
    const float* W2  = (const float*)d_in[15];
    const float* b2  = (const float*)d_in[16];
    float* out = (float*)d_out;

    char* ws = (char*)d_ws;
    size_t off = 0;
    auto alloc = [&](size_t bytes) {
        char* p = ws + off;
        off = (off + bytes + 255) & ~(size_t)255;
        return p;
    };
    bf16_t* xbf   = (bf16_t*)alloc((size_t)NTOK * LATENT * 2);
    bf16_t* Wcat  = (bf16_t*)alloc((size_t)3 * LATENT * LATENT * 2);
    bf16_t* Wobf  = (bf16_t*)alloc((size_t)LATENT * LATENT * 2);
    bf16_t* W1bf  = (bf16_t*)alloc((size_t)FFN_DIM * LATENT * 2);
    bf16_t* W2bf  = (bf16_t*)alloc((size_t)LATENT * FFN_DIM * 2);
    float*  bcat  = (float*)alloc((size_t)3 * LATENT * 4);
    bf16_t* QKV   = (bf16_t*)alloc((size_t)NTOK * 3 * LATENT * 2);
    bf16_t* attnO = (bf16_t*)alloc((size_t)NTOK * LATENT * 2);
    float*  tmpf  = (float*)alloc((size_t)NTOK * LATENT * 4);
    float*  y1f   = (float*)alloc((size_t)NTOK * LATENT * 4);
    bf16_t* y1bf  = (bf16_t*)alloc((size_t)NTOK * LATENT * 2);
    bf16_t* hbf   = (bf16_t*)alloc((size_t)NTOK * FFN_DIM * 2);
    float*  vsa   = (float*)alloc((size_t)NTOK * HEADS * 4);
    float*  vsb   = (float*)alloc((size_t)NTOK * HEADS * 4);
    bf16_t* Vtg   = (bf16_t*)hbf;   // alias: Vt lifetime disjoint from h
    float*  Oa    = tmpf;           // attn partial 0 (consumed before Wo writes tmpf)
    float*  Ob    = y1f;            // attn partial 1 (consumed before ln1 writes y1f)

    // 1. convert to bf16 + bias concat (seg 7)
    CvtDesc cd;
    cd.src[0] = x;   cd.dst[0] = xbf;                        cd.n4[0] = NTOK * LATENT / 4;
    cd.src[1] = Wq;  cd.dst[1] = Wcat;                       cd.n4[1] = LATENT * LATENT / 4;
    cd.src[2] = Wk;  cd.dst[2] = Wcat + LATENT * LATENT;     cd.n4[2] = LATENT * LATENT / 4;
    cd.src[3] = Wv;  cd.dst[3] = Wcat + 2 * LATENT * LATENT; cd.n4[3] = LATENT * LATENT / 4;
    cd.src[4] = Wo;  cd.dst[4] = Wobf;                       cd.n4[4] = LATENT * LATENT / 4;
    cd.src[5] = W1;  cd.dst[5] = W1bf;                       cd.n4[5] = FFN_DIM * LATENT / 4;
    cd.src[6] = W2;  cd.dst[6] = W2bf;                       cd.n4[6] = FFN_DIM * LATENT / 4;
    cd.bsrc[0] = bq; cd.bsrc[1] = bk; cd.bsrc[2] = bv;
    cd.bdst = bcat;
    {
        int maxn4 = NTOK * LATENT / 4;
        dim3 grid((maxn4 + 255) / 256, 8);
        cvt_f32_bf16<<<grid, 256, 0, stream>>>(cd);
    }

    // 2. fused QKV GEMM; Q region pre-scaled by C2 (EPI=3). 512 thr / 8 waves.
    gemm128<3><<<dim3(NTOK / 128, 3 * LATENT / 128), 512, 0, stream>>>(
        xbf, Wcat, bcat, QKV, NTOK, 3 * LATENT, LATENT);

    // 2.5 V transpose
    v_transpose<<<dim3(SEQ / 64, 2 * HEADS), 256, 0, stream>>>(QKV, Vtg);

    // 3. attention: S^T scheme, 768 blocks x 4 waves (128 q each), split-K x2
    attn_flash<<<dim3(2 * HEADS, SEQ / 128, 2), 256, 0, stream>>>(QKV, Vtg, Oa, Ob, vsa, vsb);

    // 3.5 combine partials -> bf16
    attn_combine<<<NTOK, 256, 0, stream>>>(Oa, Ob, vsa, vsb, attnO);

    // 4. output projection: 64x64 tiles, 768 blocks x 4 waves
    gemm64<0><<<dim3(NTOK / 64, LATENT / 64), 256, 0, stream>>>(
        attnO, Wobf, bo, tmpf, NTOK, LATENT, LATENT);

    // 5. y1 = LN(x + proj)
    ln_residual<<<NTOK, 256, 0, stream>>>(x, tmpf, g1, be1, y1f, y1bf);

    // 6. h = gelu(y1 @ W1^T + b1). 512 thr / 8 waves.
    gemm128<2><<<dim3(NTOK / 128, FFN_DIM / 128), 512, 0, stream>>>(
        y1bf, W1bf, b1, hbf, NTOK, FFN_DIM, LATENT);

    // 7. ffn = h @ W2^T + b2: 64x64 tiles, 768 blocks x 4 waves
    gemm64<0><<<dim3(NTOK / 64, LATENT / 64), 256, 0, stream>>>(
        hbf, W2bf, b2, tmpf, NTOK, LATENT, FFN_DIM);

    // 8. out = LN(y1 + ffn)
    ln_residual<<<NTOK, 256, 0, stream>>>(y1f, tmpf, g2, be2, out, nullptr);
}

// Round 8
// 294.830 us; speedup vs baseline: 1.1650x; 1.0248x over previous
//
#include <hip/hip_runtime.h>
#include <hip/hip_bf16.h>
#include <cstddef>
#include <cstdint>

typedef __bf16 bf16_t;
typedef bf16_t bf16x8 __attribute__((ext_vector_type(8)));
typedef bf16_t bf16x4 __attribute__((ext_vector_type(4)));
typedef float f32x4 __attribute__((ext_vector_type(4)));

#define LATENT 768
#define FFN_DIM 3072
#define NTOK 4096      // 2*2048
#define SEQ 2048
#define HEADS 12
#define HD 64

#define C2F 0.18033688011112042f   // 0.125 * log2(e)

__device__ __forceinline__ void gload_lds16(const bf16_t* g, bf16_t* l) {
    __builtin_amdgcn_global_load_lds((const __attribute__((address_space(1))) void*)g,
                                     (__attribute__((address_space(3))) void*)l, 16, 0, 0);
}

// ---------------------------------------------------------------------------
// fp32 -> bf16 conversion, multi-segment; segment 7 = f32 bias concat (bq|bk|bv)
// ---------------------------------------------------------------------------
struct CvtDesc {
    const float* src[7];
    bf16_t* dst[7];
    int n4[7];
    const float* bsrc[3];
    float* bdst;
};

__global__ __launch_bounds__(256) void cvt_f32_bf16(CvtDesc d) {
    int seg = blockIdx.y;
    if (seg == 7) {   // bias concat: 3 blocks x 768 floats
        int which = blockIdx.x;
        if (which >= 3) return;
        int t = threadIdx.x;
#pragma unroll
        for (int i = 0; i < 3; ++i)
            d.bdst[which * LATENT + t + i * 256] = d.bsrc[which][t + i * 256];
        return;
    }
    int i = blockIdx.x * 256 + threadIdx.x;
    if (i >= d.n4[seg]) return;
    float4 v = ((const float4*)d.src[seg])[i];
    bf16x4 o;
    o[0] = (bf16_t)v.x; o[1] = (bf16_t)v.y; o[2] = (bf16_t)v.z; o[3] = (bf16_t)v.w;
    *(bf16x4*)&d.dst[seg][(size_t)i * 4] = o;
}

// ---------------------------------------------------------------------------
// GEMM 128x128, 512 thr = 8 waves (r6: 18-24 waves/CU for latency hiding).
// Wave (wm=w&1, wn=w>>1) owns 64x32 out (4x2 frags, 8 MFMA/step); staging =
// 1 A + 1 B gload per thread. Diagonal remap (r4: spreads same-m A-sharers
// across XCDs; profiled gemm128 101->57us).
// EPI: 0 none->f32, 2 exact-GELU->bf16,
//      3 bf16 with cols<LATENT scaled by C2F (Q pre-scale for exp2 softmax)
// ---------------------------------------------------------------------------
template<int EPI>
__global__ __launch_bounds__(512) void gemm128(const bf16_t* __restrict__ A,
                                               const bf16_t* __restrict__ B,
                                               const float* __restrict__ bias,
                                               void* __restrict__ Cv,
                                               int M, int N, int K) {
    __shared__ __align__(16) bf16_t As[2][128 * 32];
    __shared__ __align__(16) bf16_t Bs[2][128 * 32];
    int t = threadIdx.x;
    int w = t >> 6;                           // 0..7
    int lane = t & 63, l16 = lane & 15, quad = lane >> 4;
    int xt = blockIdx.x + blockIdx.y;         // diagonal remap
    if (xt >= (int)gridDim.x) xt -= gridDim.x;
    int m0 = xt * 128, n0 = blockIdx.y * 128;
    int wm = w & 1, wn = w >> 1;              // 2M x 4N wave grid
    int mrow0 = wm * 64, ncol0 = wn * 32;

    f32x4 acc[4][2] = {};

    int srow = lane >> 2;                     // 0..15
    int sseg = (lane & 3) * 8;

    auto stage = [&](int k0, int buf) {
        const bf16_t* Ag = A + (size_t)(m0 + w * 16 + srow) * K + k0 + sseg;
        gload_lds16(Ag, &As[buf][(w * 16) * 32]);
        const bf16_t* Bg = B + (size_t)(n0 + w * 16 + srow) * K + k0 + sseg;
        gload_lds16(Bg, &Bs[buf][(w * 16) * 32]);
    };

    int niter = K / 32;
    stage(0, 0);
    for (int kt = 0; kt < niter; ++kt) {
        __syncthreads();   // drains prev prefetch (vmcnt0) + readers of other buf
        int cur = kt & 1;
        if (kt + 1 < niter) stage((kt + 1) * 32, cur ^ 1);

        bf16x8 a[4], b[2];
#pragma unroll
        for (int i = 0; i < 4; ++i)
            a[i] = *(const bf16x8*)&As[cur][(mrow0 + i * 16 + l16) * 32 + quad * 8];
#pragma unroll
        for (int j = 0; j < 2; ++j)
            b[j] = *(const bf16x8*)&Bs[cur][(ncol0 + j * 16 + l16) * 32 + quad * 8];
#pragma unroll
        for (int i = 0; i < 4; ++i)
#pragma unroll
            for (int j = 0; j < 2; ++j)
                acc[i][j] = __builtin_amdgcn_mfma_f32_16x16x32_bf16(a[i], b[j], acc[i][j], 0, 0, 0);
    }

    float* Cf = (float*)Cv;
    bf16_t* Cb = (bf16_t*)Cv;
#pragma unroll
    for (int j = 0; j < 2; ++j) {
        int col = n0 + ncol0 + j * 16 + l16;
        float bvv = bias[col];
#pragma unroll
        for (int i = 0; i < 4; ++i) {
            int row0 = m0 + mrow0 + i * 16 + quad * 4;
#pragma unroll
            for (int r = 0; r < 4; ++r) {
                float v = acc[i][j][r] + bvv;
                if (EPI == 2) v = 0.5f * v * (1.0f + erff(v * 0.70710678118654752f));
                if (EPI == 3) { if (col < LATENT) v *= C2F; }
                if (EPI == 0) Cf[(size_t)(row0 + r) * N + col] = v;
                else          Cb[(size_t)(row0 + r) * N + col] = (bf16_t)v;
            }
        }
    }
}

// ---------------------------------------------------------------------------
// r7: GEMM 128x128 SPLIT-K x4 for FFN2 (M=4096, N=768, K=3072).
// Theory: FFN2 as 64x64/BK=32 ran 96 latency-exposed barrier iterations
// (~1150cy each, compute ~300cy) -> 46us at MfmaUtil 15%. This kernel:
// grid (32,6,4) = 768 blocks = exactly 3/CU (even fill), 24 waves/CU,
// each block 24 iterations with 4x the per-iter MFMA. Each z writes an
// f32 partial (bias folded into z=0); final LN sums base+4 partials.
// Identity tile map: bx%8 IS the per-XCD A-partitioning (r4 lesson).
// ---------------------------------------------------------------------------
struct SKDst { float* p[4]; };

__global__ __launch_bounds__(512) void gemm128sk(const bf16_t* __restrict__ A,
                                                 const bf16_t* __restrict__ B,
                                                 const float* __restrict__ bias,
                                                 SKDst dst,
                                                 int M, int N, int Ktot) {
    __shared__ __align__(16) bf16_t As[2][128 * 32];
    __shared__ __align__(16) bf16_t Bs[2][128 * 32];
    int t = threadIdx.x;
    int w = t >> 6;                           // 0..7
    int lane = t & 63, l16 = lane & 15, quad = lane >> 4;
    int z = blockIdx.z;
    int KS = Ktot >> 2;                       // per-split K
    int kbase = z * KS;
    int m0 = blockIdx.x * 128, n0 = blockIdx.y * 128;
    int wm = w & 1, wn = w >> 1;
    int mrow0 = wm * 64, ncol0 = wn * 32;

    f32x4 acc[4][2] = {};

    int srow = lane >> 2;
    int sseg = (lane & 3) * 8;

    auto stage = [&](int k0, int buf) {
        const bf16_t* Ag = A + (size_t)(m0 + w * 16 + srow) * Ktot + kbase + k0 + sseg;
        gload_lds16(Ag, &As[buf][(w * 16) * 32]);
        const bf16_t* Bg = B + (size_t)(n0 + w * 16 + srow) * Ktot + kbase + k0 + sseg;
        gload_lds16(Bg, &Bs[buf][(w * 16) * 32]);
    };

    int niter = KS / 32;                      // 24 for FFN2
    stage(0, 0);
    for (int kt = 0; kt < niter; ++kt) {
        __syncthreads();
        int cur = kt & 1;
        if (kt + 1 < niter) stage((kt + 1) * 32, cur ^ 1);

        bf16x8 a[4], b[2];
#pragma unroll
        for (int i = 0; i < 4; ++i)
            a[i] = *(const bf16x8*)&As[cur][(mrow0 + i * 16 + l16) * 32 + quad * 8];
#pragma unroll
        for (int j = 0; j < 2; ++j)
            b[j] = *(const bf16x8*)&Bs[cur][(ncol0 + j * 16 + l16) * 32 + quad * 8];
#pragma unroll
        for (int i = 0; i < 4; ++i)
#pragma unroll
            for (int j = 0; j < 2; ++j)
                acc[i][j] = __builtin_amdgcn_mfma_f32_16x16x32_bf16(a[i], b[j], acc[i][j], 0, 0, 0);
    }

    float* Cf = dst.p[z];
#pragma unroll
    for (int j = 0; j < 2; ++j) {
        int col = n0 + ncol0 + j * 16 + l16;
        float bvv = (z == 0) ? bias[col] : 0.f;
#pragma unroll
        for (int i = 0; i < 4; ++i) {
            int row0 = m0 + mrow0 + i * 16 + quad * 4;
#pragma unroll
            for (int r = 0; r < 4; ++r)
                Cf[(size_t)(row0 + r) * N + col] = acc[i][j][r] + bvv;
        }
    }
}

// ---------------------------------------------------------------------------
// GEMM 64x64 tile, 256 thr = 4 waves (2Mx2N, 32x32 out each). Identity tile
// mapping (bx%8 = per-XCD A-partitioning; r4: diagonal remap here thrashes
// L2, FETCH 30->117MB). Now only used for Wo (K=768, 24 iters).
// ---------------------------------------------------------------------------
template<int EPI>
__global__ __launch_bounds__(256) void gemm64(const bf16_t* __restrict__ A,
                                              const bf16_t* __restrict__ B,
                                              const float* __restrict__ bias,
                                              void* __restrict__ Cv,
                                              int M, int N, int K) {
    __shared__ __align__(16) bf16_t As[2][64 * 32];
    __shared__ __align__(16) bf16_t Bs[2][64 * 32];
    int t = threadIdx.x;
    int w = t >> 6;                  // 0..3
    int lane = t & 63, l16 = lane & 15, quad = lane >> 4;
    int m0 = blockIdx.x * 64, n0 = blockIdx.y * 64;
    int wm = w & 1, wn = w >> 1;     // 2M x 2N wave grid

    f32x4 acc[2][2] = {};

    int srow = lane >> 2;
    int sseg = (lane & 3) * 8;

    auto stage = [&](int k0, int buf) {
        const bf16_t* Ag = A + (size_t)(m0 + w * 16 + srow) * K + k0 + sseg;
        gload_lds16(Ag, &As[buf][(w * 16) * 32]);
        const bf16_t* Bg = B + (size_t)(n0 + w * 16 + srow) * K + k0 + sseg;
        gload_lds16(Bg, &Bs[buf][(w * 16) * 32]);
    };

    int niter = K / 32;
    stage(0, 0);
    for (int kt = 0; kt < niter; ++kt) {
        __syncthreads();
        int cur = kt & 1;
        if (kt + 1 < niter) stage((kt + 1) * 32, cur ^ 1);

        bf16x8 a[2], b[2];
#pragma unroll
        for (int i = 0; i < 2; ++i)
            a[i] = *(const bf16x8*)&As[cur][(wm * 32 + i * 16 + l16) * 32 + quad * 8];
#pragma unroll
        for (int j = 0; j < 2; ++j)
            b[j] = *(const bf16x8*)&Bs[cur][(wn * 32 + j * 16 + l16) * 32 + quad * 8];
#pragma unroll
        for (int i = 0; i < 2; ++i)
#pragma unroll
            for (int j = 0; j < 2; ++j)
                acc[i][j] = __builtin_amdgcn_mfma_f32_16x16x32_bf16(a[i], b[j], acc[i][j], 0, 0, 0);
    }

    float* Cf = (float*)Cv;
    bf16_t* Cb = (bf16_t*)Cv;
#pragma unroll
    for (int j = 0; j < 2; ++j) {
        int col = n0 + wn * 32 + j * 16 + l16;
        float bvv = bias[col];
#pragma unroll
        for (int i = 0; i < 2; ++i) {
            int row0 = m0 + wm * 32 + i * 16 + quad * 4;
#pragma unroll
            for (int r = 0; r < 4; ++r) {
                float v = acc[i][j][r] + bvv;
                if (EPI == 2) v = 0.5f * v * (1.0f + erff(v * 0.70710678118654752f));
                if (EPI == 0) Cf[(size_t)(row0 + r) * N + col] = v;
                else          Cb[(size_t)(row0 + r) * N + col] = (bf16_t)v;
            }
        }
    }
}

// ---------------------------------------------------------------------------
// V transpose: QKV V-part [b, n, h, d] -> Vt [b, h, d, n]
// ---------------------------------------------------------------------------
__global__ __launch_bounds__(256) void v_transpose(const bf16_t* __restrict__ QKV,
                                                   bf16_t* __restrict__ Vt) {
    __shared__ bf16_t Ts[64][68];
    int t = threadIdx.x;
    int bh = blockIdx.y;
    int b = bh / HEADS, h = bh % HEADS;
    int n0 = blockIdx.x * 64;
    size_t rowbase = (size_t)b * SEQ;
    int r = t >> 3, seg = (t & 7) * 8;
#pragma unroll
    for (int i = 0; i < 2; ++i) {
        int rr = r + i * 32;
        *(bf16x8*)&Ts[rr][seg] =
            *(const bf16x8*)&QKV[(rowbase + n0 + rr) * (3 * LATENT) + 2 * LATENT + h * HD + seg];
    }
    __syncthreads();
#pragma unroll
    for (int i = 0; i < 2; ++i) {
        int d = r + i * 32;
        bf16x8 o;
#pragma unroll
        for (int jj = 0; jj < 8; ++jj) o[jj] = Ts[seg + jj][d];
        *(bf16x8*)&Vt[((size_t)bh * HD + d) * SEQ + n0 + seg] = o;
    }
}

// ---------------------------------------------------------------------------
// Flash attention (S^T formulation). r6 structure kept: 4 waves x 32 q-rows,
// grid (24,16,2) = 768 blocks = 3/CU = 12 waves/CU. LDS 50KB.
// Linear softmax; split-K x2 -> f32 partials.
// ---------------------------------------------------------------------------
__global__ __launch_bounds__(256) void attn_flash(const bf16_t* __restrict__ QKV,
                                                  const bf16_t* __restrict__ Vt,
                                                  float* __restrict__ Op0,
                                                  float* __restrict__ Op1,
                                                  float* __restrict__ vs0,
                                                  float* __restrict__ vs1) {
    __shared__ __align__(16) bf16_t Ks[2][2][64][32];    // [buf][d-chunk][key][d32]
    __shared__ __align__(16) bf16_t Vts[2][2][64][32];   // [buf][key-chunk][d][key32]
    __shared__ __align__(16) bf16_t Ps[4][32][72];       // [wave][q][key]

    int t = threadIdx.x;
    int w = t >> 6;
    int lane = t & 63, l16 = lane & 15, quad = lane >> 4;
    int bh = blockIdx.x;
    int b = bh / HEADS, h = bh % HEADS;
    int qblk = blockIdx.y * 128;
    int z = blockIdx.z;
    float* Op = z ? Op1 : Op0;
    float* vs = z ? vs1 : vs0;
    size_t rowbase = (size_t)b * SEQ;
    int kbase = z * (SEQ / 2);
    const int LD = 3 * LATENT;
    int qw = qblk + w * 32;

    bf16x8 bq[2][2];
#pragma unroll
    for (int qt = 0; qt < 2; ++qt) {
        const bf16_t* qrow = QKV + (rowbase + qw + qt * 16 + l16) * LD + h * HD;
        bq[qt][0] = *(const bf16x8*)&qrow[quad * 8];
        bq[qt][1] = *(const bf16x8*)&qrow[32 + quad * 8];
    }

    f32x4 acc[2][4] = {};    // [qt][dt]
    float vsum[2] = {};

    int srow = lane >> 2;
    int sseg = (lane & 3) * 8;

    {
        const bf16_t* kg = QKV + (rowbase + kbase + w * 16 + srow) * LD + LATENT + h * HD + sseg;
        gload_lds16(kg,      &Ks[0][0][w * 16][0]);
        gload_lds16(kg + 32, &Ks[0][1][w * 16][0]);
        const bf16_t* vg = Vt + ((size_t)bh * HD + w * 16 + srow) * SEQ + kbase + sseg;
        gload_lds16(vg,      &Vts[0][0][w * 16][0]);
        gload_lds16(vg + 32, &Vts[0][1][w * 16][0]);
    }

    for (int kt = 0; kt < SEQ / 128; ++kt) {
        __syncthreads();
        int cur = kt & 1;
        if (kt + 1 < SEQ / 128) {
            int nxt = cur ^ 1;
            int koff = kbase + (kt + 1) * 64;
            const bf16_t* kg = QKV + (rowbase + koff + w * 16 + srow) * LD + LATENT + h * HD + sseg;
            gload_lds16(kg,      &Ks[nxt][0][w * 16][0]);
            gload_lds16(kg + 32, &Ks[nxt][1][w * 16][0]);
            const bf16_t* vg = Vt + ((size_t)bh * HD + w * 16 + srow) * SEQ + koff + sseg;
            gload_lds16(vg,      &Vts[nxt][0][w * 16][0]);
            gload_lds16(vg + 32, &Vts[nxt][1][w * 16][0]);
        }

#pragma unroll
        for (int skt = 0; skt < 4; ++skt) {
            bf16x8 ak0 = *(const bf16x8*)&Ks[cur][0][skt * 16 + l16][quad * 8];
            bf16x8 ak1 = *(const bf16x8*)&Ks[cur][1][skt * 16 + l16][quad * 8];
#pragma unroll
            for (int qt = 0; qt < 2; ++qt) {
                f32x4 s = {};
                s = __builtin_amdgcn_mfma_f32_16x16x32_bf16(ak0, bq[qt][0], s, 0, 0, 0);
                s = __builtin_amdgcn_mfma_f32_16x16x32_bf16(ak1, bq[qt][1], s, 0, 0, 0);
                bf16x4 pk;
#pragma unroll
                for (int r = 0; r < 4; ++r) {
                    float p = __builtin_amdgcn_exp2f(s[r]);
                    vsum[qt] += p;
                    pk[r] = (bf16_t)p;
                }
                *(bf16x4*)&Ps[w][qt * 16 + l16][skt * 16 + quad * 4] = pk;
            }
        }
        __threadfence_block();

        bf16x8 bv[4][2];
#pragma unroll
        for (int dt = 0; dt < 4; ++dt) {
            bv[dt][0] = *(const bf16x8*)&Vts[cur][0][dt * 16 + l16][quad * 8];
            bv[dt][1] = *(const bf16x8*)&Vts[cur][1][dt * 16 + l16][quad * 8];
        }
#pragma unroll
        for (int qt = 0; qt < 2; ++qt) {
#pragma unroll
            for (int kc = 0; kc < 2; ++kc) {
                bf16x8 ap = *(const bf16x8*)&Ps[w][qt * 16 + l16][kc * 32 + quad * 8];
#pragma unroll
                for (int dt = 0; dt < 4; ++dt)
                    acc[qt][dt] = __builtin_amdgcn_mfma_f32_16x16x32_bf16(ap, bv[dt][kc], acc[qt][dt], 0, 0, 0);
            }
        }
    }

#pragma unroll
    for (int qt = 0; qt < 2; ++qt) {
        vsum[qt] += __shfl_xor(vsum[qt], 16, 64);
        vsum[qt] += __shfl_xor(vsum[qt], 32, 64);
        if (quad == 0)
            vs[(rowbase + qw + qt * 16 + l16) * HEADS + h] = vsum[qt];
    }

#pragma unroll
    for (int qt = 0; qt < 2; ++qt)
#pragma unroll
        for (int dt = 0; dt < 4; ++dt)
#pragma unroll
            for (int r = 0; r < 4; ++r) {
                size_t row = rowbase + qw + qt * 16 + quad * 4 + r;
                Op[row * LATENT + h * HD + dt * 16 + l16] = acc[qt][dt][r];
            }
}

// ---------------------------------------------------------------------------
// Combine the two attention split-K partials -> bf16
// ---------------------------------------------------------------------------
__global__ __launch_bounds__(256) void attn_combine(const float* __restrict__ Op0,
                                                    const float* __restrict__ Op1,
                                                    const float* __restrict__ vs0,
                                                    const float* __restrict__ vs1,
                                                    bf16_t* __restrict__ O) {
    int row = blockIdx.x;
    int t = threadIdx.x;
    const float* a = Op0 + (size_t)row * LATENT;
    const float* bb = Op1 + (size_t)row * LATENT;
#pragma unroll
    for (int i = 0; i < 3; ++i) {
        int c = t + i * 256;
        int h = c >> 6;
        float denom = vs0[(size_t)row * HEADS + h] + vs1[(size_t)row * HEADS + h];
        O[(size_t)row * LATENT + c] = (bf16_t)((a[c] + bb[c]) / denom);
    }
}

// ---------------------------------------------------------------------------
// Fused residual + LayerNorm; NADD extra f32 addend streams (r7: NADD=4
// consumes the FFN2 split-K partials, removing a separate combine pass).
// ---------------------------------------------------------------------------
template<int NADD>
__global__ __launch_bounds__(256) void ln_residual(const float* __restrict__ base,
                                                   const float* __restrict__ a1,
                                                   const float* __restrict__ a2,
                                                   const float* __restrict__ a3,
                                                   const float* __restrict__ a4,
                                                   const float* __restrict__ g,
                                                   const float* __restrict__ bta,
                                                   float* __restrict__ outf,
                                                   bf16_t* __restrict__ outb) {
    int row = blockIdx.x;
    size_t ro = (size_t)row * LATENT;
    int t = threadIdx.x;
    float v[3];
    float s = 0.f;
#pragma unroll
    for (int i = 0; i < 3; ++i) {
        int cix = t + i * 256;
        float x = base[ro + cix] + a1[ro + cix];
        if (NADD >= 2) x += a2[ro + cix];
        if (NADD >= 3) x += a3[ro + cix];
        if (NADD >= 4) x += a4[ro + cix];
        v[i] = x;
        s += x;
    }
    __shared__ float red[4];
#pragma unroll
    for (int off = 1; off < 64; off <<= 1) s += __shfl_xor(s, off, 64);
    if ((t & 63) == 0) red[t >> 6] = s;
    __syncthreads();
    float mu = (red[0] + red[1] + red[2] + red[3]) * (1.f / LATENT);
    float q = 0.f;
#pragma unroll
    for (int i = 0; i < 3; ++i) {
        float d = v[i] - mu;
        q += d * d;
    }
#pragma unroll
    for (int off = 1; off < 64; off <<= 1) q += __shfl_xor(q, off, 64);
    __syncthreads();
    if ((t & 63) == 0) red[t >> 6] = q;
    __syncthreads();
    float var = (red[0] + red[1] + red[2] + red[3]) * (1.f / LATENT);
    float rs = rsqrtf(var + 1e-5f);
#pragma unroll
    for (int i = 0; i < 3; ++i) {
        int cix = t + i * 256;
        float o = (v[i] - mu) * rs * g[cix] + bta[cix];
        outf[ro + cix] = o;
        if (outb) outb[ro + cix] = (bf16_t)o;
    }
}

// ---------------------------------------------------------------------------
extern "C" void kernel_launch(void* const* d_in, const int* in_sizes, int n_in,
                              void* d_out, int out_size, void* d_ws, size_t ws_size,
                              hipStream_t stream) {
    const float* x   = (const float*)d_in[0];
    const float* Wq  = (const float*)d_in[1];
    const float* bq  = (const float*)d_in[2];
    const float* Wk  = (const float*)d_in[3];
    const float* bk  = (const float*)d_in[4];
    const float* Wv  = (const float*)d_in[5];
    const float* bv  = (const float*)d_in[6];
    const float* Wo  = (const float*)d_in[7];
    const float* bo  = (const float*)d_in[8];
    const float* g1  = (const float*)d_in[9];
    const float* be1 = (const float*)d_in[10];
    const float* g2  = (const float*)d_in[11];
    const float* be2 = (const float*)d_in[12];
    const float* W1  = (const float*)d_in[13];
    const float* b1  = (const float*)d_in[14];
    const float* W2  = (const float*)d_in[15];
    const float* b2  = (const float*)d_in[16];
    float* out = (float*)d_out;

    char* ws = (char*)d_ws;
    size_t off = 0;
    auto alloc = [&](size_t bytes) {
        char* p = ws + off;
        off = (off + bytes + 255) & ~(size_t)255;
        return p;
    };
    bf16_t* xbf   = (bf16_t*)alloc((size_t)NTOK * LATENT * 2);
    bf16_t* Wcat  = (bf16_t*)alloc((size_t)3 * LATENT * LATENT * 2);
    bf16_t* Wobf  = (bf16_t*)alloc((size_t)LATENT * LATENT * 2);
    bf16_t* W1bf  = (bf16_t*)alloc((size_t)FFN_DIM * LATENT * 2);
    bf16_t* W2bf  = (bf16_t*)alloc((size_t)LATENT * FFN_DIM * 2);
    float*  bcat  = (float*)alloc((size_t)3 * LATENT * 4);
    bf16_t* QKV   = (bf16_t*)alloc((size_t)NTOK * 3 * LATENT * 2);
    bf16_t* attnO = (bf16_t*)alloc((size_t)NTOK * LATENT * 2);
    float*  tmpf  = (float*)alloc((size_t)NTOK * LATENT * 4);
    float*  y1f   = (float*)alloc((size_t)NTOK * LATENT * 4);
    bf16_t* y1bf  = (bf16_t*)alloc((size_t)NTOK * LATENT * 2);
    bf16_t* hbf   = (bf16_t*)alloc((size_t)NTOK * FFN_DIM * 2);
    float*  vsa   = (float*)alloc((size_t)NTOK * HEADS * 4);
    float*  vsb   = (float*)alloc((size_t)NTOK * HEADS * 4);
    float*  P3    = (float*)alloc((size_t)NTOK * LATENT * 4);   // r7: 4th FFN2 partial
    bf16_t* Vtg   = (bf16_t*)hbf;   // alias: Vt lifetime disjoint from h
    float*  Oa    = tmpf;           // attn partial 0 (consumed before Wo writes tmpf)
    float*  Ob    = y1f;            // attn partial 1 (consumed before ln1 writes y1f)
    // r7 FFN2 split-K partials (all dead regions at FFN2 time):
    //   P0 = tmpf   (free after ln1)
    //   P1 = QKV    (18.9MB region, free after attn)
    //   P2 = xbf+Wcat+Wobf+W1bf span (15.7MB contiguous, all dead by FFN2)
    //   P3 = dedicated alloc
    float* P0 = tmpf;
    float* P1 = (float*)QKV;
    float* P2 = (float*)xbf;

    // 1. convert to bf16 + bias concat (seg 7)
    CvtDesc cd;
    cd.src[0] = x;   cd.dst[0] = xbf;                        cd.n4[0] = NTOK * LATENT / 4;
    cd.src[1] = Wq;  cd.dst[1] = Wcat;                       cd.n4[1] = LATENT * LATENT / 4;
    cd.src[2] = Wk;  cd.dst[2] = Wcat + LATENT * LATENT;     cd.n4[2] = LATENT * LATENT / 4;
    cd.src[3] = Wv;  cd.dst[3] = Wcat + 2 * LATENT * LATENT; cd.n4[3] = LATENT * LATENT / 4;
    cd.src[4] = Wo;  cd.dst[4] = Wobf;                       cd.n4[4] = LATENT * LATENT / 4;
    cd.src[5] = W1;  cd.dst[5] = W1bf;                       cd.n4[5] = FFN_DIM * LATENT / 4;
    cd.src[6] = W2;  cd.dst[6] = W2bf;                       cd.n4[6] = FFN_DIM * LATENT / 4;
    cd.bsrc[0] = bq; cd.bsrc[1] = bk; cd.bsrc[2] = bv;
    cd.bdst = bcat;
    {
        int maxn4 = NTOK * LATENT / 4;
        dim3 grid((maxn4 + 255) / 256, 8);
        cvt_f32_bf16<<<grid, 256, 0, stream>>>(cd);
    }

    // 2. fused QKV GEMM; Q region pre-scaled by C2 (EPI=3). 512 thr / 8 waves.
    gemm128<3><<<dim3(NTOK / 128, 3 * LATENT / 128), 512, 0, stream>>>(
        xbf, Wcat, bcat, QKV, NTOK, 3 * LATENT, LATENT);

    // 2.5 V transpose
    v_transpose<<<dim3(SEQ / 64, 2 * HEADS), 256, 0, stream>>>(QKV, Vtg);

    // 3. attention: S^T scheme, 768 blocks x 4 waves (128 q each), split-K x2
    attn_flash<<<dim3(2 * HEADS, SEQ / 128, 2), 256, 0, stream>>>(QKV, Vtg, Oa, Ob, vsa, vsb);

    // 3.5 combine partials -> bf16
    attn_combine<<<NTOK, 256, 0, stream>>>(Oa, Ob, vsa, vsb, attnO);

    // 4. output projection: 64x64 tiles, 768 blocks x 4 waves
    gemm64<0><<<dim3(NTOK / 64, LATENT / 64), 256, 0, stream>>>(
        attnO, Wobf, bo, tmpf, NTOK, LATENT, LATENT);

    // 5. y1 = LN(x + proj)
    ln_residual<1><<<NTOK, 256, 0, stream>>>(x, tmpf, nullptr, nullptr, nullptr,
                                             g1, be1, y1f, y1bf);

    // 6. h = gelu(y1 @ W1^T + b1). 512 thr / 8 waves.
    gemm128<2><<<dim3(NTOK / 128, FFN_DIM / 128), 512, 0, stream>>>(
        y1bf, W1bf, b1, hbf, NTOK, FFN_DIM, LATENT);

    // 7. ffn partials = h @ W2^T + b2, 128x128 split-K x4: 768 blocks = 3/CU
    SKDst skd;
    skd.p[0] = P0; skd.p[1] = P1; skd.p[2] = P2; skd.p[3] = P3;
    gemm128sk<<<dim3(NTOK / 128, LATENT / 128, 4), 512, 0, stream>>>(
        hbf, W2bf, b2, skd, NTOK, LATENT, FFN_DIM);

    // 8. out = LN(y1 + P0 + P1 + P2 + P3)
    ln_residual<4><<<NTOK, 256, 0, stream>>>(y1f, P0, P1, P2, P3,
                                             g2, be2, out, nullptr);
}

// Round 10
// 291.582 us; speedup vs baseline: 1.1780x; 1.0111x over previous
//
#include <hip/hip_runtime.h>
#include <hip/hip_bf16.h>
#include <cstddef>
#include <cstdint>

typedef __bf16 bf16_t;
typedef bf16_t bf16x8 __attribute__((ext_vector_type(8)));
typedef bf16_t bf16x4 __attribute__((ext_vector_type(4)));
typedef float f32x4 __attribute__((ext_vector_type(4)));

#define LATENT 768
#define FFN_DIM 3072
#define NTOK 4096      // 2*2048
#define SEQ 2048
#define HEADS 12
#define HD 64

#define C2F 0.18033688011112042f   // 0.125 * log2(e)

__device__ __forceinline__ void gload_lds16(const bf16_t* g, bf16_t* l) {
    __builtin_amdgcn_global_load_lds((const __attribute__((address_space(1))) void*)g,
                                     (__attribute__((address_space(3))) void*)l, 16, 0, 0);
}

// r9 LDS XOR-swizzle for [N][32]bf16 (64B-row) tiles read by ds_read_b128:
// unswizzled, a 16-lane read phase lands on only 2 of 8 bank groups
// (bg = 4*(l16&1) + quad, quad constant per phase) -> 4-8-way serialization;
// 5.5M conflict-cycles measured in attn (~19% of its time). Physical slot p
// at row r holds logical slot p^((r>>1)&3).
// WRITE side: global_load_lds writes linearly, so the SOURCE address is
// pre-swizzled (m173): lane fetches slot (lane&3)^((lane>>3)&3).
// READ side: quad' = quad ^ ((l16>>1)&3) — loop-invariant, zero inner cost;
// per-phase bank groups become 4*(l16&1) + (quad^((l16>>1)&3)): all 8 groups
// exactly twice = minimum aliasing = free (m136).
#define SW_SRC(lane)  ((((lane) & 3) ^ (((lane) >> 3) & 3)) * 8)
#define SW_RD(quad, l16)  (((quad) ^ (((l16) >> 1) & 3)) * 8)

// ---------------------------------------------------------------------------
// fp32 -> bf16 conversion, multi-segment; segment 7 = f32 bias concat (bq|bk|bv)
// ---------------------------------------------------------------------------
struct CvtDesc {
    const float* src[7];
    bf16_t* dst[7];
    int n4[7];
    const float* bsrc[3];
    float* bdst;
};

__global__ __launch_bounds__(256) void cvt_f32_bf16(CvtDesc d) {
    int seg = blockIdx.y;
    if (seg == 7) {   // bias concat: 3 blocks x 768 floats
        int which = blockIdx.x;
        if (which >= 3) return;
        int t = threadIdx.x;
#pragma unroll
        for (int i = 0; i < 3; ++i)
            d.bdst[which * LATENT + t + i * 256] = d.bsrc[which][t + i * 256];
        return;
    }
    int i = blockIdx.x * 256 + threadIdx.x;
    if (i >= d.n4[seg]) return;
    float4 v = ((const float4*)d.src[seg])[i];
    bf16x4 o;
    o[0] = (bf16_t)v.x; o[1] = (bf16_t)v.y; o[2] = (bf16_t)v.z; o[3] = (bf16_t)v.w;
    *(bf16x4*)&d.dst[seg][(size_t)i * 4] = o;
}

// ---------------------------------------------------------------------------
// GEMM 128x128, 512 thr = 8 waves. Wave (wm=w&1, wn=w>>1) owns 64x32 out.
// Diagonal remap (r4). r9: LDS swizzle (expected ~null here per T2 regime
// gate m230 — 2-phase critical path is stage+barrier — but zero-cost).
// EPI: 0 none->f32, 2 exact-GELU->bf16, 3 bf16 + C2F scale on cols<LATENT.
// ---------------------------------------------------------------------------
template<int EPI>
__global__ __launch_bounds__(512) void gemm128(const bf16_t* __restrict__ A,
                                               const bf16_t* __restrict__ B,
                                               const float* __restrict__ bias,
                                               void* __restrict__ Cv,
                                               int M, int N, int K) {
    __shared__ __align__(16) bf16_t As[2][128 * 32];
    __shared__ __align__(16) bf16_t Bs[2][128 * 32];
    int t = threadIdx.x;
    int w = t >> 6;                           // 0..7
    int lane = t & 63, l16 = lane & 15, quad = lane >> 4;
    int xt = blockIdx.x + blockIdx.y;         // diagonal remap
    if (xt >= (int)gridDim.x) xt -= gridDim.x;
    int m0 = xt * 128, n0 = blockIdx.y * 128;
    int wm = w & 1, wn = w >> 1;              // 2M x 4N wave grid
    int mrow0 = wm * 64, ncol0 = wn * 32;

    f32x4 acc[4][2] = {};

    int srow = lane >> 2;                     // 0..15
    int sseg = SW_SRC(lane);                  // r9: pre-swizzled source slot
    int qsw  = SW_RD(quad, l16);              // r9: swizzled read slot

    auto stage = [&](int k0, int buf) {
        const bf16_t* Ag = A + (size_t)(m0 + w * 16 + srow) * K + k0 + sseg;
        gload_lds16(Ag, &As[buf][(w * 16) * 32]);
        const bf16_t* Bg = B + (size_t)(n0 + w * 16 + srow) * K + k0 + sseg;
        gload_lds16(Bg, &Bs[buf][(w * 16) * 32]);
    };

    int niter = K / 32;
    stage(0, 0);
    for (int kt = 0; kt < niter; ++kt) {
        __syncthreads();   // drains prev prefetch (vmcnt0) + readers of other buf
        int cur = kt & 1;
        if (kt + 1 < niter) stage((kt + 1) * 32, cur ^ 1);

        bf16x8 a[4], b[2];
#pragma unroll
        for (int i = 0; i < 4; ++i)
            a[i] = *(const bf16x8*)&As[cur][(mrow0 + i * 16 + l16) * 32 + qsw];
#pragma unroll
        for (int j = 0; j < 2; ++j)
            b[j] = *(const bf16x8*)&Bs[cur][(ncol0 + j * 16 + l16) * 32 + qsw];
#pragma unroll
        for (int i = 0; i < 4; ++i)
#pragma unroll
            for (int j = 0; j < 2; ++j)
                acc[i][j] = __builtin_amdgcn_mfma_f32_16x16x32_bf16(a[i], b[j], acc[i][j], 0, 0, 0);
    }

    float* Cf = (float*)Cv;
    bf16_t* Cb = (bf16_t*)Cv;
#pragma unroll
    for (int j = 0; j < 2; ++j) {
        int col = n0 + ncol0 + j * 16 + l16;
        float bvv = bias[col];
#pragma unroll
        for (int i = 0; i < 4; ++i) {
            int row0 = m0 + mrow0 + i * 16 + quad * 4;
#pragma unroll
            for (int r = 0; r < 4; ++r) {
                float v = acc[i][j][r] + bvv;
                if (EPI == 2) v = 0.5f * v * (1.0f + erff(v * 0.70710678118654752f));
                if (EPI == 3) { if (col < LATENT) v *= C2F; }
                if (EPI == 0) Cf[(size_t)(row0 + r) * N + col] = v;
                else          Cb[(size_t)(row0 + r) * N + col] = (bf16_t)v;
            }
        }
    }
}

// ---------------------------------------------------------------------------
// r7: GEMM 128x128 SPLIT-K x4 for FFN2. grid (32,6,4)=768 blocks = 3/CU,
// 24 iterations/block, partial f32 outputs summed in the final LN.
// Identity tile map (bx%8 = per-XCD A-partitioning). r9: +LDS swizzle.
// ---------------------------------------------------------------------------
struct SKDst { float* p[4]; };

__global__ __launch_bounds__(512) void gemm128sk(const bf16_t* __restrict__ A,
                                                 const bf16_t* __restrict__ B,
                                                 const float* __restrict__ bias,
                                                 SKDst dst,
                                                 int M, int N, int Ktot) {
    __shared__ __align__(16) bf16_t As[2][128 * 32];
    __shared__ __align__(16) bf16_t Bs[2][128 * 32];
    int t = threadIdx.x;
    int w = t >> 6;                           // 0..7
    int lane = t & 63, l16 = lane & 15, quad = lane >> 4;
    int z = blockIdx.z;
    int KS = Ktot >> 2;                       // per-split K
    int kbase = z * KS;
    int m0 = blockIdx.x * 128, n0 = blockIdx.y * 128;
    int wm = w & 1, wn = w >> 1;
    int mrow0 = wm * 64, ncol0 = wn * 32;

    f32x4 acc[4][2] = {};

    int srow = lane >> 2;
    int sseg = SW_SRC(lane);
    int qsw  = SW_RD(quad, l16);

    auto stage = [&](int k0, int buf) {
        const bf16_t* Ag = A + (size_t)(m0 + w * 16 + srow) * Ktot + kbase + k0 + sseg;
        gload_lds16(Ag, &As[buf][(w * 16) * 32]);
        const bf16_t* Bg = B + (size_t)(n0 + w * 16 + srow) * Ktot + kbase + k0 + sseg;
        gload_lds16(Bg, &Bs[buf][(w * 16) * 32]);
    };

    int niter = KS / 32;                      // 24 for FFN2
    stage(0, 0);
    for (int kt = 0; kt < niter; ++kt) {
        __syncthreads();
        int cur = kt & 1;
        if (kt + 1 < niter) stage((kt + 1) * 32, cur ^ 1);

        bf16x8 a[4], b[2];
#pragma unroll
        for (int i = 0; i < 4; ++i)
            a[i] = *(const bf16x8*)&As[cur][(mrow0 + i * 16 + l16) * 32 + qsw];
#pragma unroll
        for (int j = 0; j < 2; ++j)
            b[j] = *(const bf16x8*)&Bs[cur][(ncol0 + j * 16 + l16) * 32 + qsw];
#pragma unroll
        for (int i = 0; i < 4; ++i)
#pragma unroll
            for (int j = 0; j < 2; ++j)
                acc[i][j] = __builtin_amdgcn_mfma_f32_16x16x32_bf16(a[i], b[j], acc[i][j], 0, 0, 0);
    }

    float* Cf = dst.p[z];
#pragma unroll
    for (int j = 0; j < 2; ++j) {
        int col = n0 + ncol0 + j * 16 + l16;
        float bvv = (z == 0) ? bias[col] : 0.f;
#pragma unroll
        for (int i = 0; i < 4; ++i) {
            int row0 = m0 + mrow0 + i * 16 + quad * 4;
#pragma unroll
            for (int r = 0; r < 4; ++r)
                Cf[(size_t)(row0 + r) * N + col] = acc[i][j][r] + bvv;
        }
    }
}

// ---------------------------------------------------------------------------
// GEMM 64x64 tile, 256 thr = 4 waves (2Mx2N). Identity tile mapping (r4).
// Used for Wo (K=768). r9: +LDS swizzle.
// ---------------------------------------------------------------------------
template<int EPI>
__global__ __launch_bounds__(256) void gemm64(const bf16_t* __restrict__ A,
                                              const bf16_t* __restrict__ B,
                                              const float* __restrict__ bias,
                                              void* __restrict__ Cv,
                                              int M, int N, int K) {
    __shared__ __align__(16) bf16_t As[2][64 * 32];
    __shared__ __align__(16) bf16_t Bs[2][64 * 32];
    int t = threadIdx.x;
    int w = t >> 6;                  // 0..3
    int lane = t & 63, l16 = lane & 15, quad = lane >> 4;
    int m0 = blockIdx.x * 64, n0 = blockIdx.y * 64;
    int wm = w & 1, wn = w >> 1;     // 2M x 2N wave grid

    f32x4 acc[2][2] = {};

    int srow = lane >> 2;
    int sseg = SW_SRC(lane);
    int qsw  = SW_RD(quad, l16);

    auto stage = [&](int k0, int buf) {
        const bf16_t* Ag = A + (size_t)(m0 + w * 16 + srow) * K + k0 + sseg;
        gload_lds16(Ag, &As[buf][(w * 16) * 32]);
        const bf16_t* Bg = B + (size_t)(n0 + w * 16 + srow) * K + k0 + sseg;
        gload_lds16(Bg, &Bs[buf][(w * 16) * 32]);
    };

    int niter = K / 32;
    stage(0, 0);
    for (int kt = 0; kt < niter; ++kt) {
        __syncthreads();
        int cur = kt & 1;
        if (kt + 1 < niter) stage((kt + 1) * 32, cur ^ 1);

        bf16x8 a[2], b[2];
#pragma unroll
        for (int i = 0; i < 2; ++i)
            a[i] = *(const bf16x8*)&As[cur][(wm * 32 + i * 16 + l16) * 32 + qsw];
#pragma unroll
        for (int j = 0; j < 2; ++j)
            b[j] = *(const bf16x8*)&Bs[cur][(wn * 32 + j * 16 + l16) * 32 + qsw];
#pragma unroll
        for (int i = 0; i < 2; ++i)
#pragma unroll
            for (int j = 0; j < 2; ++j)
                acc[i][j] = __builtin_amdgcn_mfma_f32_16x16x32_bf16(a[i], b[j], acc[i][j], 0, 0, 0);
    }

    float* Cf = (float*)Cv;
    bf16_t* Cb = (bf16_t*)Cv;
#pragma unroll
    for (int j = 0; j < 2; ++j) {
        int col = n0 + wn * 32 + j * 16 + l16;
        float bvv = bias[col];
#pragma unroll
        for (int i = 0; i < 2; ++i) {
            int row0 = m0 + wm * 32 + i * 16 + quad * 4;
#pragma unroll
            for (int r = 0; r < 4; ++r) {
                float v = acc[i][j][r] + bvv;
                if (EPI == 2) v = 0.5f * v * (1.0f + erff(v * 0.70710678118654752f));
                if (EPI == 0) Cf[(size_t)(row0 + r) * N + col] = v;
                else          Cb[(size_t)(row0 + r) * N + col] = (bf16_t)v;
            }
        }
    }
}

// ---------------------------------------------------------------------------
// V transpose: QKV V-part [b, n, h, d] -> Vt [b, h, d, n]
// ---------------------------------------------------------------------------
__global__ __launch_bounds__(256) void v_transpose(const bf16_t* __restrict__ QKV,
                                                   bf16_t* __restrict__ Vt) {
    __shared__ bf16_t Ts[64][68];
    int t = threadIdx.x;
    int bh = blockIdx.y;
    int b = bh / HEADS, h = bh % HEADS;
    int n0 = blockIdx.x * 64;
    size_t rowbase = (size_t)b * SEQ;
    int r = t >> 3, seg = (t & 7) * 8;
#pragma unroll
    for (int i = 0; i < 2; ++i) {
        int rr = r + i * 32;
        *(bf16x8*)&Ts[rr][seg] =
            *(const bf16x8*)&QKV[(rowbase + n0 + rr) * (3 * LATENT) + 2 * LATENT + h * HD + seg];
    }
    __syncthreads();
#pragma unroll
    for (int i = 0; i < 2; ++i) {
        int d = r + i * 32;
        bf16x8 o;
#pragma unroll
        for (int jj = 0; jj < 8; ++jj) o[jj] = Ts[seg + jj][d];
        *(bf16x8*)&Vt[((size_t)bh * HD + d) * SEQ + n0 + seg] = o;
    }
}

// ---------------------------------------------------------------------------
// Flash attention (S^T formulation). 4 waves x 32 q-rows = 128 q/block,
// grid (24,16,2) = 768 blocks = 3/CU. r9: K/V LDS XOR-swizzle (read-phase
// bank-group spread 2->8 of 8; 5.5M conflict-cycles measured = ~19% of
// kernel time). Linear softmax; split-K x2 -> f32 partials.
// ---------------------------------------------------------------------------
__global__ __launch_bounds__(256) void attn_flash(const bf16_t* __restrict__ QKV,
                                                  const bf16_t* __restrict__ Vt,
                                                  float* __restrict__ Op0,
                                                  float* __restrict__ Op1,
                                                  float* __restrict__ vs0,
                                                  float* __restrict__ vs1) {
    __shared__ __align__(16) bf16_t Ks[2][2][64][32];    // [buf][d-chunk][key][d32]
    __shared__ __align__(16) bf16_t Vts[2][2][64][32];   // [buf][key-chunk][d][key32]
    __shared__ __align__(16) bf16_t Ps[4][32][72];       // [wave][q][key]

    int t = threadIdx.x;
    int w = t >> 6;
    int lane = t & 63, l16 = lane & 15, quad = lane >> 4;
    int bh = blockIdx.x;
    int b = bh / HEADS, h = bh % HEADS;
    int qblk = blockIdx.y * 128;
    int z = blockIdx.z;
    float* Op = z ? Op1 : Op0;
    float* vs = z ? vs1 : vs0;
    size_t rowbase = (size_t)b * SEQ;
    int kbase = z * (SEQ / 2);
    const int LD = 3 * LATENT;
    int qw = qblk + w * 32;

    bf16x8 bq[2][2];
#pragma unroll
    for (int qt = 0; qt < 2; ++qt) {
        const bf16_t* qrow = QKV + (rowbase + qw + qt * 16 + l16) * LD + h * HD;
        bq[qt][0] = *(const bf16x8*)&qrow[quad * 8];
        bq[qt][1] = *(const bf16x8*)&qrow[32 + quad * 8];
    }

    f32x4 acc[2][4] = {};    // [qt][dt]
    float vsum[2] = {};

    int srow = lane >> 2;
    int sseg = SW_SRC(lane);               // r9: pre-swizzled source slot
    int qsw  = SW_RD(quad, l16);           // r9: swizzled read slot

    {
        const bf16_t* kg = QKV + (rowbase + kbase + w * 16 + srow) * LD + LATENT + h * HD + sseg;
        gload_lds16(kg,      &Ks[0][0][w * 16][0]);
        gload_lds16(kg + 32, &Ks[0][1][w * 16][0]);
        const bf16_t* vg = Vt + ((size_t)bh * HD + w * 16 + srow) * SEQ + kbase + sseg;
        gload_lds16(vg,      &Vts[0][0][w * 16][0]);
        gload_lds16(vg + 32, &Vts[0][1][w * 16][0]);
    }

    for (int kt = 0; kt < SEQ / 128; ++kt) {
        __syncthreads();
        int cur = kt & 1;
        if (kt + 1 < SEQ / 128) {
            int nxt = cur ^ 1;
            int koff = kbase + (kt + 1) * 64;
            const bf16_t* kg = QKV + (rowbase + koff + w * 16 + srow) * LD + LATENT + h * HD + sseg;
            gload_lds16(kg,      &Ks[nxt][0][w * 16][0]);
            gload_lds16(kg + 32, &Ks[nxt][1][w * 16][0]);
            const bf16_t* vg = Vt + ((size_t)bh * HD + w * 16 + srow) * SEQ + koff + sseg;
            gload_lds16(vg,      &Vts[nxt][0][w * 16][0]);
            gload_lds16(vg + 32, &Vts[nxt][1][w * 16][0]);
        }

#pragma unroll
        for (int skt = 0; skt < 4; ++skt) {
            bf16x8 ak0 = *(const bf16x8*)&Ks[cur][0][skt * 16 + l16][qsw];
            bf16x8 ak1 = *(const bf16x8*)&Ks[cur][1][skt * 16 + l16][qsw];
#pragma unroll
            for (int qt = 0; qt < 2; ++qt) {
                f32x4 s = {};
                s = __builtin_amdgcn_mfma_f32_16x16x32_bf16(ak0, bq[qt][0], s, 0, 0, 0);
                s = __builtin_amdgcn_mfma_f32_16x16x32_bf16(ak1, bq[qt][1], s, 0, 0, 0);
                bf16x4 pk;
#pragma unroll
                for (int r = 0; r < 4; ++r) {
                    float p = __builtin_amdgcn_exp2f(s[r]);
                    vsum[qt] += p;
                    pk[r] = (bf16_t)p;
                }
                *(bf16x4*)&Ps[w][qt * 16 + l16][skt * 16 + quad * 4] = pk;
            }
        }
        __threadfence_block();

        bf16x8 bv[4][2];
#pragma unroll
        for (int dt = 0; dt < 4; ++dt) {
            bv[dt][0] = *(const bf16x8*)&Vts[cur][0][dt * 16 + l16][qsw];
            bv[dt][1] = *(const bf16x8*)&Vts[cur][1][dt * 16 + l16][qsw];
        }
#pragma unroll
        for (int qt = 0; qt < 2; ++qt) {
#pragma unroll
            for (int kc = 0; kc < 2; ++kc) {
                bf16x8 ap = *(const bf16x8*)&Ps[w][qt * 16 + l16][kc * 32 + quad * 8];
#pragma unroll
                for (int dt = 0; dt < 4; ++dt)
                    acc[qt][dt] = __builtin_amdgcn_mfma_f32_16x16x32_bf16(ap, bv[dt][kc], acc[qt][dt], 0, 0, 0);
            }
        }
    }

#pragma unroll
    for (int qt = 0; qt < 2; ++qt) {
        vsum[qt] += __shfl_xor(vsum[qt], 16, 64);
        vsum[qt] += __shfl_xor(vsum[qt], 32, 64);
        if (quad == 0)
            vs[(rowbase + qw + qt * 16 + l16) * HEADS + h] = vsum[qt];
    }

#pragma unroll
    for (int qt = 0; qt < 2; ++qt)
#pragma unroll
        for (int dt = 0; dt < 4; ++dt)
#pragma unroll
            for (int r = 0; r < 4; ++r) {
                size_t row = rowbase + qw + qt * 16 + quad * 4 + r;
                Op[row * LATENT + h * HD + dt * 16 + l16] = acc[qt][dt][r];
            }
}

// ---------------------------------------------------------------------------
// Combine the two attention split-K partials -> bf16
// ---------------------------------------------------------------------------
__global__ __launch_bounds__(256) void attn_combine(const float* __restrict__ Op0,
                                                    const float* __restrict__ Op1,
                                                    const float* __restrict__ vs0,
                                                    const float* __restrict__ vs1,
                                                    bf16_t* __restrict__ O) {
    int row = blockIdx.x;
    int t = threadIdx.x;
    const float* a = Op0 + (size_t)row * LATENT;
    const float* bb = Op1 + (size_t)row * LATENT;
#pragma unroll
    for (int i = 0; i < 3; ++i) {
        int c = t + i * 256;
        int h = c >> 6;
        float denom = vs0[(size_t)row * HEADS + h] + vs1[(size_t)row * HEADS + h];
        O[(size_t)row * LATENT + c] = (bf16_t)((a[c] + bb[c]) / denom);
    }
}

// ---------------------------------------------------------------------------
// Fused residual + LayerNorm; NADD extra f32 addend streams (NADD=4 consumes
// the FFN2 split-K partials, removing a separate combine pass).
// ---------------------------------------------------------------------------
template<int NADD>
__global__ __launch_bounds__(256) void ln_residual(const float* __restrict__ base,
                                                   const float* __restrict__ a1,
                                                   const float* __restrict__ a2,
                                                   const float* __restrict__ a3,
                                                   const float* __restrict__ a4,
                                                   const float* __restrict__ g,
                                                   const float* __restrict__ bta,
                                                   float* __restrict__ outf,
                                                   bf16_t* __restrict__ outb) {
    int row = blockIdx.x;
    size_t ro = (size_t)row * LATENT;
    int t = threadIdx.x;
    float v[3];
    float s = 0.f;
#pragma unroll
    for (int i = 0; i < 3; ++i) {
        int cix = t + i * 256;
        float x = base[ro + cix] + a1[ro + cix];
        if (NADD >= 2) x += a2[ro + cix];
        if (NADD >= 3) x += a3[ro + cix];
        if (NADD >= 4) x += a4[ro + cix];
        v[i] = x;
        s += x;
    }
    __shared__ float red[4];
#pragma unroll
    for (int off = 1; off < 64; off <<= 1) s += __shfl_xor(s, off, 64);
    if ((t & 63) == 0) red[t >> 6] = s;
    __syncthreads();
    float mu = (red[0] + red[1] + red[2] + red[3]) * (1.f / LATENT);
    float q = 0.f;
#pragma unroll
    for (int i = 0; i < 3; ++i) {
        float d = v[i] - mu;
        q += d * d;
    }
#pragma unroll
    for (int off = 1; off < 64; off <<= 1) q += __shfl_xor(q, off, 64);
    __syncthreads();
    if ((t & 63) == 0) red[t >> 6] = q;
    __syncthreads();
    float var = (red[0] + red[1] + red[2] + red[3]) * (1.f / LATENT);
    float rs = rsqrtf(var + 1e-5f);
#pragma unroll
    for (int i = 0; i < 3; ++i) {
        int cix = t + i * 256;
        float o = (v[i] - mu) * rs * g[cix] + bta[cix];
        outf[ro + cix] = o;
        if (outb) outb[ro + cix] = (bf16_t)o;
    }
}

// ---------------------------------------------------------------------------
extern "C" void kernel_launch(void* const* d_in, const int* in_sizes, int n_in,
                              void* d_out, int out_size, void* d_ws, size_t ws_size,
                              hipStream_t stream) {
    const float* x   = (const float*)d_in[0];
    const float* Wq  = (const float*)d_in[1];
    const float* bq  = (const float*)d_in[2];
    const float* Wk  = (const float*)d_in[3];
    const float* bk  = (const float*)d_in[4];
    const float* Wv  = (const float*)d_in[5];
    const float* bv  = (const float*)d_in[6];
    const float* Wo  = (const float*)d_in[7];
    const float* bo  = (const float*)d_in[8];
    const float* g1  = (const float*)d_in[9];
    const float* be1 = (const float*)d_in[10];
    const float* g2  = (const float*)d_in[11];
    const float* be2 = (const float*)d_in[12];
    const float* W1  = (const float*)d_in[13];
    const float* b1  = (const float*)d_in[14];
    const float* W2  = (const float*)d_in[15];
    const float* b2  = (const float*)d_in[16];
    float* out = (float*)d_out;

    char* ws = (char*)d_ws;
    size_t off = 0;
    auto alloc = [&](size_t bytes) {
        char* p = ws + off;
        off = (off + bytes + 255) & ~(size_t)255;
        return p;
    };
    bf16_t* xbf   = (bf16_t*)alloc((size_t)NTOK * LATENT * 2);
    bf16_t* Wcat  = (bf16_t*)alloc((size_t)3 * LATENT * LATENT * 2);
    bf16_t* Wobf  = (bf16_t*)alloc((size_t)LATENT * LATENT * 2);
    bf16_t* W1bf  = (bf16_t*)alloc((size_t)FFN_DIM * LATENT * 2);
    bf16_t* W2bf  = (bf16_t*)alloc((size_t)LATENT * FFN_DIM * 2);
    float*  bcat  = (float*)alloc((size_t)3 * LATENT * 4);
    bf16_t* QKV   = (bf16_t*)alloc((size_t)NTOK * 3 * LATENT * 2);
    bf16_t* attnO = (bf16_t*)alloc((size_t)NTOK * LATENT * 2);
    float*  tmpf  = (float*)alloc((size_t)NTOK * LATENT * 4);
    float*  y1f   = (float*)alloc((size_t)NTOK * LATENT * 4);
    bf16_t* y1bf  = (bf16_t*)alloc((size_t)NTOK * LATENT * 2);
    bf16_t* hbf   = (bf16_t*)alloc((size_t)NTOK * FFN_DIM * 2);
    float*  vsa   = (float*)alloc((size_t)NTOK * HEADS * 4);
    float*  vsb   = (float*)alloc((size_t)NTOK * HEADS * 4);
    float*  P3    = (float*)alloc((size_t)NTOK * LATENT * 4);   // 4th FFN2 partial
    bf16_t* Vtg   = (bf16_t*)hbf;   // alias: Vt lifetime disjoint from h
    float*  Oa    = tmpf;           // attn partial 0 (consumed before Wo writes tmpf)
    float*  Ob    = y1f;            // attn partial 1 (consumed before ln1 writes y1f)
    // FFN2 split-K partials (all dead regions at FFN2 time):
    float* P0 = tmpf;
    float* P1 = (float*)QKV;
    float* P2 = (float*)xbf;

    // 1. convert to bf16 + bias concat (seg 7)
    CvtDesc cd;
    cd.src[0] = x;   cd.dst[0] = xbf;                        cd.n4[0] = NTOK * LATENT / 4;
    cd.src[1] = Wq;  cd.dst[1] = Wcat;                       cd.n4[1] = LATENT * LATENT / 4;
    cd.src[2] = Wk;  cd.dst[2] = Wcat + LATENT * LATENT;     cd.n4[2] = LATENT * LATENT / 4;
    cd.src[3] = Wv;  cd.dst[3] = Wcat + 2 * LATENT * LATENT; cd.n4[3] = LATENT * LATENT / 4;
    cd.src[4] = Wo;  cd.dst[4] = Wobf;                       cd.n4[4] = LATENT * LATENT / 4;
    cd.src[5] = W1;  cd.dst[5] = W1bf;                       cd.n4[5] = FFN_DIM * LATENT / 4;
    cd.src[6] = W2;  cd.dst[6] = W2bf;                       cd.n4[6] = FFN_DIM * LATENT / 4;
    cd.bsrc[0] = bq; cd.bsrc[1] = bk; cd.bsrc[2] = bv;
    cd.bdst = bcat;
    {
        int maxn4 = NTOK * LATENT / 4;
        dim3 grid((maxn4 + 255) / 256, 8);
        cvt_f32_bf16<<<grid, 256, 0, stream>>>(cd);
    }

    // 2. fused QKV GEMM; Q region pre-scaled by C2 (EPI=3). 512 thr / 8 waves.
    gemm128<3><<<dim3(NTOK / 128, 3 * LATENT / 128), 512, 0, stream>>>(
        xbf, Wcat, bcat, QKV, NTOK, 3 * LATENT, LATENT);

    // 2.5 V transpose
    v_transpose<<<dim3(SEQ / 64, 2 * HEADS), 256, 0, stream>>>(QKV, Vtg);

    // 3. attention: S^T scheme, 768 blocks x 4 waves (128 q each), split-K x2
    attn_flash<<<dim3(2 * HEADS, SEQ / 128, 2), 256, 0, stream>>>(QKV, Vtg, Oa, Ob, vsa, vsb);

    // 3.5 combine partials -> bf16
    attn_combine<<<NTOK, 256, 0, stream>>>(Oa, Ob, vsa, vsb, attnO);

    // 4. output projection: 64x64 tiles, 768 blocks x 4 waves
    gemm64<0><<<dim3(NTOK / 64, LATENT / 64), 256, 0, stream>>>(
        attnO, Wobf, bo, tmpf, NTOK, LATENT, LATENT);

    // 5. y1 = LN(x + proj)
    ln_residual<1><<<NTOK, 256, 0, stream>>>(x, tmpf, nullptr, nullptr, nullptr,
                                             g1, be1, y1f, y1bf);

    // 6. h = gelu(y1 @ W1^T + b1). 512 thr / 8 waves.
    gemm128<2><<<dim3(NTOK / 128, FFN_DIM / 128), 512, 0, stream>>>(
        y1bf, W1bf, b1, hbf, NTOK, FFN_DIM, LATENT);

    // 7. ffn partials = h @ W2^T + b2, 128x128 split-K x4: 768 blocks = 3/CU
    SKDst skd;
    skd.p[0] = P0; skd.p[1] = P1; skd.p[2] = P2; skd.p[3] = P3;
    gemm128sk<<<dim3(NTOK / 128, LATENT / 128, 4), 512, 0, stream>>>(
        hbf, W2bf, b2, skd, NTOK, LATENT, FFN_DIM);

    // 8. out = LN(y1 + P0 + P1 + P2 + P3)
    ln_residual<4><<<NTOK, 256, 0, stream>>>(y1f, P0, P1, P2, P3,
                                             g2, be2, out, nullptr);
}

// Round 12
// 290.361 us; speedup vs baseline: 1.1830x; 1.0042x over previous
//
#include <hip/hip_runtime.h>
#include <hip/hip_bf16.h>
#include <cstddef>
#include <cstdint>

typedef __bf16 bf16_t;
typedef bf16_t bf16x8 __attribute__((ext_vector_type(8)));
typedef bf16_t bf16x4 __attribute__((ext_vector_type(4)));
typedef float f32x4 __attribute__((ext_vector_type(4)));

#define LATENT 768
#define FFN_DIM 3072
#define NTOK 4096      // 2*2048
#define SEQ 2048
#define HEADS 12
#define HD 64

#define C2F 0.18033688011112042f   // 0.125 * log2(e)

__device__ __forceinline__ void gload_lds16(const bf16_t* g, bf16_t* l) {
    __builtin_amdgcn_global_load_lds((const __attribute__((address_space(1))) void*)g,
                                     (__attribute__((address_space(3))) void*)l, 16, 0, 0);
}

// r9 LDS XOR-swizzle for [N][32]bf16 (64B-row) tiles read by ds_read_b128:
// verified r10: attn conflicts 5.5M -> 2.36M (remaining = benign 2-way floor),
// attn 47.5 -> 43.7us. Physical slot p at row r holds logical p^((r>>1)&3).
// WRITE side: global_load_lds writes linearly -> SOURCE address pre-swizzled
// (m173). READ side: quad' = quad ^ ((l16>>1)&3), loop-invariant.
#define SW_SRC(lane)  ((((lane) & 3) ^ (((lane) >> 3) & 3)) * 8)
#define SW_RD(quad, l16)  (((quad) ^ (((l16) >> 1) & 3)) * 8)

// ---------------------------------------------------------------------------
// fp32 -> bf16 conversion, multi-segment; segment 7 = f32 bias concat (bq|bk|bv)
// ---------------------------------------------------------------------------
struct CvtDesc {
    const float* src[7];
    bf16_t* dst[7];
    int n4[7];
    const float* bsrc[3];
    float* bdst;
};

__global__ __launch_bounds__(256) void cvt_f32_bf16(CvtDesc d) {
    int seg = blockIdx.y;
    if (seg == 7) {   // bias concat: 3 blocks x 768 floats
        int which = blockIdx.x;
        if (which >= 3) return;
        int t = threadIdx.x;
#pragma unroll
        for (int i = 0; i < 3; ++i)
            d.bdst[which * LATENT + t + i * 256] = d.bsrc[which][t + i * 256];
        return;
    }
    int i = blockIdx.x * 256 + threadIdx.x;
    if (i >= d.n4[seg]) return;
    float4 v = ((const float4*)d.src[seg])[i];
    bf16x4 o;
    o[0] = (bf16_t)v.x; o[1] = (bf16_t)v.y; o[2] = (bf16_t)v.z; o[3] = (bf16_t)v.w;
    *(bf16x4*)&d.dst[seg][(size_t)i * 4] = o;
}

// ---------------------------------------------------------------------------
// GEMM 128x128, 512 thr = 8 waves. Wave (wm=w&1, wn=w>>1) owns 64x32 out.
// Diagonal remap (r4). LDS swizzle (r9).
// EPI: 0 none->f32, 2 exact-GELU->bf16, 3 bf16 + C2F scale on cols<LATENT.
// ---------------------------------------------------------------------------
template<int EPI>
__global__ __launch_bounds__(512) void gemm128(const bf16_t* __restrict__ A,
                                               const bf16_t* __restrict__ B,
                                               const float* __restrict__ bias,
                                               void* __restrict__ Cv,
                                               int M, int N, int K) {
    __shared__ __align__(16) bf16_t As[2][128 * 32];
    __shared__ __align__(16) bf16_t Bs[2][128 * 32];
    int t = threadIdx.x;
    int w = t >> 6;                           // 0..7
    int lane = t & 63, l16 = lane & 15, quad = lane >> 4;
    int xt = blockIdx.x + blockIdx.y;         // diagonal remap
    if (xt >= (int)gridDim.x) xt -= gridDim.x;
    int m0 = xt * 128, n0 = blockIdx.y * 128;
    int wm = w & 1, wn = w >> 1;              // 2M x 4N wave grid
    int mrow0 = wm * 64, ncol0 = wn * 32;

    f32x4 acc[4][2] = {};

    int srow = lane >> 2;                     // 0..15
    int sseg = SW_SRC(lane);
    int qsw  = SW_RD(quad, l16);

    auto stage = [&](int k0, int buf) {
        const bf16_t* Ag = A + (size_t)(m0 + w * 16 + srow) * K + k0 + sseg;
        gload_lds16(Ag, &As[buf][(w * 16) * 32]);
        const bf16_t* Bg = B + (size_t)(n0 + w * 16 + srow) * K + k0 + sseg;
        gload_lds16(Bg, &Bs[buf][(w * 16) * 32]);
    };

    int niter = K / 32;
    stage(0, 0);
    for (int kt = 0; kt < niter; ++kt) {
        __syncthreads();   // drains prev prefetch (vmcnt0) + readers of other buf
        int cur = kt & 1;
        if (kt + 1 < niter) stage((kt + 1) * 32, cur ^ 1);

        bf16x8 a[4], b[2];
#pragma unroll
        for (int i = 0; i < 4; ++i)
            a[i] = *(const bf16x8*)&As[cur][(mrow0 + i * 16 + l16) * 32 + qsw];
#pragma unroll
        for (int j = 0; j < 2; ++j)
            b[j] = *(const bf16x8*)&Bs[cur][(ncol0 + j * 16 + l16) * 32 + qsw];
#pragma unroll
        for (int i = 0; i < 4; ++i)
#pragma unroll
            for (int j = 0; j < 2; ++j)
                acc[i][j] = __builtin_amdgcn_mfma_f32_16x16x32_bf16(a[i], b[j], acc[i][j], 0, 0, 0);
    }

    float* Cf = (float*)Cv;
    bf16_t* Cb = (bf16_t*)Cv;
#pragma unroll
    for (int j = 0; j < 2; ++j) {
        int col = n0 + ncol0 + j * 16 + l16;
        float bvv = bias[col];
#pragma unroll
        for (int i = 0; i < 4; ++i) {
            int row0 = m0 + mrow0 + i * 16 + quad * 4;
#pragma unroll
            for (int r = 0; r < 4; ++r) {
                float v = acc[i][j][r] + bvv;
                if (EPI == 2) v = 0.5f * v * (1.0f + erff(v * 0.70710678118654752f));
                if (EPI == 3) { if (col < LATENT) v *= C2F; }
                if (EPI == 0) Cf[(size_t)(row0 + r) * N + col] = v;
                else          Cb[(size_t)(row0 + r) * N + col] = (bf16_t)v;
            }
        }
    }
}

// ---------------------------------------------------------------------------
// GEMM 128x128 SPLIT-K x4 for FFN2 (r7). grid (32,6,4)=768 blocks = 3/CU,
// 24 iterations/block, f32 partials summed in the final LN. Identity tile
// map (bx%8 = per-XCD A-partitioning). LDS swizzle (r9).
// ---------------------------------------------------------------------------
struct SKDst { float* p[4]; };

__global__ __launch_bounds__(512) void gemm128sk(const bf16_t* __restrict__ A,
                                                 const bf16_t* __restrict__ B,
                                                 const float* __restrict__ bias,
                                                 SKDst dst,
                                                 int M, int N, int Ktot) {
    __shared__ __align__(16) bf16_t As[2][128 * 32];
    __shared__ __align__(16) bf16_t Bs[2][128 * 32];
    int t = threadIdx.x;
    int w = t >> 6;                           // 0..7
    int lane = t & 63, l16 = lane & 15, quad = lane >> 4;
    int z = blockIdx.z;
    int KS = Ktot >> 2;                       // per-split K
    int kbase = z * KS;
    int m0 = blockIdx.x * 128, n0 = blockIdx.y * 128;
    int wm = w & 1, wn = w >> 1;
    int mrow0 = wm * 64, ncol0 = wn * 32;

    f32x4 acc[4][2] = {};

    int srow = lane >> 2;
    int sseg = SW_SRC(lane);
    int qsw  = SW_RD(quad, l16);

    auto stage = [&](int k0, int buf) {
        const bf16_t* Ag = A + (size_t)(m0 + w * 16 + srow) * Ktot + kbase + k0 + sseg;
        gload_lds16(Ag, &As[buf][(w * 16) * 32]);
        const bf16_t* Bg = B + (size_t)(n0 + w * 16 + srow) * Ktot + kbase + k0 + sseg;
        gload_lds16(Bg, &Bs[buf][(w * 16) * 32]);
    };

    int niter = KS / 32;                      // 24 for FFN2
    stage(0, 0);
    for (int kt = 0; kt < niter; ++kt) {
        __syncthreads();
        int cur = kt & 1;
        if (kt + 1 < niter) stage((kt + 1) * 32, cur ^ 1);

        bf16x8 a[4], b[2];
#pragma unroll
        for (int i = 0; i < 4; ++i)
            a[i] = *(const bf16x8*)&As[cur][(mrow0 + i * 16 + l16) * 32 + qsw];
#pragma unroll
        for (int j = 0; j < 2; ++j)
            b[j] = *(const bf16x8*)&Bs[cur][(ncol0 + j * 16 + l16) * 32 + qsw];
#pragma unroll
        for (int i = 0; i < 4; ++i)
#pragma unroll
            for (int j = 0; j < 2; ++j)
                acc[i][j] = __builtin_amdgcn_mfma_f32_16x16x32_bf16(a[i], b[j], acc[i][j], 0, 0, 0);
    }

    float* Cf = dst.p[z];
#pragma unroll
    for (int j = 0; j < 2; ++j) {
        int col = n0 + ncol0 + j * 16 + l16;
        float bvv = (z == 0) ? bias[col] : 0.f;
#pragma unroll
        for (int i = 0; i < 4; ++i) {
            int row0 = m0 + mrow0 + i * 16 + quad * 4;
#pragma unroll
            for (int r = 0; r < 4; ++r)
                Cf[(size_t)(row0 + r) * N + col] = acc[i][j][r] + bvv;
        }
    }
}

// ---------------------------------------------------------------------------
// GEMM 64x64 tile, 256 thr = 4 waves (2Mx2N). Identity tile mapping (r4).
// Used for Wo (K=768). LDS swizzle (r9).
// ---------------------------------------------------------------------------
template<int EPI>
__global__ __launch_bounds__(256) void gemm64(const bf16_t* __restrict__ A,
                                              const bf16_t* __restrict__ B,
                                              const float* __restrict__ bias,
                                              void* __restrict__ Cv,
                                              int M, int N, int K) {
    __shared__ __align__(16) bf16_t As[2][64 * 32];
    __shared__ __align__(16) bf16_t Bs[2][64 * 32];
    int t = threadIdx.x;
    int w = t >> 6;                  // 0..3
    int lane = t & 63, l16 = lane & 15, quad = lane >> 4;
    int m0 = blockIdx.x * 64, n0 = blockIdx.y * 64;
    int wm = w & 1, wn = w >> 1;     // 2M x 2N wave grid

    f32x4 acc[2][2] = {};

    int srow = lane >> 2;
    int sseg = SW_SRC(lane);
    int qsw  = SW_RD(quad, l16);

    auto stage = [&](int k0, int buf) {
        const bf16_t* Ag = A + (size_t)(m0 + w * 16 + srow) * K + k0 + sseg;
        gload_lds16(Ag, &As[buf][(w * 16) * 32]);
        const bf16_t* Bg = B + (size_t)(n0 + w * 16 + srow) * K + k0 + sseg;
        gload_lds16(Bg, &Bs[buf][(w * 16) * 32]);
    };

    int niter = K / 32;
    stage(0, 0);
    for (int kt = 0; kt < niter; ++kt) {
        __syncthreads();
        int cur = kt & 1;
        if (kt + 1 < niter) stage((kt + 1) * 32, cur ^ 1);

        bf16x8 a[2], b[2];
#pragma unroll
        for (int i = 0; i < 2; ++i)
            a[i] = *(const bf16x8*)&As[cur][(wm * 32 + i * 16 + l16) * 32 + qsw];
#pragma unroll
        for (int j = 0; j < 2; ++j)
            b[j] = *(const bf16x8*)&Bs[cur][(wn * 32 + j * 16 + l16) * 32 + qsw];
#pragma unroll
        for (int i = 0; i < 2; ++i)
#pragma unroll
            for (int j = 0; j < 2; ++j)
                acc[i][j] = __builtin_amdgcn_mfma_f32_16x16x32_bf16(a[i], b[j], acc[i][j], 0, 0, 0);
    }

    float* Cf = (float*)Cv;
    bf16_t* Cb = (bf16_t*)Cv;
#pragma unroll
    for (int j = 0; j < 2; ++j) {
        int col = n0 + wn * 32 + j * 16 + l16;
        float bvv = bias[col];
#pragma unroll
        for (int i = 0; i < 2; ++i) {
            int row0 = m0 + wm * 32 + i * 16 + quad * 4;
#pragma unroll
            for (int r = 0; r < 4; ++r) {
                float v = acc[i][j][r] + bvv;
                if (EPI == 2) v = 0.5f * v * (1.0f + erff(v * 0.70710678118654752f));
                if (EPI == 0) Cf[(size_t)(row0 + r) * N + col] = v;
                else          Cb[(size_t)(row0 + r) * N + col] = (bf16_t)v;
            }
        }
    }
}

// ---------------------------------------------------------------------------
// V transpose: QKV V-part [b, n, h, d] -> Vt [b, h, d, n]
// ---------------------------------------------------------------------------
__global__ __launch_bounds__(256) void v_transpose(const bf16_t* __restrict__ QKV,
                                                   bf16_t* __restrict__ Vt) {
    __shared__ bf16_t Ts[64][68];
    int t = threadIdx.x;
    int bh = blockIdx.y;
    int b = bh / HEADS, h = bh % HEADS;
    int n0 = blockIdx.x * 64;
    size_t rowbase = (size_t)b * SEQ;
    int r = t >> 3, seg = (t & 7) * 8;
#pragma unroll
    for (int i = 0; i < 2; ++i) {
        int rr = r + i * 32;
        *(bf16x8*)&Ts[rr][seg] =
            *(const bf16x8*)&QKV[(rowbase + n0 + rr) * (3 * LATENT) + 2 * LATENT + h * HD + seg];
    }
    __syncthreads();
#pragma unroll
    for (int i = 0; i < 2; ++i) {
        int d = r + i * 32;
        bf16x8 o;
#pragma unroll
        for (int jj = 0; jj < 8; ++jj) o[jj] = Ts[seg + jj][d];
        *(bf16x8*)&Vt[((size_t)bh * HD + d) * SEQ + n0 + seg] = o;
    }
}

// ---------------------------------------------------------------------------
// Flash attention (S^T formulation). r11: NO split-K — each block owns 64
// q-rows (4 waves x 16 q) and walks all 2048 keys (32 k-tiles); epilogue
// divides by vsum and writes bf16 directly. Eliminates attn_combine and
// ~44MB of f32 partial round-trip traffic (attn WRITE 27MB -> ~7MB).
// grid (24,32) = 768 blocks = 3/CU (r6 occupancy preserved). LDS ~41.5KB.
// K/V LDS XOR-swizzled (r9/r10: conflicts 5.5M->2.36M).
// ---------------------------------------------------------------------------
__global__ __launch_bounds__(256) void attn_flash(const bf16_t* __restrict__ QKV,
                                                  const bf16_t* __restrict__ Vt,
                                                  bf16_t* __restrict__ O) {
    __shared__ __align__(16) bf16_t Ks[2][2][64][32];    // [buf][d-chunk][key][d32]
    __shared__ __align__(16) bf16_t Vts[2][2][64][32];   // [buf][key-chunk][d][key32]
    __shared__ __align__(16) bf16_t Ps[4][16][72];       // [wave][q][key]

    int t = threadIdx.x;
    int w = t >> 6;
    int lane = t & 63, l16 = lane & 15, quad = lane >> 4;
    int bh = blockIdx.x;
    int b = bh / HEADS, h = bh % HEADS;
    int qblk = blockIdx.y * 64;
    size_t rowbase = (size_t)b * SEQ;
    const int LD = 3 * LATENT;
    int qw = qblk + w * 16;

    bf16x8 bq[2];
    {
        const bf16_t* qrow = QKV + (rowbase + qw + l16) * LD + h * HD;
        bq[0] = *(const bf16x8*)&qrow[quad * 8];
        bq[1] = *(const bf16x8*)&qrow[32 + quad * 8];
    }

    f32x4 acc[4] = {};    // [dt]
    float vsum = 0.f;

    int srow = lane >> 2;
    int sseg = SW_SRC(lane);
    int qsw  = SW_RD(quad, l16);

    auto stage = [&](int koff, int buf) {
        const bf16_t* kg = QKV + (rowbase + koff + w * 16 + srow) * LD + LATENT + h * HD + sseg;
        gload_lds16(kg,      &Ks[buf][0][w * 16][0]);
        gload_lds16(kg + 32, &Ks[buf][1][w * 16][0]);
        const bf16_t* vg = Vt + ((size_t)bh * HD + w * 16 + srow) * SEQ + koff + sseg;
        gload_lds16(vg,      &Vts[buf][0][w * 16][0]);
        gload_lds16(vg + 32, &Vts[buf][1][w * 16][0]);
    };

    stage(0, 0);

    const int NKT = SEQ / 64;          // 32 k-tiles of 64 keys
    for (int kt = 0; kt < NKT; ++kt) {
        __syncthreads();
        int cur = kt & 1;
        if (kt + 1 < NKT) stage((kt + 1) * 64, cur ^ 1);

#pragma unroll
        for (int skt = 0; skt < 4; ++skt) {
            bf16x8 ak0 = *(const bf16x8*)&Ks[cur][0][skt * 16 + l16][qsw];
            bf16x8 ak1 = *(const bf16x8*)&Ks[cur][1][skt * 16 + l16][qsw];
            f32x4 s = {};
            s = __builtin_amdgcn_mfma_f32_16x16x32_bf16(ak0, bq[0], s, 0, 0, 0);
            s = __builtin_amdgcn_mfma_f32_16x16x32_bf16(ak1, bq[1], s, 0, 0, 0);
            bf16x4 pk;
#pragma unroll
            for (int r = 0; r < 4; ++r) {
                float p = __builtin_amdgcn_exp2f(s[r]);
                vsum += p;
                pk[r] = (bf16_t)p;
            }
            *(bf16x4*)&Ps[w][l16][skt * 16 + quad * 4] = pk;
        }
        __threadfence_block();

        bf16x8 bv[4][2];
#pragma unroll
        for (int dt = 0; dt < 4; ++dt) {
            bv[dt][0] = *(const bf16x8*)&Vts[cur][0][dt * 16 + l16][qsw];
            bv[dt][1] = *(const bf16x8*)&Vts[cur][1][dt * 16 + l16][qsw];
        }
#pragma unroll
        for (int kc = 0; kc < 2; ++kc) {
            bf16x8 ap = *(const bf16x8*)&Ps[w][l16][kc * 32 + quad * 8];
#pragma unroll
            for (int dt = 0; dt < 4; ++dt)
                acc[dt] = __builtin_amdgcn_mfma_f32_16x16x32_bf16(ap, bv[dt][kc], acc[dt], 0, 0, 0);
        }
    }

    // vsum: reduce across quads (all lanes then hold total for q = l16)
    vsum += __shfl_xor(vsum, 16, 64);
    vsum += __shfl_xor(vsum, 32, 64);
    // fetch this lane's 4 row-denominators (rows q = quad*4 + r)
    float dv[4];
#pragma unroll
    for (int r = 0; r < 4; ++r)
        dv[r] = __shfl(vsum, quad * 4 + r, 64);

#pragma unroll
    for (int dt = 0; dt < 4; ++dt)
#pragma unroll
        for (int r = 0; r < 4; ++r) {
            size_t row = rowbase + qw + quad * 4 + r;
            O[row * LATENT + h * HD + dt * 16 + l16] = (bf16_t)(acc[dt][r] / dv[r]);
        }
}

// ---------------------------------------------------------------------------
// Fused residual + LayerNorm; NADD extra f32 addend streams (NADD=4 consumes
// the FFN2 split-K partials, removing a separate combine pass).
// ---------------------------------------------------------------------------
template<int NADD>
__global__ __launch_bounds__(256) void ln_residual(const float* __restrict__ base,
                                                   const float* __restrict__ a1,
                                                   const float* __restrict__ a2,
                                                   const float* __restrict__ a3,
                                                   const float* __restrict__ a4,
                                                   const float* __restrict__ g,
                                                   const float* __restrict__ bta,
                                                   float* __restrict__ outf,
                                                   bf16_t* __restrict__ outb) {
    int row = blockIdx.x;
    size_t ro = (size_t)row * LATENT;
    int t = threadIdx.x;
    float v[3];
    float s = 0.f;
#pragma unroll
    for (int i = 0; i < 3; ++i) {
        int cix = t + i * 256;
        float x = base[ro + cix] + a1[ro + cix];
        if (NADD >= 2) x += a2[ro + cix];
        if (NADD >= 3) x += a3[ro + cix];
        if (NADD >= 4) x += a4[ro + cix];
        v[i] = x;
        s += x;
    }
    __shared__ float red[4];
#pragma unroll
    for (int off = 1; off < 64; off <<= 1) s += __shfl_xor(s, off, 64);
    if ((t & 63) == 0) red[t >> 6] = s;
    __syncthreads();
    float mu = (red[0] + red[1] + red[2] + red[3]) * (1.f / LATENT);
    float q = 0.f;
#pragma unroll
    for (int i = 0; i < 3; ++i) {
        float d = v[i] - mu;
        q += d * d;
    }
#pragma unroll
    for (int off = 1; off < 64; off <<= 1) q += __shfl_xor(q, off, 64);
    __syncthreads();
    if ((t & 63) == 0) red[t >> 6] = q;
    __syncthreads();
    float var = (red[0] + red[1] + red[2] + red[3]) * (1.f / LATENT);
    float rs = rsqrtf(var + 1e-5f);
#pragma unroll
    for (int i = 0; i < 3; ++i) {
        int cix = t + i * 256;
        float o = (v[i] - mu) * rs * g[cix] + bta[cix];
        outf[ro + cix] = o;
        if (outb) outb[ro + cix] = (bf16_t)o;
    }
}

// ---------------------------------------------------------------------------
extern "C" void kernel_launch(void* const* d_in, const int* in_sizes, int n_in,
                              void* d_out, int out_size, void* d_ws, size_t ws_size,
                              hipStream_t stream) {
    const float* x   = (const float*)d_in[0];
    const float* Wq  = (const float*)d_in[1];
    const float* bq  = (const float*)d_in[2];
    const float* Wk  = (const float*)d_in[3];
    const float* bk  = (const float*)d_in[4];
    const float* Wv  = (const float*)d_in[5];
    const float* bv  = (const float*)d_in[6];
    const float* Wo  = (const float*)d_in[7];
    const float* bo  = (const float*)d_in[8];
    const float* g1  = (const float*)d_in[9];
    const float* be1 = (const float*)d_in[10];
    const float* g2  = (const float*)d_in[11];
    const float* be2 = (const float*)d_in[12];
    const float* W1  = (const float*)d_in[13];
    const float* b1  = (const float*)d_in[14];
    const float* W2  = (const float*)d_in[15];
    const float* b2  = (const float*)d_in[16];
    float* out = (float*)d_out;

    char* ws = (char*)d_ws;
    size_t off = 0;
    auto alloc = [&](size_t bytes) {
        char* p = ws + off;
        off = (off + bytes + 255) & ~(size_t)255;
        return p;
    };
    bf16_t* xbf   = (bf16_t*)alloc((size_t)NTOK * LATENT * 2);
    bf16_t* Wcat  = (bf16_t*)alloc((size_t)3 * LATENT * LATENT * 2);
    bf16_t* Wobf  = (bf16_t*)alloc((size_t)LATENT * LATENT * 2);
    bf16_t* W1bf  = (bf16_t*)alloc((size_t)FFN_DIM * LATENT * 2);
    bf16_t* W2bf  = (bf16_t*)alloc((size_t)LATENT * FFN_DIM * 2);
    float*  bcat  = (float*)alloc((size_t)3 * LATENT * 4);
    bf16_t* QKV   = (bf16_t*)alloc((size_t)NTOK * 3 * LATENT * 2);
    bf16_t* attnO = (bf16_t*)alloc((size_t)NTOK * LATENT * 2);
    float*  tmpf  = (float*)alloc((size_t)NTOK * LATENT * 4);
    float*  y1f   = (float*)alloc((size_t)NTOK * LATENT * 4);
    bf16_t* y1bf  = (bf16_t*)alloc((size_t)NTOK * LATENT * 2);
    bf16_t* hbf   = (bf16_t*)alloc((size_t)NTOK * FFN_DIM * 2);
    float*  P3    = (float*)alloc((size_t)NTOK * LATENT * 4);   // 4th FFN2 partial
    bf16_t* Vtg   = (bf16_t*)hbf;   // alias: Vt lifetime disjoint from h
    // FFN2 split-K partials (all dead regions at FFN2 time):
    //   P0 = tmpf (dead after ln1), P1 = QKV (dead after attn),
    //   P2 = xbf..Wcat span (15.7MB, dead after QKV gemm), P3 dedicated.
    float* P0 = tmpf;
    float* P1 = (float*)QKV;
    float* P2 = (float*)xbf;

    // 1. convert to bf16 + bias concat (seg 7)
    CvtDesc cd;
    cd.src[0] = x;   cd.dst[0] = xbf;                        cd.n4[0] = NTOK * LATENT / 4;
    cd.src[1] = Wq;  cd.dst[1] = Wcat;                       cd.n4[1] = LATENT * LATENT / 4;
    cd.src[2] = Wk;  cd.dst[2] = Wcat + LATENT * LATENT;     cd.n4[2] = LATENT * LATENT / 4;
    cd.src[3] = Wv;  cd.dst[3] = Wcat + 2 * LATENT * LATENT; cd.n4[3] = LATENT * LATENT / 4;
    cd.src[4] = Wo;  cd.dst[4] = Wobf;                       cd.n4[4] = LATENT * LATENT / 4;
    cd.src[5] = W1;  cd.dst[5] = W1bf;                       cd.n4[5] = FFN_DIM * LATENT / 4;
    cd.src[6] = W2;  cd.dst[6] = W2bf;                       cd.n4[6] = FFN_DIM * LATENT / 4;
    cd.bsrc[0] = bq; cd.bsrc[1] = bk; cd.bsrc[2] = bv;
    cd.bdst = bcat;
    {
        int maxn4 = NTOK * LATENT / 4;
        dim3 grid((maxn4 + 255) / 256, 8);
        cvt_f32_bf16<<<grid, 256, 0, stream>>>(cd);
    }

    // 2. fused QKV GEMM; Q region pre-scaled by C2 (EPI=3). 512 thr / 8 waves.
    gemm128<3><<<dim3(NTOK / 128, 3 * LATENT / 128), 512, 0, stream>>>(
        xbf, Wcat, bcat, QKV, NTOK, 3 * LATENT, LATENT);

    // 2.5 V transpose
    v_transpose<<<dim3(SEQ / 64, 2 * HEADS), 256, 0, stream>>>(QKV, Vtg);

    // 3. attention: no split-K, 768 blocks x 4 waves (64 q each), bf16 out
    attn_flash<<<dim3(2 * HEADS, SEQ / 64), 256, 0, stream>>>(QKV, Vtg, attnO);

    // 4. output projection: 64x64 tiles, 768 blocks x 4 waves
    gemm64<0><<<dim3(NTOK / 64, LATENT / 64), 256, 0, stream>>>(
        attnO, Wobf, bo, tmpf, NTOK, LATENT, LATENT);

    // 5. y1 = LN(x + proj)
    ln_residual<1><<<NTOK, 256, 0, stream>>>(x, tmpf, nullptr, nullptr, nullptr,
                                             g1, be1, y1f, y1bf);

    // 6. h = gelu(y1 @ W1^T + b1). 512 thr / 8 waves.
    gemm128<2><<<dim3(NTOK / 128, FFN_DIM / 128), 512, 0, stream>>>(
        y1bf, W1bf, b1, hbf, NTOK, FFN_DIM, LATENT);

    // 7. ffn partials = h @ W2^T + b2, 128x128 split-K x4: 768 blocks = 3/CU
    SKDst skd;
    skd.p[0] = P0; skd.p[1] = P1; skd.p[2] = P2; skd.p[3] = P3;
    gemm128sk<<<dim3(NTOK / 128, LATENT / 128, 4), 512, 0, stream>>>(
        hbf, W2bf, b2, skd, NTOK, LATENT, FFN_DIM);

    // 8. out = LN(y1 + P0 + P1 + P2 + P3)
    ln_residual<4><<<NTOK, 256, 0, stream>>>(y1f, P0, P1, P2, P3,
                                             g2, be2, out, nullptr);
}

// Round 13
// 286.087 us; speedup vs baseline: 1.2006x; 1.0149x over previous
//
#include <hip/hip_runtime.h>
#include <hip/hip_bf16.h>
#include <cstddef>
#include <cstdint>

typedef __bf16 bf16_t;
typedef bf16_t bf16x8 __attribute__((ext_vector_type(8)));
typedef bf16_t bf16x4 __attribute__((ext_vector_type(4)));
typedef float f32x4 __attribute__((ext_vector_type(4)));

#define LATENT 768
#define FFN_DIM 3072
#define NTOK 4096      // 2*2048
#define SEQ 2048
#define HEADS 12
#define HD 64

#define C2F 0.18033688011112042f   // 0.125 * log2(e)

__device__ __forceinline__ void gload_lds16(const bf16_t* g, bf16_t* l) {
    __builtin_amdgcn_global_load_lds((const __attribute__((address_space(1))) void*)g,
                                     (__attribute__((address_space(3))) void*)l, 16, 0, 0);
}

// r9 LDS XOR-swizzle for [N][32]bf16 (64B-row) tiles read by ds_read_b128:
// verified r10: attn conflicts 5.5M -> 2.36M, attn 47.5 -> 43.7us; r12: gemm
// conflicts 0. Physical slot p at row r holds logical p^((r>>1)&3).
// WRITE side: global_load_lds writes linearly -> SOURCE address pre-swizzled
// (m173). READ side: quad' = quad ^ ((l16>>1)&3), loop-invariant.
#define SW_SRC(lane)  ((((lane) & 3) ^ (((lane) >> 3) & 3)) * 8)
#define SW_RD(quad, l16)  (((quad) ^ (((l16) >> 1) & 3)) * 8)

// ---------------------------------------------------------------------------
// fp32 -> bf16 conversion, multi-segment; segment 7 = f32 bias concat (bq|bk|bv)
// ---------------------------------------------------------------------------
struct CvtDesc {
    const float* src[7];
    bf16_t* dst[7];
    int n4[7];
    const float* bsrc[3];
    float* bdst;
};

__global__ __launch_bounds__(256) void cvt_f32_bf16(CvtDesc d) {
    int seg = blockIdx.y;
    if (seg == 7) {   // bias concat: 3 blocks x 768 floats
        int which = blockIdx.x;
        if (which >= 3) return;
        int t = threadIdx.x;
#pragma unroll
        for (int i = 0; i < 3; ++i)
            d.bdst[which * LATENT + t + i * 256] = d.bsrc[which][t + i * 256];
        return;
    }
    int i = blockIdx.x * 256 + threadIdx.x;
    if (i >= d.n4[seg]) return;
    float4 v = ((const float4*)d.src[seg])[i];
    bf16x4 o;
    o[0] = (bf16_t)v.x; o[1] = (bf16_t)v.y; o[2] = (bf16_t)v.z; o[3] = (bf16_t)v.w;
    *(bf16x4*)&d.dst[seg][(size_t)i * 4] = o;
}

// ---------------------------------------------------------------------------
// GEMM 128x128, 512 thr = 8 waves. Wave (wm=w&1, wn=w>>1) owns 64x32 out.
// r13: IDENTITY tile mapping — the r4 diagonal remap is REMOVED. r12 FETCH
// arithmetic proved it duplicates B across all 8 XCDs (FFN1: 43.2MB =
// 8*B(4.7) + A(6.3); per-XCD set ~10MB >> 4MB L2 -> thrash, 62.6us). The
// r4 "win" was measured against a replay-inflated baseline (r5 lesson).
// Identity: per-XCD set = A/8 + B ~= 5.5MB, lockstep-streaming (cf. gemm64
// FFN2 identity: FETCH = A+B exactly). LDS swizzle (r9).
// EPI: 0 none->f32, 2 exact-GELU->bf16, 3 bf16 + C2F scale on cols<LATENT.
// ---------------------------------------------------------------------------
template<int EPI>
__global__ __launch_bounds__(512) void gemm128(const bf16_t* __restrict__ A,
                                               const bf16_t* __restrict__ B,
                                               const float* __restrict__ bias,
                                               void* __restrict__ Cv,
                                               int M, int N, int K) {
    __shared__ __align__(16) bf16_t As[2][128 * 32];
    __shared__ __align__(16) bf16_t Bs[2][128 * 32];
    int t = threadIdx.x;
    int w = t >> 6;                           // 0..7
    int lane = t & 63, l16 = lane & 15, quad = lane >> 4;
    int m0 = blockIdx.x * 128, n0 = blockIdx.y * 128;
    int wm = w & 1, wn = w >> 1;              // 2M x 4N wave grid
    int mrow0 = wm * 64, ncol0 = wn * 32;

    f32x4 acc[4][2] = {};

    int srow = lane >> 2;                     // 0..15
    int sseg = SW_SRC(lane);
    int qsw  = SW_RD(quad, l16);

    auto stage = [&](int k0, int buf) {
        const bf16_t* Ag = A + (size_t)(m0 + w * 16 + srow) * K + k0 + sseg;
        gload_lds16(Ag, &As[buf][(w * 16) * 32]);
        const bf16_t* Bg = B + (size_t)(n0 + w * 16 + srow) * K + k0 + sseg;
        gload_lds16(Bg, &Bs[buf][(w * 16) * 32]);
    };

    int niter = K / 32;
    stage(0, 0);
    for (int kt = 0; kt < niter; ++kt) {
        __syncthreads();   // drains prev prefetch (vmcnt0) + readers of other buf
        int cur = kt & 1;
        if (kt + 1 < niter) stage((kt + 1) * 32, cur ^ 1);

        bf16x8 a[4], b[2];
#pragma unroll
        for (int i = 0; i < 4; ++i)
            a[i] = *(const bf16x8*)&As[cur][(mrow0 + i * 16 + l16) * 32 + qsw];
#pragma unroll
        for (int j = 0; j < 2; ++j)
            b[j] = *(const bf16x8*)&Bs[cur][(ncol0 + j * 16 + l16) * 32 + qsw];
#pragma unroll
        for (int i = 0; i < 4; ++i)
#pragma unroll
            for (int j = 0; j < 2; ++j)
                acc[i][j] = __builtin_amdgcn_mfma_f32_16x16x32_bf16(a[i], b[j], acc[i][j], 0, 0, 0);
    }

    float* Cf = (float*)Cv;
    bf16_t* Cb = (bf16_t*)Cv;
#pragma unroll
    for (int j = 0; j < 2; ++j) {
        int col = n0 + ncol0 + j * 16 + l16;
        float bvv = bias[col];
#pragma unroll
        for (int i = 0; i < 4; ++i) {
            int row0 = m0 + mrow0 + i * 16 + quad * 4;
#pragma unroll
            for (int r = 0; r < 4; ++r) {
                float v = acc[i][j][r] + bvv;
                if (EPI == 2) v = 0.5f * v * (1.0f + erff(v * 0.70710678118654752f));
                if (EPI == 3) { if (col < LATENT) v *= C2F; }
                if (EPI == 0) Cf[(size_t)(row0 + r) * N + col] = v;
                else          Cb[(size_t)(row0 + r) * N + col] = (bf16_t)v;
            }
        }
    }
}

// ---------------------------------------------------------------------------
// GEMM 128x128 SPLIT-K x4 for FFN2 (r7). grid (32,6,4)=768 blocks = 3/CU,
// 24 iterations/block, f32 partials summed in the final LN. Identity tile
// map (bx%8 = per-XCD A-partitioning). LDS swizzle (r9).
// ---------------------------------------------------------------------------
struct SKDst { float* p[4]; };

__global__ __launch_bounds__(512) void gemm128sk(const bf16_t* __restrict__ A,
                                                 const bf16_t* __restrict__ B,
                                                 const float* __restrict__ bias,
                                                 SKDst dst,
                                                 int M, int N, int Ktot) {
    __shared__ __align__(16) bf16_t As[2][128 * 32];
    __shared__ __align__(16) bf16_t Bs[2][128 * 32];
    int t = threadIdx.x;
    int w = t >> 6;                           // 0..7
    int lane = t & 63, l16 = lane & 15, quad = lane >> 4;
    int z = blockIdx.z;
    int KS = Ktot >> 2;                       // per-split K
    int kbase = z * KS;
    int m0 = blockIdx.x * 128, n0 = blockIdx.y * 128;
    int wm = w & 1, wn = w >> 1;
    int mrow0 = wm * 64, ncol0 = wn * 32;

    f32x4 acc[4][2] = {};

    int srow = lane >> 2;
    int sseg = SW_SRC(lane);
    int qsw  = SW_RD(quad, l16);

    auto stage = [&](int k0, int buf) {
        const bf16_t* Ag = A + (size_t)(m0 + w * 16 + srow) * Ktot + kbase + k0 + sseg;
        gload_lds16(Ag, &As[buf][(w * 16) * 32]);
        const bf16_t* Bg = B + (size_t)(n0 + w * 16 + srow) * Ktot + kbase + k0 + sseg;
        gload_lds16(Bg, &Bs[buf][(w * 16) * 32]);
    };

    int niter = KS / 32;                      // 24 for FFN2
    stage(0, 0);
    for (int kt = 0; kt < niter; ++kt) {
        __syncthreads();
        int cur = kt & 1;
        if (kt + 1 < niter) stage((kt + 1) * 32, cur ^ 1);

        bf16x8 a[4], b[2];
#pragma unroll
        for (int i = 0; i < 4; ++i)
            a[i] = *(const bf16x8*)&As[cur][(mrow0 + i * 16 + l16) * 32 + qsw];
#pragma unroll
        for (int j = 0; j < 2; ++j)
            b[j] = *(const bf16x8*)&Bs[cur][(ncol0 + j * 16 + l16) * 32 + qsw];
#pragma unroll
        for (int i = 0; i < 4; ++i)
#pragma unroll
            for (int j = 0; j < 2; ++j)
                acc[i][j] = __builtin_amdgcn_mfma_f32_16x16x32_bf16(a[i], b[j], acc[i][j], 0, 0, 0);
    }

    float* Cf = dst.p[z];
#pragma unroll
    for (int j = 0; j < 2; ++j) {
        int col = n0 + ncol0 + j * 16 + l16;
        float bvv = (z == 0) ? bias[col] : 0.f;
#pragma unroll
        for (int i = 0; i < 4; ++i) {
            int row0 = m0 + mrow0 + i * 16 + quad * 4;
#pragma unroll
            for (int r = 0; r < 4; ++r)
                Cf[(size_t)(row0 + r) * N + col] = acc[i][j][r] + bvv;
        }
    }
}

// ---------------------------------------------------------------------------
// GEMM 64x64 tile, 256 thr = 4 waves (2Mx2N). Identity tile mapping (r4).
// Used for Wo (K=768). LDS swizzle (r9).
// ---------------------------------------------------------------------------
template<int EPI>
__global__ __launch_bounds__(256) void gemm64(const bf16_t* __restrict__ A,
                                              const bf16_t* __restrict__ B,
                                              const float* __restrict__ bias,
                                              void* __restrict__ Cv,
                                              int M, int N, int K) {
    __shared__ __align__(16) bf16_t As[2][64 * 32];
    __shared__ __align__(16) bf16_t Bs[2][64 * 32];
    int t = threadIdx.x;
    int w = t >> 6;                  // 0..3
    int lane = t & 63, l16 = lane & 15, quad = lane >> 4;
    int m0 = blockIdx.x * 64, n0 = blockIdx.y * 64;
    int wm = w & 1, wn = w >> 1;     // 2M x 2N wave grid

    f32x4 acc[2][2] = {};

    int srow = lane >> 2;
    int sseg = SW_SRC(lane);
    int qsw  = SW_RD(quad, l16);

    auto stage = [&](int k0, int buf) {
        const bf16_t* Ag = A + (size_t)(m0 + w * 16 + srow) * K + k0 + sseg;
        gload_lds16(Ag, &As[buf][(w * 16) * 32]);
        const bf16_t* Bg = B + (size_t)(n0 + w * 16 + srow) * K + k0 + sseg;
        gload_lds16(Bg, &Bs[buf][(w * 16) * 32]);
    };

    int niter = K / 32;
    stage(0, 0);
    for (int kt = 0; kt < niter; ++kt) {
        __syncthreads();
        int cur = kt & 1;
        if (kt + 1 < niter) stage((kt + 1) * 32, cur ^ 1);

        bf16x8 a[2], b[2];
#pragma unroll
        for (int i = 0; i < 2; ++i)
            a[i] = *(const bf16x8*)&As[cur][(wm * 32 + i * 16 + l16) * 32 + qsw];
#pragma unroll
        for (int j = 0; j < 2; ++j)
            b[j] = *(const bf16x8*)&Bs[cur][(wn * 32 + j * 16 + l16) * 32 + qsw];
#pragma unroll
        for (int i = 0; i < 2; ++i)
#pragma unroll
            for (int j = 0; j < 2; ++j)
                acc[i][j] = __builtin_amdgcn_mfma_f32_16x16x32_bf16(a[i], b[j], acc[i][j], 0, 0, 0);
    }

    float* Cf = (float*)Cv;
    bf16_t* Cb = (bf16_t*)Cv;
#pragma unroll
    for (int j = 0; j < 2; ++j) {
        int col = n0 + wn * 32 + j * 16 + l16;
        float bvv = bias[col];
#pragma unroll
        for (int i = 0; i < 2; ++i) {
            int row0 = m0 + wm * 32 + i * 16 + quad * 4;
#pragma unroll
            for (int r = 0; r < 4; ++r) {
                float v = acc[i][j][r] + bvv;
                if (EPI == 2) v = 0.5f * v * (1.0f + erff(v * 0.70710678118654752f));
                if (EPI == 0) Cf[(size_t)(row0 + r) * N + col] = v;
                else          Cb[(size_t)(row0 + r) * N + col] = (bf16_t)v;
            }
        }
    }
}

// ---------------------------------------------------------------------------
// V transpose: QKV V-part [b, n, h, d] -> Vt [b, h, d, n]
// ---------------------------------------------------------------------------
__global__ __launch_bounds__(256) void v_transpose(const bf16_t* __restrict__ QKV,
                                                   bf16_t* __restrict__ Vt) {
    __shared__ bf16_t Ts[64][68];
    int t = threadIdx.x;
    int bh = blockIdx.y;
    int b = bh / HEADS, h = bh % HEADS;
    int n0 = blockIdx.x * 64;
    size_t rowbase = (size_t)b * SEQ;
    int r = t >> 3, seg = (t & 7) * 8;
#pragma unroll
    for (int i = 0; i < 2; ++i) {
        int rr = r + i * 32;
        *(bf16x8*)&Ts[rr][seg] =
            *(const bf16x8*)&QKV[(rowbase + n0 + rr) * (3 * LATENT) + 2 * LATENT + h * HD + seg];
    }
    __syncthreads();
#pragma unroll
    for (int i = 0; i < 2; ++i) {
        int d = r + i * 32;
        bf16x8 o;
#pragma unroll
        for (int jj = 0; jj < 8; ++jj) o[jj] = Ts[seg + jj][d];
        *(bf16x8*)&Vt[((size_t)bh * HD + d) * SEQ + n0 + seg] = o;
    }
}

// ---------------------------------------------------------------------------
// Flash attention (S^T formulation). r11: no split-K — each block owns 64
// q-rows (4 waves x 16 q), walks all 2048 keys (32 k-tiles); epilogue
// divides by vsum, writes bf16 directly. grid (24,32) = 768 blocks = 3/CU.
// K/V LDS XOR-swizzled (r9/r10).
// ---------------------------------------------------------------------------
__global__ __launch_bounds__(256) void attn_flash(const bf16_t* __restrict__ QKV,
                                                  const bf16_t* __restrict__ Vt,
                                                  bf16_t* __restrict__ O) {
    __shared__ __align__(16) bf16_t Ks[2][2][64][32];    // [buf][d-chunk][key][d32]
    __shared__ __align__(16) bf16_t Vts[2][2][64][32];   // [buf][key-chunk][d][key32]
    __shared__ __align__(16) bf16_t Ps[4][16][72];       // [wave][q][key]

    int t = threadIdx.x;
    int w = t >> 6;
    int lane = t & 63, l16 = lane & 15, quad = lane >> 4;
    int bh = blockIdx.x;
    int b = bh / HEADS, h = bh % HEADS;
    int qblk = blockIdx.y * 64;
    size_t rowbase = (size_t)b * SEQ;
    const int LD = 3 * LATENT;
    int qw = qblk + w * 16;

    bf16x8 bq[2];
    {
        const bf16_t* qrow = QKV + (rowbase + qw + l16) * LD + h * HD;
        bq[0] = *(const bf16x8*)&qrow[quad * 8];
        bq[1] = *(const bf16x8*)&qrow[32 + quad * 8];
    }

    f32x4 acc[4] = {};    // [dt]
    float vsum = 0.f;

    int srow = lane >> 2;
    int sseg = SW_SRC(lane);
    int qsw  = SW_RD(quad, l16);

    auto stage = [&](int koff, int buf) {
        const bf16_t* kg = QKV + (rowbase + koff + w * 16 + srow) * LD + LATENT + h * HD + sseg;
        gload_lds16(kg,      &Ks[buf][0][w * 16][0]);
        gload_lds16(kg + 32, &Ks[buf][1][w * 16][0]);
        const bf16_t* vg = Vt + ((size_t)bh * HD + w * 16 + srow) * SEQ + koff + sseg;
        gload_lds16(vg,      &Vts[buf][0][w * 16][0]);
        gload_lds16(vg + 32, &Vts[buf][1][w * 16][0]);
    };

    stage(0, 0);

    const int NKT = SEQ / 64;          // 32 k-tiles of 64 keys
    for (int kt = 0; kt < NKT; ++kt) {
        __syncthreads();
        int cur = kt & 1;
        if (kt + 1 < NKT) stage((kt + 1) * 64, cur ^ 1);

#pragma unroll
        for (int skt = 0; skt < 4; ++skt) {
            bf16x8 ak0 = *(const bf16x8*)&Ks[cur][0][skt * 16 + l16][qsw];
            bf16x8 ak1 = *(const bf16x8*)&Ks[cur][1][skt * 16 + l16][qsw];
            f32x4 s = {};
            s = __builtin_amdgcn_mfma_f32_16x16x32_bf16(ak0, bq[0], s, 0, 0, 0);
            s = __builtin_amdgcn_mfma_f32_16x16x32_bf16(ak1, bq[1], s, 0, 0, 0);
            bf16x4 pk;
#pragma unroll
            for (int r = 0; r < 4; ++r) {
                float p = __builtin_amdgcn_exp2f(s[r]);
                vsum += p;
                pk[r] = (bf16_t)p;
            }
            *(bf16x4*)&Ps[w][l16][skt * 16 + quad * 4] = pk;
        }
        __threadfence_block();

        bf16x8 bv[4][2];
#pragma unroll
        for (int dt = 0; dt < 4; ++dt) {
            bv[dt][0] = *(const bf16x8*)&Vts[cur][0][dt * 16 + l16][qsw];
            bv[dt][1] = *(const bf16x8*)&Vts[cur][1][dt * 16 + l16][qsw];
        }
#pragma unroll
        for (int kc = 0; kc < 2; ++kc) {
            bf16x8 ap = *(const bf16x8*)&Ps[w][l16][kc * 32 + quad * 8];
#pragma unroll
            for (int dt = 0; dt < 4; ++dt)
                acc[dt] = __builtin_amdgcn_mfma_f32_16x16x32_bf16(ap, bv[dt][kc], acc[dt], 0, 0, 0);
        }
    }

    // vsum: reduce across quads (all lanes then hold total for q = l16)
    vsum += __shfl_xor(vsum, 16, 64);
    vsum += __shfl_xor(vsum, 32, 64);
    // fetch this lane's 4 row-denominators (rows q = quad*4 + r)
    float dv[4];
#pragma unroll
    for (int r = 0; r < 4; ++r)
        dv[r] = __shfl(vsum, quad * 4 + r, 64);

#pragma unroll
    for (int dt = 0; dt < 4; ++dt)
#pragma unroll
        for (int r = 0; r < 4; ++r) {
            size_t row = rowbase + qw + quad * 4 + r;
            O[row * LATENT + h * HD + dt * 16 + l16] = (bf16_t)(acc[dt][r] / dv[r]);
        }
}

// ---------------------------------------------------------------------------
// Fused residual + LayerNorm; NADD extra f32 addend streams (NADD=4 consumes
// the FFN2 split-K partials, removing a separate combine pass).
// ---------------------------------------------------------------------------
template<int NADD>
__global__ __launch_bounds__(256) void ln_residual(const float* __restrict__ base,
                                                   const float* __restrict__ a1,
                                                   const float* __restrict__ a2,
                                                   const float* __restrict__ a3,
                                                   const float* __restrict__ a4,
                                                   const float* __restrict__ g,
                                                   const float* __restrict__ bta,
                                                   float* __restrict__ outf,
                                                   bf16_t* __restrict__ outb) {
    int row = blockIdx.x;
    size_t ro = (size_t)row * LATENT;
    int t = threadIdx.x;
    float v[3];
    float s = 0.f;
#pragma unroll
    for (int i = 0; i < 3; ++i) {
        int cix = t + i * 256;
        float x = base[ro + cix] + a1[ro + cix];
        if (NADD >= 2) x += a2[ro + cix];
        if (NADD >= 3) x += a3[ro + cix];
        if (NADD >= 4) x += a4[ro + cix];
        v[i] = x;
        s += x;
    }
    __shared__ float red[4];
#pragma unroll
    for (int off = 1; off < 64; off <<= 1) s += __shfl_xor(s, off, 64);
    if ((t & 63) == 0) red[t >> 6] = s;
    __syncthreads();
    float mu = (red[0] + red[1] + red[2] + red[3]) * (1.f / LATENT);
    float q = 0.f;
#pragma unroll
    for (int i = 0; i < 3; ++i) {
        float d = v[i] - mu;
        q += d * d;
    }
#pragma unroll
    for (int off = 1; off < 64; off <<= 1) q += __shfl_xor(q, off, 64);
    __syncthreads();
    if ((t & 63) == 0) red[t >> 6] = q;
    __syncthreads();
    float var = (red[0] + red[1] + red[2] + red[3]) * (1.f / LATENT);
    float rs = rsqrtf(var + 1e-5f);
#pragma unroll
    for (int i = 0; i < 3; ++i) {
        int cix = t + i * 256;
        float o = (v[i] - mu) * rs * g[cix] + bta[cix];
        outf[ro + cix] = o;
        if (outb) outb[ro + cix] = (bf16_t)o;
    }
}

// ---------------------------------------------------------------------------
extern "C" void kernel_launch(void* const* d_in, const int* in_sizes, int n_in,
                              void* d_out, int out_size, void* d_ws, size_t ws_size,
                              hipStream_t stream) {
    const float* x   = (const float*)d_in[0];
    const float* Wq  = (const float*)d_in[1];
    const float* bq  = (const float*)d_in[2];
    const float* Wk  = (const float*)d_in[3];
    const float* bk  = (const float*)d_in[4];
    const float* Wv  = (const float*)d_in[5];
    const float* bv  = (const float*)d_in[6];
    const float* Wo  = (const float*)d_in[7];
    const float* bo  = (const float*)d_in[8];
    const float* g1  = (const float*)d_in[9];
    const float* be1 = (const float*)d_in[10];
    const float* g2  = (const float*)d_in[11];
    const float* be2 = (const float*)d_in[12];
    const float* W1  = (const float*)d_in[13];
    const float* b1  = (const float*)d_in[14];
    const float* W2  = (const float*)d_in[15];
    const float* b2  = (const float*)d_in[16];
    float* out = (float*)d_out;

    char* ws = (char*)d_ws;
    size_t off = 0;
    auto alloc = [&](size_t bytes) {
        char* p = ws + off;
        off = (off + bytes + 255) & ~(size_t)255;
        return p;
    };
    bf16_t* xbf   = (bf16_t*)alloc((size_t)NTOK * LATENT * 2);
    bf16_t* Wcat  = (bf16_t*)alloc((size_t)3 * LATENT * LATENT * 2);
    bf16_t* Wobf  = (bf16_t*)alloc((size_t)LATENT * LATENT * 2);
    bf16_t* W1bf  = (bf16_t*)alloc((size_t)FFN_DIM * LATENT * 2);
    bf16_t* W2bf  = (bf16_t*)alloc((size_t)LATENT * FFN_DIM * 2);
    float*  bcat  = (float*)alloc((size_t)3 * LATENT * 4);
    bf16_t* QKV   = (bf16_t*)alloc((size_t)NTOK * 3 * LATENT * 2);
    bf16_t* attnO = (bf16_t*)alloc((size_t)NTOK * LATENT * 2);
    float*  tmpf  = (float*)alloc((size_t)NTOK * LATENT * 4);
    float*  y1f   = (float*)alloc((size_t)NTOK * LATENT * 4);
    bf16_t* y1bf  = (bf16_t*)alloc((size_t)NTOK * LATENT * 2);
    bf16_t* hbf   = (bf16_t*)alloc((size_t)NTOK * FFN_DIM * 2);
    float*  P3    = (float*)alloc((size_t)NTOK * LATENT * 4);   // 4th FFN2 partial
    bf16_t* Vtg   = (bf16_t*)hbf;   // alias: Vt lifetime disjoint from h
    // FFN2 split-K partials (all dead regions at FFN2 time):
    //   P0 = tmpf (dead after ln1), P1 = QKV (dead after attn),
    //   P2 = xbf..Wcat span (15.7MB, dead after QKV gemm), P3 dedicated.
    float* P0 = tmpf;
    float* P1 = (float*)QKV;
    float* P2 = (float*)xbf;

    // 1. convert to bf16 + bias concat (seg 7)
    CvtDesc cd;
    cd.src[0] = x;   cd.dst[0] = xbf;                        cd.n4[0] = NTOK * LATENT / 4;
    cd.src[1] = Wq;  cd.dst[1] = Wcat;                       cd.n4[1] = LATENT * LATENT / 4;
    cd.src[2] = Wk;  cd.dst[2] = Wcat + LATENT * LATENT;     cd.n4[2] = LATENT * LATENT / 4;
    cd.src[3] = Wv;  cd.dst[3] = Wcat + 2 * LATENT * LATENT; cd.n4[3] = LATENT * LATENT / 4;
    cd.src[4] = Wo;  cd.dst[4] = Wobf;                       cd.n4[4] = LATENT * LATENT / 4;
    cd.src[5] = W1;  cd.dst[5] = W1bf;                       cd.n4[5] = FFN_DIM * LATENT / 4;
    cd.src[6] = W2;  cd.dst[6] = W2bf;                       cd.n4[6] = FFN_DIM * LATENT / 4;
    cd.bsrc[0] = bq; cd.bsrc[1] = bk; cd.bsrc[2] = bv;
    cd.bdst = bcat;
    {
        int maxn4 = NTOK * LATENT / 4;
        dim3 grid((maxn4 + 255) / 256, 8);
        cvt_f32_bf16<<<grid, 256, 0, stream>>>(cd);
    }

    // 2. fused QKV GEMM; Q region pre-scaled by C2 (EPI=3). 512 thr / 8 waves.
    gemm128<3><<<dim3(NTOK / 128, 3 * LATENT / 128), 512, 0, stream>>>(
        xbf, Wcat, bcat, QKV, NTOK, 3 * LATENT, LATENT);

    // 2.5 V transpose
    v_transpose<<<dim3(SEQ / 64, 2 * HEADS), 256, 0, stream>>>(QKV, Vtg);

    // 3. attention: no split-K, 768 blocks x 4 waves (64 q each), bf16 out
    attn_flash<<<dim3(2 * HEADS, SEQ / 64), 256, 0, stream>>>(QKV, Vtg, attnO);

    // 4. output projection: 64x64 tiles, 768 blocks x 4 waves
    gemm64<0><<<dim3(NTOK / 64, LATENT / 64), 256, 0, stream>>>(
        attnO, Wobf, bo, tmpf, NTOK, LATENT, LATENT);

    // 5. y1 = LN(x + proj)
    ln_residual<1><<<NTOK, 256, 0, stream>>>(x, tmpf, nullptr, nullptr, nullptr,
                                             g1, be1, y1f, y1bf);

    // 6. h = gelu(y1 @ W1^T + b1). 512 thr / 8 waves.
    gemm128<2><<<dim3(NTOK / 128, FFN_DIM / 128), 512, 0, stream>>>(
        y1bf, W1bf, b1, hbf, NTOK, FFN_DIM, LATENT);

    // 7. ffn partials = h @ W2^T + b2, 128x128 split-K x4: 768 blocks = 3/CU
    SKDst skd;
    skd.p[0] = P0; skd.p[1] = P1; skd.p[2] = P2; skd.p[3] = P3;
    gemm128sk<<<dim3(NTOK / 128, LATENT / 128, 4), 512, 0, stream>>>(
        hbf, W2bf, b2, skd, NTOK, LATENT, FFN_DIM);

    // 8. out = LN(y1 + P0 + P1 + P2 + P3)
    ln_residual<4><<<NTOK, 256, 0, stream>>>(y1f, P0, P1, P2, P3,
                                             g2, be2, out, nullptr);
}

// Round 14
// 282.906 us; speedup vs baseline: 1.2141x; 1.0112x over previous
//
#include <hip/hip_runtime.h>
#include <hip/hip_bf16.h>
#include <cstddef>
#include <cstdint>

typedef __bf16 bf16_t;
typedef bf16_t bf16x8 __attribute__((ext_vector_type(8)));
typedef bf16_t bf16x4 __attribute__((ext_vector_type(4)));
typedef float f32x4 __attribute__((ext_vector_type(4)));

#define LATENT 768
#define FFN_DIM 3072
#define NTOK 4096      // 2*2048
#define SEQ 2048
#define HEADS 12
#define HD 64

#define C2F 0.18033688011112042f   // 0.125 * log2(e)

__device__ __forceinline__ void gload_lds16(const bf16_t* g, bf16_t* l) {
    __builtin_amdgcn_global_load_lds((const __attribute__((address_space(1))) void*)g,
                                     (__attribute__((address_space(3))) void*)l, 16, 0, 0);
}

// r9 LDS XOR-swizzle for [N][32]bf16 (64B-row) tiles read by ds_read_b128:
// verified r10: attn conflicts 5.5M -> 2.36M, attn 47.5 -> 43.7us; r12: gemm
// conflicts 0. Physical slot p at row r holds logical p^((r>>1)&3).
// WRITE side: global_load_lds writes linearly -> SOURCE address pre-swizzled
// (m173). READ side: quad' = quad ^ ((l16>>1)&3), loop-invariant.
#define SW_SRC(lane)  ((((lane) & 3) ^ (((lane) >> 3) & 3)) * 8)
#define SW_RD(quad, l16)  (((quad) ^ (((l16) >> 1) & 3)) * 8)

// ---------------------------------------------------------------------------
// fp32 -> bf16 conversion, multi-segment; segment 7 = f32 bias concat (bq|bk|bv)
// ---------------------------------------------------------------------------
struct CvtDesc {
    const float* src[7];
    bf16_t* dst[7];
    int n4[7];
    const float* bsrc[3];
    float* bdst;
};

__global__ __launch_bounds__(256) void cvt_f32_bf16(CvtDesc d) {
    int seg = blockIdx.y;
    if (seg == 7) {   // bias concat: 3 blocks x 768 floats
        int which = blockIdx.x;
        if (which >= 3) return;
        int t = threadIdx.x;
#pragma unroll
        for (int i = 0; i < 3; ++i)
            d.bdst[which * LATENT + t + i * 256] = d.bsrc[which][t + i * 256];
        return;
    }
    int i = blockIdx.x * 256 + threadIdx.x;
    if (i >= d.n4[seg]) return;
    float4 v = ((const float4*)d.src[seg])[i];
    bf16x4 o;
    o[0] = (bf16_t)v.x; o[1] = (bf16_t)v.y; o[2] = (bf16_t)v.z; o[3] = (bf16_t)v.w;
    *(bf16x4*)&d.dst[seg][(size_t)i * 4] = o;
}

// ---------------------------------------------------------------------------
// GEMM 128x128, 512 thr = 8 waves. Wave (wm=w&1, wn=w>>1) owns 64x32 out.
// r13: IDENTITY tile mapping (diagonal remap removed — it duplicated B
// across all 8 XCDs: FETCH 43MB = 8*B + A, L2 thrash). LDS swizzle (r9).
// EPI: 0 none->f32, 2 exact-GELU->bf16, 3 bf16 + C2F scale on cols<LATENT.
// ---------------------------------------------------------------------------
template<int EPI>
__global__ __launch_bounds__(512) void gemm128(const bf16_t* __restrict__ A,
                                               const bf16_t* __restrict__ B,
                                               const float* __restrict__ bias,
                                               void* __restrict__ Cv,
                                               int M, int N, int K) {
    __shared__ __align__(16) bf16_t As[2][128 * 32];
    __shared__ __align__(16) bf16_t Bs[2][128 * 32];
    int t = threadIdx.x;
    int w = t >> 6;                           // 0..7
    int lane = t & 63, l16 = lane & 15, quad = lane >> 4;
    int m0 = blockIdx.x * 128, n0 = blockIdx.y * 128;
    int wm = w & 1, wn = w >> 1;              // 2M x 4N wave grid
    int mrow0 = wm * 64, ncol0 = wn * 32;

    f32x4 acc[4][2] = {};

    int srow = lane >> 2;                     // 0..15
    int sseg = SW_SRC(lane);
    int qsw  = SW_RD(quad, l16);

    auto stage = [&](int k0, int buf) {
        const bf16_t* Ag = A + (size_t)(m0 + w * 16 + srow) * K + k0 + sseg;
        gload_lds16(Ag, &As[buf][(w * 16) * 32]);
        const bf16_t* Bg = B + (size_t)(n0 + w * 16 + srow) * K + k0 + sseg;
        gload_lds16(Bg, &Bs[buf][(w * 16) * 32]);
    };

    int niter = K / 32;
    stage(0, 0);
    for (int kt = 0; kt < niter; ++kt) {
        __syncthreads();   // drains prev prefetch (vmcnt0) + readers of other buf
        int cur = kt & 1;
        if (kt + 1 < niter) stage((kt + 1) * 32, cur ^ 1);

        bf16x8 a[4], b[2];
#pragma unroll
        for (int i = 0; i < 4; ++i)
            a[i] = *(const bf16x8*)&As[cur][(mrow0 + i * 16 + l16) * 32 + qsw];
#pragma unroll
        for (int j = 0; j < 2; ++j)
            b[j] = *(const bf16x8*)&Bs[cur][(ncol0 + j * 16 + l16) * 32 + qsw];
#pragma unroll
        for (int i = 0; i < 4; ++i)
#pragma unroll
            for (int j = 0; j < 2; ++j)
                acc[i][j] = __builtin_amdgcn_mfma_f32_16x16x32_bf16(a[i], b[j], acc[i][j], 0, 0, 0);
    }

    float* Cf = (float*)Cv;
    bf16_t* Cb = (bf16_t*)Cv;
#pragma unroll
    for (int j = 0; j < 2; ++j) {
        int col = n0 + ncol0 + j * 16 + l16;
        float bvv = bias[col];
#pragma unroll
        for (int i = 0; i < 4; ++i) {
            int row0 = m0 + mrow0 + i * 16 + quad * 4;
#pragma unroll
            for (int r = 0; r < 4; ++r) {
                float v = acc[i][j][r] + bvv;
                if (EPI == 2) v = 0.5f * v * (1.0f + erff(v * 0.70710678118654752f));
                if (EPI == 3) { if (col < LATENT) v *= C2F; }
                if (EPI == 0) Cf[(size_t)(row0 + r) * N + col] = v;
                else          Cb[(size_t)(row0 + r) * N + col] = (bf16_t)v;
            }
        }
    }
}

// ---------------------------------------------------------------------------
// GEMM 128x128 SPLIT-K x4 for FFN2 (r7). grid (32,6,4)=768 blocks = 3/CU,
// 24 iterations/block, f32 partials summed in the final LN. Identity tile
// map (bx%8 = per-XCD A-partitioning). LDS swizzle (r9).
// ---------------------------------------------------------------------------
struct SKDst { float* p[4]; };

__global__ __launch_bounds__(512) void gemm128sk(const bf16_t* __restrict__ A,
                                                 const bf16_t* __restrict__ B,
                                                 const float* __restrict__ bias,
                                                 SKDst dst,
                                                 int M, int N, int Ktot) {
    __shared__ __align__(16) bf16_t As[2][128 * 32];
    __shared__ __align__(16) bf16_t Bs[2][128 * 32];
    int t = threadIdx.x;
    int w = t >> 6;                           // 0..7
    int lane = t & 63, l16 = lane & 15, quad = lane >> 4;
    int z = blockIdx.z;
    int KS = Ktot >> 2;                       // per-split K
    int kbase = z * KS;
    int m0 = blockIdx.x * 128, n0 = blockIdx.y * 128;
    int wm = w & 1, wn = w >> 1;
    int mrow0 = wm * 64, ncol0 = wn * 32;

    f32x4 acc[4][2] = {};

    int srow = lane >> 2;
    int sseg = SW_SRC(lane);
    int qsw  = SW_RD(quad, l16);

    auto stage = [&](int k0, int buf) {
        const bf16_t* Ag = A + (size_t)(m0 + w * 16 + srow) * Ktot + kbase + k0 + sseg;
        gload_lds16(Ag, &As[buf][(w * 16) * 32]);
        const bf16_t* Bg = B + (size_t)(n0 + w * 16 + srow) * Ktot + kbase + k0 + sseg;
        gload_lds16(Bg, &Bs[buf][(w * 16) * 32]);
    };

    int niter = KS / 32;                      // 24 for FFN2
    stage(0, 0);
    for (int kt = 0; kt < niter; ++kt) {
        __syncthreads();
        int cur = kt & 1;
        if (kt + 1 < niter) stage((kt + 1) * 32, cur ^ 1);

        bf16x8 a[4], b[2];
#pragma unroll
        for (int i = 0; i < 4; ++i)
            a[i] = *(const bf16x8*)&As[cur][(mrow0 + i * 16 + l16) * 32 + qsw];
#pragma unroll
        for (int j = 0; j < 2; ++j)
            b[j] = *(const bf16x8*)&Bs[cur][(ncol0 + j * 16 + l16) * 32 + qsw];
#pragma unroll
        for (int i = 0; i < 4; ++i)
#pragma unroll
            for (int j = 0; j < 2; ++j)
                acc[i][j] = __builtin_amdgcn_mfma_f32_16x16x32_bf16(a[i], b[j], acc[i][j], 0, 0, 0);
    }

    float* Cf = dst.p[z];
#pragma unroll
    for (int j = 0; j < 2; ++j) {
        int col = n0 + ncol0 + j * 16 + l16;
        float bvv = (z == 0) ? bias[col] : 0.f;
#pragma unroll
        for (int i = 0; i < 4; ++i) {
            int row0 = m0 + mrow0 + i * 16 + quad * 4;
#pragma unroll
            for (int r = 0; r < 4; ++r)
                Cf[(size_t)(row0 + r) * N + col] = acc[i][j][r] + bvv;
        }
    }
}

// ---------------------------------------------------------------------------
// GEMM 64x64 tile. r14: **512 thr = 8 waves** (was 4) — replays r6's
// occupancy lever (58->46us): 24 waves/CU for latency hiding. Wave
// (wm=w&1, wn=w>>1) owns 32x16 out (2x1 frags); staging = exactly 1
// gload/thread (waves 0-3 stage A's 64 rows, waves 4-7 stage B's).
// Identity tile mapping (bx%8 = per-XCD A-partitioning). LDS swizzle (r9).
// Used for Wo (K=768, 24 iters).
// ---------------------------------------------------------------------------
template<int EPI>
__global__ __launch_bounds__(512) void gemm64(const bf16_t* __restrict__ A,
                                              const bf16_t* __restrict__ B,
                                              const float* __restrict__ bias,
                                              void* __restrict__ Cv,
                                              int M, int N, int K) {
    __shared__ __align__(16) bf16_t As[2][64 * 32];
    __shared__ __align__(16) bf16_t Bs[2][64 * 32];
    int t = threadIdx.x;
    int w = t >> 6;                  // 0..7
    int lane = t & 63, l16 = lane & 15, quad = lane >> 4;
    int m0 = blockIdx.x * 64, n0 = blockIdx.y * 64;
    int wm = w & 1, wn = w >> 1;     // 2M x 4N wave grid

    f32x4 acc[2] = {};

    int srow = lane >> 2;            // 0..15
    int sseg = SW_SRC(lane);
    int qsw  = SW_RD(quad, l16);
    int sw4 = w & 3;                 // wave's row-group within its matrix

    auto stage = [&](int k0, int buf) {
        if (w < 4) {
            const bf16_t* Ag = A + (size_t)(m0 + sw4 * 16 + srow) * K + k0 + sseg;
            gload_lds16(Ag, &As[buf][(sw4 * 16) * 32]);
        } else {
            const bf16_t* Bg = B + (size_t)(n0 + sw4 * 16 + srow) * K + k0 + sseg;
            gload_lds16(Bg, &Bs[buf][(sw4 * 16) * 32]);
        }
    };

    int niter = K / 32;
    stage(0, 0);
    for (int kt = 0; kt < niter; ++kt) {
        __syncthreads();
        int cur = kt & 1;
        if (kt + 1 < niter) stage((kt + 1) * 32, cur ^ 1);

        bf16x8 a[2], b;
#pragma unroll
        for (int i = 0; i < 2; ++i)
            a[i] = *(const bf16x8*)&As[cur][(wm * 32 + i * 16 + l16) * 32 + qsw];
        b = *(const bf16x8*)&Bs[cur][(wn * 16 + l16) * 32 + qsw];
#pragma unroll
        for (int i = 0; i < 2; ++i)
            acc[i] = __builtin_amdgcn_mfma_f32_16x16x32_bf16(a[i], b, acc[i], 0, 0, 0);
    }

    float* Cf = (float*)Cv;
    bf16_t* Cb = (bf16_t*)Cv;
    {
        int col = n0 + wn * 16 + l16;
        float bvv = bias[col];
#pragma unroll
        for (int i = 0; i < 2; ++i) {
            int row0 = m0 + wm * 32 + i * 16 + quad * 4;
#pragma unroll
            for (int r = 0; r < 4; ++r) {
                float v = acc[i][r] + bvv;
                if (EPI == 2) v = 0.5f * v * (1.0f + erff(v * 0.70710678118654752f));
                if (EPI == 0) Cf[(size_t)(row0 + r) * N + col] = v;
                else          Cb[(size_t)(row0 + r) * N + col] = (bf16_t)v;
            }
        }
    }
}

// ---------------------------------------------------------------------------
// V transpose: QKV V-part [b, n, h, d] -> Vt [b, h, d, n]
// ---------------------------------------------------------------------------
__global__ __launch_bounds__(256) void v_transpose(const bf16_t* __restrict__ QKV,
                                                   bf16_t* __restrict__ Vt) {
    __shared__ bf16_t Ts[64][68];
    int t = threadIdx.x;
    int bh = blockIdx.y;
    int b = bh / HEADS, h = bh % HEADS;
    int n0 = blockIdx.x * 64;
    size_t rowbase = (size_t)b * SEQ;
    int r = t >> 3, seg = (t & 7) * 8;
#pragma unroll
    for (int i = 0; i < 2; ++i) {
        int rr = r + i * 32;
        *(bf16x8*)&Ts[rr][seg] =
            *(const bf16x8*)&QKV[(rowbase + n0 + rr) * (3 * LATENT) + 2 * LATENT + h * HD + seg];
    }
    __syncthreads();
#pragma unroll
    for (int i = 0; i < 2; ++i) {
        int d = r + i * 32;
        bf16x8 o;
#pragma unroll
        for (int jj = 0; jj < 8; ++jj) o[jj] = Ts[seg + jj][d];
        *(bf16x8*)&Vt[((size_t)bh * HD + d) * SEQ + n0 + seg] = o;
    }
}

// ---------------------------------------------------------------------------
// Flash attention (S^T formulation). r11: no split-K — each block owns 64
// q-rows (4 waves x 16 q), walks all 2048 keys (32 k-tiles); epilogue
// divides by vsum, writes bf16 directly. grid (24,32) = 768 blocks = 3/CU.
// K/V LDS XOR-swizzled (r9/r10). r14: s_setprio(1) around MFMA clusters
// (T5, m191: helps when independent blocks co-resident — ours are 3/CU).
// ---------------------------------------------------------------------------
__global__ __launch_bounds__(256) void attn_flash(const bf16_t* __restrict__ QKV,
                                                  const bf16_t* __restrict__ Vt,
                                                  bf16_t* __restrict__ O) {
    __shared__ __align__(16) bf16_t Ks[2][2][64][32];    // [buf][d-chunk][key][d32]
    __shared__ __align__(16) bf16_t Vts[2][2][64][32];   // [buf][key-chunk][d][key32]
    __shared__ __align__(16) bf16_t Ps[4][16][72];       // [wave][q][key]

    int t = threadIdx.x;
    int w = t >> 6;
    int lane = t & 63, l16 = lane & 15, quad = lane >> 4;
    int bh = blockIdx.x;
    int b = bh / HEADS, h = bh % HEADS;
    int qblk = blockIdx.y * 64;
    size_t rowbase = (size_t)b * SEQ;
    const int LD = 3 * LATENT;
    int qw = qblk + w * 16;

    bf16x8 bq[2];
    {
        const bf16_t* qrow = QKV + (rowbase + qw + l16) * LD + h * HD;
        bq[0] = *(const bf16x8*)&qrow[quad * 8];
        bq[1] = *(const bf16x8*)&qrow[32 + quad * 8];
    }

    f32x4 acc[4] = {};    // [dt]
    float vsum = 0.f;

    int srow = lane >> 2;
    int sseg = SW_SRC(lane);
    int qsw  = SW_RD(quad, l16);

    auto stage = [&](int koff, int buf) {
        const bf16_t* kg = QKV + (rowbase + koff + w * 16 + srow) * LD + LATENT + h * HD + sseg;
        gload_lds16(kg,      &Ks[buf][0][w * 16][0]);
        gload_lds16(kg + 32, &Ks[buf][1][w * 16][0]);
        const bf16_t* vg = Vt + ((size_t)bh * HD + w * 16 + srow) * SEQ + koff + sseg;
        gload_lds16(vg,      &Vts[buf][0][w * 16][0]);
        gload_lds16(vg + 32, &Vts[buf][1][w * 16][0]);
    };

    stage(0, 0);

    const int NKT = SEQ / 64;          // 32 k-tiles of 64 keys
    for (int kt = 0; kt < NKT; ++kt) {
        __syncthreads();
        int cur = kt & 1;
        if (kt + 1 < NKT) stage((kt + 1) * 64, cur ^ 1);

#pragma unroll
        for (int skt = 0; skt < 4; ++skt) {
            bf16x8 ak0 = *(const bf16x8*)&Ks[cur][0][skt * 16 + l16][qsw];
            bf16x8 ak1 = *(const bf16x8*)&Ks[cur][1][skt * 16 + l16][qsw];
            f32x4 s = {};
            __builtin_amdgcn_s_setprio(1);
            s = __builtin_amdgcn_mfma_f32_16x16x32_bf16(ak0, bq[0], s, 0, 0, 0);
            s = __builtin_amdgcn_mfma_f32_16x16x32_bf16(ak1, bq[1], s, 0, 0, 0);
            __builtin_amdgcn_s_setprio(0);
            bf16x4 pk;
#pragma unroll
            for (int r = 0; r < 4; ++r) {
                float p = __builtin_amdgcn_exp2f(s[r]);
                vsum += p;
                pk[r] = (bf16_t)p;
            }
            *(bf16x4*)&Ps[w][l16][skt * 16 + quad * 4] = pk;
        }
        __threadfence_block();

        bf16x8 bv[4][2];
#pragma unroll
        for (int dt = 0; dt < 4; ++dt) {
            bv[dt][0] = *(const bf16x8*)&Vts[cur][0][dt * 16 + l16][qsw];
            bv[dt][1] = *(const bf16x8*)&Vts[cur][1][dt * 16 + l16][qsw];
        }
        __builtin_amdgcn_s_setprio(1);
#pragma unroll
        for (int kc = 0; kc < 2; ++kc) {
            bf16x8 ap = *(const bf16x8*)&Ps[w][l16][kc * 32 + quad * 8];
#pragma unroll
            for (int dt = 0; dt < 4; ++dt)
                acc[dt] = __builtin_amdgcn_mfma_f32_16x16x32_bf16(ap, bv[dt][kc], acc[dt], 0, 0, 0);
        }
        __builtin_amdgcn_s_setprio(0);
    }

    // vsum: reduce across quads (all lanes then hold total for q = l16)
    vsum += __shfl_xor(vsum, 16, 64);
    vsum += __shfl_xor(vsum, 32, 64);
    // fetch this lane's 4 row-denominators (rows q = quad*4 + r)
    float dv[4];
#pragma unroll
    for (int r = 0; r < 4; ++r)
        dv[r] = __shfl(vsum, quad * 4 + r, 64);

#pragma unroll
    for (int dt = 0; dt < 4; ++dt)
#pragma unroll
        for (int r = 0; r < 4; ++r) {
            size_t row = rowbase + qw + quad * 4 + r;
            O[row * LATENT + h * HD + dt * 16 + l16] = (bf16_t)(acc[dt][r] / dv[r]);
        }
}

// ---------------------------------------------------------------------------
// Fused residual + LayerNorm; NADD extra f32 addend streams (NADD=4 consumes
// the FFN2 split-K partials, removing a separate combine pass).
// ---------------------------------------------------------------------------
template<int NADD>
__global__ __launch_bounds__(256) void ln_residual(const float* __restrict__ base,
                                                   const float* __restrict__ a1,
                                                   const float* __restrict__ a2,
                                                   const float* __restrict__ a3,
                                                   const float* __restrict__ a4,
                                                   const float* __restrict__ g,
                                                   const float* __restrict__ bta,
                                                   float* __restrict__ outf,
                                                   bf16_t* __restrict__ outb) {
    int row = blockIdx.x;
    size_t ro = (size_t)row * LATENT;
    int t = threadIdx.x;
    float v[3];
    float s = 0.f;
#pragma unroll
    for (int i = 0; i < 3; ++i) {
        int cix = t + i * 256;
        float x = base[ro + cix] + a1[ro + cix];
        if (NADD >= 2) x += a2[ro + cix];
        if (NADD >= 3) x += a3[ro + cix];
        if (NADD >= 4) x += a4[ro + cix];
        v[i] = x;
        s += x;
    }
    __shared__ float red[4];
#pragma unroll
    for (int off = 1; off < 64; off <<= 1) s += __shfl_xor(s, off, 64);
    if ((t & 63) == 0) red[t >> 6] = s;
    __syncthreads();
    float mu = (red[0] + red[1] + red[2] + red[3]) * (1.f / LATENT);
    float q = 0.f;
#pragma unroll
    for (int i = 0; i < 3; ++i) {
        float d = v[i] - mu;
        q += d * d;
    }
#pragma unroll
    for (int off = 1; off < 64; off <<= 1) q += __shfl_xor(q, off, 64);
    __syncthreads();
    if ((t & 63) == 0) red[t >> 6] = q;
    __syncthreads();
    float var = (red[0] + red[1] + red[2] + red[3]) * (1.f / LATENT);
    float rs = rsqrtf(var + 1e-5f);
#pragma unroll
    for (int i = 0; i < 3; ++i) {
        int cix = t + i * 256;
        float o = (v[i] - mu) * rs * g[cix] + bta[cix];
        outf[ro + cix] = o;
        if (outb) outb[ro + cix] = (bf16_t)o;
    }
}

// ---------------------------------------------------------------------------
extern "C" void kernel_launch(void* const* d_in, const int* in_sizes, int n_in,
                              void* d_out, int out_size, void* d_ws, size_t ws_size,
                              hipStream_t stream) {
    const float* x   = (const float*)d_in[0];
    const float* Wq  = (const float*)d_in[1];
    const float* bq  = (const float*)d_in[2];
    const float* Wk  = (const float*)d_in[3];
    const float* bk  = (const float*)d_in[4];
    const float* Wv  = (const float*)d_in[5];
    const float* bv  = (const float*)d_in[6];
    const float* Wo  = (const float*)d_in[7];
    const float* bo  = (const float*)d_in[8];
    const float* g1  = (const float*)d_in[9];
    const float* be1 = (const float*)d_in[10];
    const float* g2  = (const float*)d_in[11];
    const float* be2 = (const float*)d_in[12];
    const float* W1  = (const float*)d_in[13];
    const float* b1  = (const float*)d_in[14];
    const float* W2  = (const float*)d_in[15];
    const float* b2  = (const float*)d_in[16];
    float* out = (float*)d_out;

    char* ws = (char*)d_ws;
    size_t off = 0;
    auto alloc = [&](size_t bytes) {
        char* p = ws + off;
        off = (off + bytes + 255) & ~(size_t)255;
        return p;
    };
    bf16_t* xbf   = (bf16_t*)alloc((size_t)NTOK * LATENT * 2);
    bf16_t* Wcat  = (bf16_t*)alloc((size_t)3 * LATENT * LATENT * 2);
    bf16_t* Wobf  = (bf16_t*)alloc((size_t)LATENT * LATENT * 2);
    bf16_t* W1bf  = (bf16_t*)alloc((size_t)FFN_DIM * LATENT * 2);
    bf16_t* W2bf  = (bf16_t*)alloc((size_t)LATENT * FFN_DIM * 2);
    float*  bcat  = (float*)alloc((size_t)3 * LATENT * 4);
    bf16_t* QKV   = (bf16_t*)alloc((size_t)NTOK * 3 * LATENT * 2);
    bf16_t* attnO = (bf16_t*)alloc((size_t)NTOK * LATENT * 2);
    float*  tmpf  = (float*)alloc((size_t)NTOK * LATENT * 4);
    float*  y1f   = (float*)alloc((size_t)NTOK * LATENT * 4);
    bf16_t* y1bf  = (bf16_t*)alloc((size_t)NTOK * LATENT * 2);
    bf16_t* hbf   = (bf16_t*)alloc((size_t)NTOK * FFN_DIM * 2);
    float*  P3    = (float*)alloc((size_t)NTOK * LATENT * 4);   // 4th FFN2 partial
    bf16_t* Vtg   = (bf16_t*)hbf;   // alias: Vt lifetime disjoint from h
    // FFN2 split-K partials (all dead regions at FFN2 time):
    //   P0 = tmpf (dead after ln1), P1 = QKV (dead after attn),
    //   P2 = xbf..Wcat span (15.7MB, dead after QKV gemm), P3 dedicated.
    float* P0 = tmpf;
    float* P1 = (float*)QKV;
    float* P2 = (float*)xbf;

    // 1. convert to bf16 + bias concat (seg 7)
    CvtDesc cd;
    cd.src[0] = x;   cd.dst[0] = xbf;                        cd.n4[0] = NTOK * LATENT / 4;
    cd.src[1] = Wq;  cd.dst[1] = Wcat;                       cd.n4[1] = LATENT * LATENT / 4;
    cd.src[2] = Wk;  cd.dst[2] = Wcat + LATENT * LATENT;     cd.n4[2] = LATENT * LATENT / 4;
    cd.src[3] = Wv;  cd.dst[3] = Wcat + 2 * LATENT * LATENT; cd.n4[3] = LATENT * LATENT / 4;
    cd.src[4] = Wo;  cd.dst[4] = Wobf;                       cd.n4[4] = LATENT * LATENT / 4;
    cd.src[5] = W1;  cd.dst[5] = W1bf;                       cd.n4[5] = FFN_DIM * LATENT / 4;
    cd.src[6] = W2;  cd.dst[6] = W2bf;                       cd.n4[6] = FFN_DIM * LATENT / 4;
    cd.bsrc[0] = bq; cd.bsrc[1] = bk; cd.bsrc[2] = bv;
    cd.bdst = bcat;
    {
        int maxn4 = NTOK * LATENT / 4;
        dim3 grid((maxn4 + 255) / 256, 8);
        cvt_f32_bf16<<<grid, 256, 0, stream>>>(cd);
    }

    // 2. fused QKV GEMM; Q region pre-scaled by C2 (EPI=3). 512 thr / 8 waves.
    gemm128<3><<<dim3(NTOK / 128, 3 * LATENT / 128), 512, 0, stream>>>(
        xbf, Wcat, bcat, QKV, NTOK, 3 * LATENT, LATENT);

    // 2.5 V transpose
    v_transpose<<<dim3(SEQ / 64, 2 * HEADS), 256, 0, stream>>>(QKV, Vtg);

    // 3. attention: no split-K, 768 blocks x 4 waves (64 q each), bf16 out
    attn_flash<<<dim3(2 * HEADS, SEQ / 64), 256, 0, stream>>>(QKV, Vtg, attnO);

    // 4. output projection: 64x64 tiles, 768 blocks x 8 waves (r14)
    gemm64<0><<<dim3(NTOK / 64, LATENT / 64), 512, 0, stream>>>(
        attnO, Wobf, bo, tmpf, NTOK, LATENT, LATENT);

    // 5. y1 = LN(x + proj)
    ln_residual<1><<<NTOK, 256, 0, stream>>>(x, tmpf, nullptr, nullptr, nullptr,
                                             g1, be1, y1f, y1bf);

    // 6. h = gelu(y1 @ W1^T + b1). 512 thr / 8 waves.
    gemm128<2><<<dim3(NTOK / 128, FFN_DIM / 128), 512, 0, stream>>>(
        y1bf, W1bf, b1, hbf, NTOK, FFN_DIM, LATENT);

    // 7. ffn partials = h @ W2^T + b2, 128x128 split-K x4: 768 blocks = 3/CU
    SKDst skd;
    skd.p[0] = P0; skd.p[1] = P1; skd.p[2] = P2; skd.p[3] = P3;
    gemm128sk<<<dim3(NTOK / 128, LATENT / 128, 4), 512, 0, stream>>>(
        hbf, W2bf, b2, skd, NTOK, LATENT, FFN_DIM);

    // 8. out = LN(y1 + P0 + P1 + P2 + P3)
    ln_residual<4><<<NTOK, 256, 0, stream>>>(y1f, P0, P1, P2, P3,
                                             g2, be2, out, nullptr);
}